// Round 1
// baseline (3177.626 us; speedup 1.0000x reference)
//
#include <hip/hip_runtime.h>
#include <math.h>

// Problem constants
#define Bn 16
#define Ln 1024
#define Dn 768
#define Hn 12
#define PHDn 64
#define NK 33                 // Hermitian bins for 64-pt DFT (k=0..32)
#define TWOPI_64 0.09817477042468103f   // 2*pi/64

// ---------------- workspace layout (float offsets) ----------------
static const size_t O_P    = 0;          // psf softmaxed taps [H][1024][64]         786432
static const size_t O_PSFH = 786432;     // psf-hat [h*33+k][1024][2]                 811008
static const size_t O_QH   = 1597440;    // q-hat  [h*33+k][2]                        792 (pad 800)
static const size_t O_X    = 1598240;    // x = pre-proj [B*L][768]                   12582912
static const size_t O_XH   = 14181152;   // X-hat [bhk][1024][2] (later reused as G)  12976128
static const size_t O_YH   = 27157280;   // Y-hat (later reused as conv_emb)          12976128
static const size_t O_TH   = 40133408;   // totals per (b,h,k) [bhk][2]               12672
static const size_t O_SPE  = 40146080;   // sparse_emb [B*L][768]                     12582912
static const size_t O_V    = 52728992;   // v vector (1024)
static const size_t O_UR   = 52730016;   // u_raw (1024)
static const size_t O_SIG  = 52731040;   // inv_sigma scalar
// total = 52731048 floats = ~211 MB

// ---------------- psf softmax over 2047 taps (1023 are zeros) ----------------
__global__ __launch_bounds__(256) void k_psf_softmax(const float* __restrict__ psfs,
                                                     float* __restrict__ p,
                                                     float* __restrict__ q) {
    int he = blockIdx.x;            // h*64+e
    int h = he >> 6, e = he & 63;
    int tid = threadIdx.x;
    float ev[4];
    float s = 0.f;
#pragma unroll
    for (int i = 0; i < 4; ++i) {
        int t = tid + 256 * i;
        float v = psfs[((size_t)h * 2047 + t) * 64 + e];
        ev[i] = expf(v);
        s += ev[i];
    }
    __shared__ float red[256];
    red[tid] = s; __syncthreads();
    for (int st = 128; st > 0; st >>= 1) {
        if (tid < st) red[tid] += red[tid + st];
        __syncthreads();
    }
    // 1023 masked taps contribute exp(0)=1 each to the softmax denominator
    float denom = red[0] + 1023.0f;
    float inv = 1.0f / denom;
#pragma unroll
    for (int i = 0; i < 4; ++i) {
        int t = tid + 256 * i;
        p[((size_t)h * 1024 + t) * 64 + e] = ev[i] * inv;
    }
    if (tid == 0) q[he] = inv;
}

// ---------------- DFT over head-dim of psf taps: psfh[h*33+k][t] ----------------
__global__ __launch_bounds__(64) void k_psf_dft(const float* __restrict__ p,
                                                float* __restrict__ psfh) {
    int ht = blockIdx.x;            // h*1024+t
    int h = ht >> 10, t = ht & 1023;
    int tid = threadIdx.x;          // 64
    __shared__ float pv[64], cc[64], ssn[64];
    pv[tid] = p[((size_t)h * 1024 + t) * 64 + tid];
    float ang = TWOPI_64 * tid;
    cc[tid] = cosf(ang); ssn[tid] = sinf(ang);
    __syncthreads();
    if (tid < NK) {
        float re = 0.f, im = 0.f;
#pragma unroll 8
        for (int e = 0; e < 64; ++e) {
            int j = (tid * e) & 63;
            float v = pv[e];
            re += v * cc[j];
            im -= v * ssn[j];
        }
        size_t o = (((size_t)h * NK + tid) * 1024 + t) * 2;
        psfh[o] = re; psfh[o + 1] = im;
    }
}

// ---------------- DFT of uniform tap value q[h][e] ----------------
__global__ __launch_bounds__(64) void k_q_dft(const float* __restrict__ q,
                                              float* __restrict__ qh) {
    int h = blockIdx.x;
    int tid = threadIdx.x;
    __shared__ float qv[64], cc[64], ssn[64];
    qv[tid] = q[h * 64 + tid];
    float ang = TWOPI_64 * tid;
    cc[tid] = cosf(ang); ssn[tid] = sinf(ang);
    __syncthreads();
    if (tid < NK) {
        float re = 0.f, im = 0.f;
        for (int e = 0; e < 64; ++e) {
            int j = (tid * e) & 63;
            re += qv[e] * cc[j];
            im -= qv[e] * ssn[j];
        }
        qh[(h * NK + tid) * 2] = re;
        qh[(h * NK + tid) * 2 + 1] = im;
    }
}

// ---------------- generic C = A(MxK) * W(NxK)^T + bias, f32, 128x128 tile ----------------
__global__ __launch_bounds__(256) void k_gemm_abt(const float* __restrict__ A,
                                                  const float* __restrict__ W,
                                                  const float* __restrict__ bias,
                                                  float* __restrict__ C,
                                                  int M, int N, int K) {
    int n0 = blockIdx.x * 128, m0 = blockIdx.y * 128;
    int tid = threadIdx.x;
    int tx = tid & 15, ty = tid >> 4;
    __shared__ float As[128 * 33], Bs[128 * 33];
    float acc[8][8] = {};
    for (int k0 = 0; k0 < K; k0 += 32) {
#pragma unroll
        for (int i = 0; i < 16; ++i) {
            int idx = tid + 256 * i;      // 0..4095
            int r = idx >> 5, c = idx & 31;
            As[r * 33 + c] = A[(size_t)(m0 + r) * K + k0 + c];
            Bs[r * 33 + c] = W[(size_t)(n0 + r) * K + k0 + c];
        }
        __syncthreads();
#pragma unroll
        for (int kk = 0; kk < 32; ++kk) {
            float a[8], b[8];
#pragma unroll
            for (int i = 0; i < 8; ++i) a[i] = As[(ty * 8 + i) * 33 + kk];
#pragma unroll
            for (int j = 0; j < 8; ++j) b[j] = Bs[(tx * 8 + j) * 33 + kk];
#pragma unroll
            for (int i = 0; i < 8; ++i)
#pragma unroll
                for (int j = 0; j < 8; ++j)
                    acc[i][j] += a[i] * b[j];
        }
        __syncthreads();
    }
#pragma unroll
    for (int i = 0; i < 8; ++i) {
        int m = m0 + ty * 8 + i;
#pragma unroll
        for (int j = 0; j < 8; ++j) {
            int n = n0 + tx * 8 + j;
            float bv = bias ? bias[n] : 0.f;
            C[(size_t)m * N + n] = acc[i][j] + bv;
        }
    }
}

// ---------------- forward DFT over head-dim of x: XH[bhk][u] ----------------
__global__ __launch_bounds__(512) void k_dft_d(const float* __restrict__ X,
                                               float* __restrict__ XH) {
    int r = blockIdx.x;                  // b*1024+u
    int b = r >> 10, u = r & 1023;
    int tid = threadIdx.x;               // 512
    __shared__ float xs[12 * 65], cc[64], ssn[64];
    if (tid < 64) {
        float ang = TWOPI_64 * tid;
        cc[tid] = cosf(ang); ssn[tid] = sinf(ang);
    }
    for (int o = tid; o < 768; o += 512)
        xs[(o >> 6) * 65 + (o & 63)] = X[(size_t)r * 768 + o];
    __syncthreads();
    if (tid < Hn * NK) {
        int h = tid / NK, k = tid - h * NK;
        float re = 0.f, im = 0.f;
#pragma unroll 8
        for (int d = 0; d < 64; ++d) {
            float v = xs[h * 65 + d];
            int j = (k * d) & 63;
            re += v * cc[j];
            im -= v * ssn[j];
        }
        size_t o = (((size_t)(b * Hn + h) * NK + k) * 1024 + u) * 2;
        XH[o] = re; XH[o + 1] = im;
    }
}

// ---------------- totals T[bhk] = sum_u XH[bhk][u] ----------------
__global__ __launch_bounds__(256) void k_total(const float* __restrict__ XH,
                                               float* __restrict__ TH) {
    int bhk = blockIdx.x;
    int tid = threadIdx.x;
    float re = 0.f, im = 0.f;
    for (int u = tid; u < 1024; u += 256) {
        size_t o = ((size_t)bhk * 1024 + u) * 2;
        re += XH[o]; im += XH[o + 1];
    }
    __shared__ float rr[256], ri[256];
    rr[tid] = re; ri[tid] = im; __syncthreads();
    for (int st = 128; st > 0; st >>= 1) {
        if (tid < st) { rr[tid] += rr[tid + st]; ri[tid] += ri[tid + st]; }
        __syncthreads();
    }
    if (tid == 0) { TH[bhk * 2] = rr[0]; TH[bhk * 2 + 1] = ri[0]; }
}

// ---------------- causal conv per (b,h,k) + uniform suffix term ----------------
__global__ __launch_bounds__(128) void k_causal_conv(const float* __restrict__ XH,
                                                     const float* __restrict__ PH,
                                                     const float* __restrict__ QH,
                                                     const float* __restrict__ TH,
                                                     float* __restrict__ YH) {
    int blk = blockIdx.x;
    int bhk = blk >> 3, st = blk & 7;
    int s0 = st << 7;
    int hk = bhk % (Hn * NK);       // h*33+k
    int tid = threadIdx.x;          // 128
    __shared__ float Xs[128 * 2], Tp[256 * 2];
    float ar = 0.f, ai = 0.f, pr = 0.f, pi = 0.f;
    for (int ut = 0; ut <= st; ++ut) {
        int u0 = ut << 7;
        size_t xb = ((size_t)bhk * 1024 + u0 + tid) * 2;
        Xs[tid * 2] = XH[xb];
        Xs[tid * 2 + 1] = XH[xb + 1];
        int base = s0 - u0 - 127;
        for (int l = tid; l < 256; l += 128) {
            int t = base + l;
            bool ok = (t >= 0) && (t < 1024);
            size_t pb = ((size_t)hk * 1024 + (ok ? t : 0)) * 2;
            Tp[l * 2] = ok ? PH[pb] : 0.f;
            Tp[l * 2 + 1] = ok ? PH[pb + 1] : 0.f;
        }
        __syncthreads();
        if (ut < st) {
#pragma unroll 4
            for (int j = 0; j < 128; ++j) {
                float xr = Xs[j * 2], xi = Xs[j * 2 + 1];
                int l = tid - j + 127;
                float tr = Tp[l * 2], ti = Tp[l * 2 + 1];
                ar += tr * xr - ti * xi;
                ai += tr * xi + ti * xr;
                pr += xr; pi += xi;
            }
        } else {
            for (int j = 0; j <= tid; ++j) {
                float xr = Xs[j * 2], xi = Xs[j * 2 + 1];
                int l = tid - j + 127;
                float tr = Tp[l * 2], ti = Tp[l * 2 + 1];
                ar += tr * xr - ti * xi;
                ai += tr * xi + ti * xr;
                pr += xr; pi += xi;
            }
        }
        __syncthreads();
    }
    float qr = QH[hk * 2], qi = QH[hk * 2 + 1];
    float dr = TH[bhk * 2] - pr, di = TH[bhk * 2 + 1] - pi;
    float yr = ar + qr * dr - qi * di;
    float yi = ai + qr * di + qi * dr;
    size_t o = ((size_t)bhk * 1024 + s0 + tid) * 2;
    YH[o] = yr; YH[o + 1] = yi;
}

// ---------------- inverse DFT over head-dim + exact GELU ----------------
__global__ __launch_bounds__(512) void k_idft_gelu(const float* __restrict__ YH,
                                                   float* __restrict__ G) {
    int r = blockIdx.x;                 // b*1024+s
    int b = r >> 10, s = r & 1023;
    int tid = threadIdx.x;
    __shared__ float Ys[Hn * NK * 2], cc[64], ssn[64];
    if (tid < 64) {
        float ang = TWOPI_64 * tid;
        cc[tid] = cosf(ang); ssn[tid] = sinf(ang);
    }
    if (tid < Hn * NK) {
        size_t o = (((size_t)b * (Hn * NK) + tid) * 1024 + s) * 2;
        Ys[tid * 2] = YH[o]; Ys[tid * 2 + 1] = YH[o + 1];
    }
    __syncthreads();
    for (int o = tid; o < 768; o += 512) {
        int h = o >> 6, d = o & 63;
        const float* Yh = &Ys[(h * NK) * 2];
        float acc = Yh[0];              // k=0 (im contributes 0)
        {
            int j = (32 * d) & 63;
            acc += Yh[32 * 2] * cc[j] - Yh[32 * 2 + 1] * ssn[j];
        }
#pragma unroll 8
        for (int k = 1; k < 32; ++k) {
            int j = (k * d) & 63;
            acc += 2.f * (Yh[k * 2] * cc[j] - Yh[k * 2 + 1] * ssn[j]);
        }
        float conv = acc * (1.0f / 64.0f);
        float g = conv * 0.5f * (1.0f + erff(conv * 0.70710678118f));
        G[(size_t)r * 768 + o] = g;
    }
}

// ---------------- spectral norm pieces ----------------
__global__ __launch_bounds__(1024) void k_sn_v(const float* __restrict__ Wm,
                                               float* __restrict__ v) {
    int j = threadIdx.x;
    float s = 0.f;
    for (int i = 0; i < 1024; ++i) s += Wm[(size_t)i * 1024 + j];
    s *= 0.03125f;                    // 1/sqrt(1024)
    __shared__ float red[1024];
    red[j] = s * s; __syncthreads();
    for (int st = 512; st > 0; st >>= 1) {
        if (j < st) red[j] += red[j + st];
        __syncthreads();
    }
    float nrm = sqrtf(red[0]);
    v[j] = s / (nrm + 1e-12f);
}

__global__ __launch_bounds__(64) void k_sn_u(const float* __restrict__ Wm,
                                             const float* __restrict__ v,
                                             float* __restrict__ ur) {
    int i = blockIdx.x;
    int lane = threadIdx.x;           // 64
    float s = 0.f;
    for (int j = lane; j < 1024; j += 64) s += Wm[(size_t)i * 1024 + j] * v[j];
#pragma unroll
    for (int off = 32; off > 0; off >>= 1) s += __shfl_down(s, off);
    if (lane == 0) ur[i] = s;
}

__global__ __launch_bounds__(1024) void k_sn_sigma(const float* __restrict__ ur,
                                                   float* __restrict__ sig) {
    int i = threadIdx.x;
    __shared__ float red[1024];
    float u = ur[i];
    red[i] = u * u; __syncthreads();
    for (int st = 512; st > 0; st >>= 1) {
        if (i < st) red[i] += red[i + st];
        __syncthreads();
    }
    if (i == 0) {
        float ss = red[0];
        // sigma = u_hat . (W v) = ||u_raw||^2 / (||u_raw|| + eps)
        float sigma = ss / (sqrtf(ss) + 1e-12f);
        sig[0] = 1.0f / sigma;
    }
}

// ---------------- sparse branch: C_b = tril(SP)*invs @ x_b, 128x128 tile ----------------
__global__ __launch_bounds__(256) void k_gemm_sparse(const float* __restrict__ SP,
                                                     const float* __restrict__ X,
                                                     const float* __restrict__ sigbuf,
                                                     float* __restrict__ Cout) {
    int n0 = blockIdx.x * 128, m0 = blockIdx.y * 128, b = blockIdx.z;
    const float invs = sigbuf[0];
    const float* Xb = X + (size_t)b * 1024 * 768;
    float* Cb = Cout + (size_t)b * 1024 * 768;
    int tid = threadIdx.x;
    int tx = tid & 15, ty = tid >> 4;
    __shared__ float As[128 * 33], Bs[32 * 129];
    float acc[8][8] = {};
    int nkt = (m0 >> 5) + 4;          // only t-tiles with t0 <= m0+127
    for (int kt = 0; kt < nkt; ++kt) {
        int k0 = kt * 32;
#pragma unroll
        for (int i = 0; i < 16; ++i) {
            int idx = tid + 256 * i;
            int r = idx >> 5, c = idx & 31;
            int s = m0 + r, t = k0 + c;
            float v = SP[(size_t)s * 1024 + t];
            As[r * 33 + c] = (t <= s) ? v * invs : 0.f;
        }
#pragma unroll
        for (int i = 0; i < 16; ++i) {
            int idx = tid + 256 * i;
            int kr = idx >> 7, c = idx & 127;    // 32 rows x 128 cols
            Bs[kr * 129 + c] = Xb[(size_t)(k0 + kr) * 768 + n0 + c];
        }
        __syncthreads();
#pragma unroll
        for (int kk = 0; kk < 32; ++kk) {
            float a[8], bv[8];
#pragma unroll
            for (int i = 0; i < 8; ++i) a[i] = As[(ty * 8 + i) * 33 + kk];
#pragma unroll
            for (int j = 0; j < 8; ++j) bv[j] = Bs[kk * 129 + tx * 8 + j];
#pragma unroll
            for (int i = 0; i < 8; ++i)
#pragma unroll
                for (int j = 0; j < 8; ++j)
                    acc[i][j] += a[i] * bv[j];
        }
        __syncthreads();
    }
#pragma unroll
    for (int i = 0; i < 8; ++i)
#pragma unroll
        for (int j = 0; j < 8; ++j)
            Cb[(size_t)(m0 + ty * 8 + i) * 768 + n0 + tx * 8 + j] = acc[i][j];
}

// ---------------- final residual + LayerNorm ----------------
__global__ __launch_bounds__(256) void k_final_ln(const float* __restrict__ CE,
                                                  const float* __restrict__ SE,
                                                  const float* __restrict__ EMB,
                                                  const float* __restrict__ g,
                                                  const float* __restrict__ be,
                                                  float* __restrict__ out) {
    int r = blockIdx.x;
    int tid = threadIdx.x;
    float y[3];
    float s = 0.f;
#pragma unroll
    for (int i = 0; i < 3; ++i) {
        int o = tid + i * 256;
        size_t idx = (size_t)r * 768 + o;
        y[i] = CE[idx] + SE[idx] + EMB[idx];
        s += y[i];
    }
    __shared__ float red[256];
    red[tid] = s; __syncthreads();
    for (int st = 128; st > 0; st >>= 1) {
        if (tid < st) red[tid] += red[tid + st];
        __syncthreads();
    }
    float mu = red[0] * (1.f / 768.f);
    __syncthreads();
    float vs = 0.f;
#pragma unroll
    for (int i = 0; i < 3; ++i) { float d = y[i] - mu; vs += d * d; }
    red[tid] = vs; __syncthreads();
    for (int st = 128; st > 0; st >>= 1) {
        if (tid < st) red[tid] += red[tid + st];
        __syncthreads();
    }
    float var = red[0] * (1.f / 768.f);
    float rstd = rsqrtf(var + 1e-12f);
#pragma unroll
    for (int i = 0; i < 3; ++i) {
        int o = tid + i * 256;
        size_t idx = (size_t)r * 768 + o;
        out[idx] = (y[i] - mu) * rstd * g[o] + be[o];
    }
}

extern "C" void kernel_launch(void* const* d_in, const int* in_sizes, int n_in,
                              void* d_out, int out_size, void* d_ws, size_t ws_size,
                              hipStream_t stream) {
    const float* emb     = (const float*)d_in[0];
    const float* pre_w   = (const float*)d_in[1];
    const float* pre_b   = (const float*)d_in[2];
    const float* psfs    = (const float*)d_in[3];
    const float* post_w  = (const float*)d_in[4];
    const float* post_b  = (const float*)d_in[5];
    const float* spmat   = (const float*)d_in[6];
    const float* ln_g    = (const float*)d_in[7];
    const float* ln_b    = (const float*)d_in[8];
    float* out = (float*)d_out;
    float* ws = (float*)d_ws;

    float* p    = ws + O_P;
    float* psfh = ws + O_PSFH;
    float* qh   = ws + O_QH;
    float* q    = ws + O_QH + 800 - 768;  // reuse tail; actually allocate q separately below
    // q needs 768 floats; place it in the sigma-region padding instead:
    q = ws + O_SIG + 8;                   // 768 floats after sigma slot
    float* x    = ws + O_X;
    float* XH   = ws + O_XH;
    float* YH   = ws + O_YH;
    float* TH   = ws + O_TH;
    float* spe  = ws + O_SPE;
    float* v    = ws + O_V;
    float* urw  = ws + O_UR;
    float* sig  = ws + O_SIG;
    float* G    = XH;    // reuse: XH dead after k_causal_conv
    float* CE   = YH;    // reuse: YH dead after k_idft_gelu

    // PSF preprocessing
    k_psf_softmax<<<Hn * 64, 256, 0, stream>>>(psfs, p, q);
    k_psf_dft<<<Hn * 1024, 64, 0, stream>>>(p, psfh);
    k_q_dft<<<Hn, 64, 0, stream>>>(q, qh);

    // pre-projection
    k_gemm_abt<<<dim3(6, 128), 256, 0, stream>>>(emb, pre_w, pre_b, x, Bn * Ln, Dn, Dn);

    // head-dim DFT of x
    k_dft_d<<<Bn * Ln, 512, 0, stream>>>(x, XH);
    k_total<<<Bn * Hn * NK, 256, 0, stream>>>(XH, TH);

    // causal conv + uniform suffix term, per (b,h,k) bin
    k_causal_conv<<<Bn * Hn * NK * 8, 128, 0, stream>>>(XH, psfh, qh, TH, YH);

    // inverse DFT + gelu -> G (reuses XH)
    k_idft_gelu<<<Bn * Ln, 512, 0, stream>>>(YH, G);

    // post-projection -> conv_emb (reuses YH)
    k_gemm_abt<<<dim3(6, 128), 256, 0, stream>>>(G, post_w, post_b, CE, Bn * Ln, Dn, Dn);

    // spectral norm scalar
    k_sn_v<<<1, 1024, 0, stream>>>(spmat, v);
    k_sn_u<<<1024, 64, 0, stream>>>(spmat, v, urw);
    k_sn_sigma<<<1, 1024, 0, stream>>>(urw, sig);

    // sparse branch
    k_gemm_sparse<<<dim3(6, 8, Bn), 256, 0, stream>>>(spmat, x, sig, spe);

    // residual + LayerNorm
    k_final_ln<<<Bn * Ln, 256, 0, stream>>>(CE, spe, emb, ln_g, ln_b, out);
}

// Round 2
// 1893.904 us; speedup vs baseline: 1.6778x; 1.6778x over previous
//
#include <hip/hip_runtime.h>
#include <math.h>

// Problem constants
#define Bn 16
#define Ln 1024
#define Dn 768
#define Hn 12
#define PHDn 64
#define NK 33                 // Hermitian bins for 64-pt DFT (k=0..32)
#define NHK (Hn * NK)         // 396
#define TWOPI_64 0.09817477042468103f   // 2*pi/64

// ---------------- workspace layout (float offsets) ----------------
static const size_t O_P    = 0;          // psf softmaxed taps [H][1024][64]         786432
static const size_t O_PSFH = 786432;     // psf-hat [h*33+k][1024][2]                 811008
static const size_t O_QH   = 1597440;    // q-hat  [h*33+k][2]                        792 (pad 800)
static const size_t O_X    = 1598240;    // x = pre-proj [B*L][768]                   12582912
static const size_t O_XH   = 14181152;   // X-hat [bhk][1024][2] (later reused as G)  12976128
static const size_t O_YH   = 27157280;   // Y-hat (later reused as conv_emb)          12976128
static const size_t O_TH   = 40133408;   // (free)
static const size_t O_SPE  = 40146080;   // sparse_emb [B*L][768]; PHF aliased here   12582912
static const size_t O_V    = 52728992;   // v vector (1024)
static const size_t O_UR   = 52730016;   // u_raw (1024)
static const size_t O_SIG  = 52731040;   // inv_sigma scalar (+ q[768] after)

// ---------------- psf softmax over 2047 taps (1023 are zeros) ----------------
__global__ __launch_bounds__(256) void k_psf_softmax(const float* __restrict__ psfs,
                                                     float* __restrict__ p,
                                                     float* __restrict__ q) {
    int he = blockIdx.x;            // h*64+e
    int h = he >> 6, e = he & 63;
    int tid = threadIdx.x;
    float ev[4];
    float s = 0.f;
#pragma unroll
    for (int i = 0; i < 4; ++i) {
        int t = tid + 256 * i;
        float v = psfs[((size_t)h * 2047 + t) * 64 + e];
        ev[i] = expf(v);
        s += ev[i];
    }
    __shared__ float red[256];
    red[tid] = s; __syncthreads();
    for (int st = 128; st > 0; st >>= 1) {
        if (tid < st) red[tid] += red[tid + st];
        __syncthreads();
    }
    // 1023 masked taps contribute exp(0)=1 each to the softmax denominator
    float denom = red[0] + 1023.0f;
    float inv = 1.0f / denom;
#pragma unroll
    for (int i = 0; i < 4; ++i) {
        int t = tid + 256 * i;
        p[((size_t)h * 1024 + t) * 64 + e] = ev[i] * inv;
    }
    if (tid == 0) q[he] = inv;
}

// ---------------- DFT over head-dim of psf taps: psfh[h*33+k][t] ----------------
__global__ __launch_bounds__(64) void k_psf_dft(const float* __restrict__ p,
                                                float* __restrict__ psfh) {
    int ht = blockIdx.x;            // h*1024+t
    int h = ht >> 10, t = ht & 1023;
    int tid = threadIdx.x;          // 64
    __shared__ float pv[64], cc[64], ssn[64];
    pv[tid] = p[((size_t)h * 1024 + t) * 64 + tid];
    float ang = TWOPI_64 * tid;
    cc[tid] = cosf(ang); ssn[tid] = sinf(ang);
    __syncthreads();
    if (tid < NK) {
        float re = 0.f, im = 0.f;
#pragma unroll 8
        for (int e = 0; e < 64; ++e) {
            int j = (tid * e) & 63;
            float v = pv[e];
            re += v * cc[j];
            im -= v * ssn[j];
        }
        size_t o = (((size_t)h * NK + tid) * 1024 + t) * 2;
        psfh[o] = re; psfh[o + 1] = im;
    }
}

// ---------------- DFT of uniform tap value q[h][e] ----------------
__global__ __launch_bounds__(64) void k_q_dft(const float* __restrict__ q,
                                              float* __restrict__ qh) {
    int h = blockIdx.x;
    int tid = threadIdx.x;
    __shared__ float qv[64], cc[64], ssn[64];
    qv[tid] = q[h * 64 + tid];
    float ang = TWOPI_64 * tid;
    cc[tid] = cosf(ang); ssn[tid] = sinf(ang);
    __syncthreads();
    if (tid < NK) {
        float re = 0.f, im = 0.f;
        for (int e = 0; e < 64; ++e) {
            int j = (tid * e) & 63;
            re += qv[e] * cc[j];
            im -= qv[e] * ssn[j];
        }
        qh[(h * NK + tid) * 2] = re;
        qh[(h * NK + tid) * 2 + 1] = im;
    }
}

// ---------------- 2048-pt radix-2 Stockham FFT stages (ping-pong LDS) ----------------
// Caller: load input into A, __syncthreads(), call; result lands in B.
__device__ __forceinline__ void fft_stages(float2* __restrict__ A,
                                           float2* __restrict__ B,
                                           const float2* __restrict__ tw,
                                           int tid) {
    float2* X = A;
    float2* Y = B;
#pragma unroll 1
    for (int s = 0; s < 11; ++s) {
        int m = 1 << s;
        int mask = ~(m - 1);
#pragma unroll
        for (int it = 0; it < 4; ++it) {
            int i = tid + it * 256;
            float2 c0 = X[i];
            float2 c1 = X[i + 1024];
            float2 w = tw[i & mask];
            float dr = c0.x - c1.x, di = c0.y - c1.y;
            int o0 = i + (i & mask);
            Y[o0] = make_float2(c0.x + c1.x, c0.y + c1.y);
            Y[o0 + m] = make_float2(w.x * dr - w.y * di, w.x * di + w.y * dr);
        }
        __syncthreads();
        float2* t = X; X = Y; Y = t;
    }
}

__device__ __forceinline__ void build_twiddles(float2* tw, int tid) {
#pragma unroll
    for (int it = 0; it < 4; ++it) {
        int j = tid + it * 256;
        float a = (float)j * 3.0679615757712823e-3f;   // 2*pi/2048
        float sv, cv;
        __sincosf(a, &sv, &cv);
        tw[j] = make_float2(cv, -sv);
    }
}

// ---------------- FFT of tap vector per (h,k): p-taps at [0,1024), q at [1025,2048) ----------------
__global__ __launch_bounds__(256) void k_tap_fft(const float* __restrict__ psfh,
                                                 const float* __restrict__ qh,
                                                 float* __restrict__ phf) {
    __shared__ float2 A[2048], Bf[2048], tw[1024];
    int hk = blockIdx.x, tid = threadIdx.x;
    build_twiddles(tw, tid);
    float2 q = make_float2(qh[hk * 2], qh[hk * 2 + 1]);
    const float2* Pg = (const float2*)(psfh + (size_t)hk * 2048);
#pragma unroll
    for (int it = 0; it < 8; ++it) {
        int t = tid + it * 256;
        float2 v;
        if (t < 1024)       v = Pg[t];
        else if (t == 1024) v = make_float2(0.f, 0.f);
        else                v = q;
        A[t] = v;
    }
    __syncthreads();
    fft_stages(A, Bf, tw, tid);
    float2* out = (float2*)(phf + (size_t)hk * 4096);
#pragma unroll
    for (int it = 0; it < 8; ++it) {
        int t = tid + it * 256;
        out[t] = Bf[t];
    }
}

// ---------------- per-(b,h,k) causal conv + uniform suffix via circular-2048 FFT ----------------
__global__ __launch_bounds__(256) void k_conv_fft(const float* __restrict__ XH,
                                                  const float* __restrict__ PHF,
                                                  float* __restrict__ YH) {
    __shared__ float2 A[2048], Bf[2048], tw[1024];
    int bhk = blockIdx.x, tid = threadIdx.x;
    int hk = bhk % NHK;
    build_twiddles(tw, tid);
    const float2* Xg = (const float2*)(XH + (size_t)bhk * 2048);
#pragma unroll
    for (int it = 0; it < 8; ++it) {
        int t = tid + it * 256;
        A[t] = (t < 1024) ? Xg[t] : make_float2(0.f, 0.f);
    }
    __syncthreads();
    fft_stages(A, Bf, tw, tid);        // X-hat in Bf
    const float2* P = (const float2*)(PHF + (size_t)hk * 4096);
#pragma unroll
    for (int it = 0; it < 8; ++it) {
        int t = tid + it * 256;
        float2 u = Bf[t], pv = P[t];
        float vr = u.x * pv.x - u.y * pv.y;
        float vi = u.x * pv.y + u.y * pv.x;
        A[t] = make_float2(vr, -vi);   // conj for inverse-FFT trick
    }
    __syncthreads();
    fft_stages(A, Bf, tw, tid);        // FFT of conj(product) in Bf
    float2* Yg = (float2*)(YH + (size_t)bhk * 2048);
    const float inv_n = 1.0f / 2048.0f;
#pragma unroll
    for (int it = 0; it < 4; ++it) {
        int s = tid + it * 256;
        float2 r = Bf[s];
        Yg[s] = make_float2(r.x * inv_n, -r.y * inv_n);
    }
}

// ---------------- generic C = A(MxK) * W(NxK)^T + bias, f32, 128x128 tile ----------------
__global__ __launch_bounds__(256) void k_gemm_abt(const float* __restrict__ A,
                                                  const float* __restrict__ W,
                                                  const float* __restrict__ bias,
                                                  float* __restrict__ C,
                                                  int M, int N, int K) {
    int n0 = blockIdx.x * 128, m0 = blockIdx.y * 128;
    int tid = threadIdx.x;
    int tx = tid & 15, ty = tid >> 4;
    __shared__ float As[128 * 33], Bs[128 * 33];
    float acc[8][8] = {};
    for (int k0 = 0; k0 < K; k0 += 32) {
#pragma unroll
        for (int i = 0; i < 16; ++i) {
            int idx = tid + 256 * i;      // 0..4095
            int r = idx >> 5, c = idx & 31;
            As[r * 33 + c] = A[(size_t)(m0 + r) * K + k0 + c];
            Bs[r * 33 + c] = W[(size_t)(n0 + r) * K + k0 + c];
        }
        __syncthreads();
#pragma unroll
        for (int kk = 0; kk < 32; ++kk) {
            float a[8], b[8];
#pragma unroll
            for (int i = 0; i < 8; ++i) a[i] = As[(ty * 8 + i) * 33 + kk];
#pragma unroll
            for (int j = 0; j < 8; ++j) b[j] = Bs[(tx * 8 + j) * 33 + kk];
#pragma unroll
            for (int i = 0; i < 8; ++i)
#pragma unroll
                for (int j = 0; j < 8; ++j)
                    acc[i][j] += a[i] * b[j];
        }
        __syncthreads();
    }
#pragma unroll
    for (int i = 0; i < 8; ++i) {
        int m = m0 + ty * 8 + i;
#pragma unroll
        for (int j = 0; j < 8; ++j) {
            int n = n0 + tx * 8 + j;
            float bv = bias ? bias[n] : 0.f;
            C[(size_t)m * N + n] = acc[i][j] + bv;
        }
    }
}

// ---------------- forward DFT over head-dim of x: XH[bhk][u] ----------------
__global__ __launch_bounds__(512) void k_dft_d(const float* __restrict__ X,
                                               float* __restrict__ XH) {
    int r = blockIdx.x;                  // b*1024+u
    int b = r >> 10, u = r & 1023;
    int tid = threadIdx.x;               // 512
    __shared__ float xs[12 * 65], cc[64], ssn[64];
    if (tid < 64) {
        float ang = TWOPI_64 * tid;
        cc[tid] = cosf(ang); ssn[tid] = sinf(ang);
    }
    for (int o = tid; o < 768; o += 512)
        xs[(o >> 6) * 65 + (o & 63)] = X[(size_t)r * 768 + o];
    __syncthreads();
    if (tid < Hn * NK) {
        int h = tid / NK, k = tid - h * NK;
        float re = 0.f, im = 0.f;
#pragma unroll 8
        for (int d = 0; d < 64; ++d) {
            float v = xs[h * 65 + d];
            int j = (k * d) & 63;
            re += v * cc[j];
            im -= v * ssn[j];
        }
        size_t o = (((size_t)(b * Hn + h) * NK + k) * 1024 + u) * 2;
        XH[o] = re; XH[o + 1] = im;
    }
}

// ---------------- inverse DFT over head-dim + exact GELU ----------------
__global__ __launch_bounds__(512) void k_idft_gelu(const float* __restrict__ YH,
                                                   float* __restrict__ G) {
    int r = blockIdx.x;                 // b*1024+s
    int b = r >> 10, s = r & 1023;
    int tid = threadIdx.x;
    __shared__ float Ys[Hn * NK * 2], cc[64], ssn[64];
    if (tid < 64) {
        float ang = TWOPI_64 * tid;
        cc[tid] = cosf(ang); ssn[tid] = sinf(ang);
    }
    if (tid < Hn * NK) {
        size_t o = (((size_t)b * (Hn * NK) + tid) * 1024 + s) * 2;
        Ys[tid * 2] = YH[o]; Ys[tid * 2 + 1] = YH[o + 1];
    }
    __syncthreads();
    for (int o = tid; o < 768; o += 512) {
        int h = o >> 6, d = o & 63;
        const float* Yh = &Ys[(h * NK) * 2];
        float acc = Yh[0];              // k=0 (im contributes 0)
        {
            int j = (32 * d) & 63;
            acc += Yh[32 * 2] * cc[j] - Yh[32 * 2 + 1] * ssn[j];
        }
#pragma unroll 8
        for (int k = 1; k < 32; ++k) {
            int j = (k * d) & 63;
            acc += 2.f * (Yh[k * 2] * cc[j] - Yh[k * 2 + 1] * ssn[j]);
        }
        float conv = acc * (1.0f / 64.0f);
        float g = conv * 0.5f * (1.0f + erff(conv * 0.70710678118f));
        G[(size_t)r * 768 + o] = g;
    }
}

// ---------------- spectral norm pieces ----------------
__global__ __launch_bounds__(1024) void k_sn_v(const float* __restrict__ Wm,
                                               float* __restrict__ v) {
    int j = threadIdx.x;
    float s = 0.f;
    for (int i = 0; i < 1024; ++i) s += Wm[(size_t)i * 1024 + j];
    s *= 0.03125f;                    // 1/sqrt(1024)
    __shared__ float red[1024];
    red[j] = s * s; __syncthreads();
    for (int st = 512; st > 0; st >>= 1) {
        if (j < st) red[j] += red[j + st];
        __syncthreads();
    }
    float nrm = sqrtf(red[0]);
    v[j] = s / (nrm + 1e-12f);
}

__global__ __launch_bounds__(64) void k_sn_u(const float* __restrict__ Wm,
                                             const float* __restrict__ v,
                                             float* __restrict__ ur) {
    int i = blockIdx.x;
    int lane = threadIdx.x;           // 64
    float s = 0.f;
    for (int j = lane; j < 1024; j += 64) s += Wm[(size_t)i * 1024 + j] * v[j];
#pragma unroll
    for (int off = 32; off > 0; off >>= 1) s += __shfl_down(s, off);
    if (lane == 0) ur[i] = s;
}

__global__ __launch_bounds__(1024) void k_sn_sigma(const float* __restrict__ ur,
                                                   float* __restrict__ sig) {
    int i = threadIdx.x;
    __shared__ float red[1024];
    float u = ur[i];
    red[i] = u * u; __syncthreads();
    for (int st = 512; st > 0; st >>= 1) {
        if (i < st) red[i] += red[i + st];
        __syncthreads();
    }
    if (i == 0) {
        float ss = red[0];
        // sigma = u_hat . (W v) = ||u_raw||^2 / (||u_raw|| + eps)
        float sigma = ss / (sqrtf(ss) + 1e-12f);
        sig[0] = 1.0f / sigma;
    }
}

// ---------------- sparse branch: C_b = tril(SP)*invs @ x_b, 128x128 tile ----------------
__global__ __launch_bounds__(256) void k_gemm_sparse(const float* __restrict__ SP,
                                                     const float* __restrict__ X,
                                                     const float* __restrict__ sigbuf,
                                                     float* __restrict__ Cout) {
    int n0 = blockIdx.x * 128, m0 = blockIdx.y * 128, b = blockIdx.z;
    const float invs = sigbuf[0];
    const float* Xb = X + (size_t)b * 1024 * 768;
    float* Cb = Cout + (size_t)b * 1024 * 768;
    int tid = threadIdx.x;
    int tx = tid & 15, ty = tid >> 4;
    __shared__ float As[128 * 33], Bs[32 * 129];
    float acc[8][8] = {};
    int nkt = (m0 >> 5) + 4;          // only t-tiles with t0 <= m0+127
    for (int kt = 0; kt < nkt; ++kt) {
        int k0 = kt * 32;
#pragma unroll
        for (int i = 0; i < 16; ++i) {
            int idx = tid + 256 * i;
            int r = idx >> 5, c = idx & 31;
            int s = m0 + r, t = k0 + c;
            float v = SP[(size_t)s * 1024 + t];
            As[r * 33 + c] = (t <= s) ? v * invs : 0.f;
        }
#pragma unroll
        for (int i = 0; i < 16; ++i) {
            int idx = tid + 256 * i;
            int kr = idx >> 7, c = idx & 127;    // 32 rows x 128 cols
            Bs[kr * 129 + c] = Xb[(size_t)(k0 + kr) * 768 + n0 + c];
        }
        __syncthreads();
#pragma unroll
        for (int kk = 0; kk < 32; ++kk) {
            float a[8], bv[8];
#pragma unroll
            for (int i = 0; i < 8; ++i) a[i] = As[(ty * 8 + i) * 33 + kk];
#pragma unroll
            for (int j = 0; j < 8; ++j) bv[j] = Bs[kk * 129 + tx * 8 + j];
#pragma unroll
            for (int i = 0; i < 8; ++i)
#pragma unroll
                for (int j = 0; j < 8; ++j)
                    acc[i][j] += a[i] * bv[j];
        }
        __syncthreads();
    }
#pragma unroll
    for (int i = 0; i < 8; ++i)
#pragma unroll
        for (int j = 0; j < 8; ++j)
            Cb[(size_t)(m0 + ty * 8 + i) * 768 + n0 + tx * 8 + j] = acc[i][j];
}

// ---------------- final residual + LayerNorm ----------------
__global__ __launch_bounds__(256) void k_final_ln(const float* __restrict__ CE,
                                                  const float* __restrict__ SE,
                                                  const float* __restrict__ EMB,
                                                  const float* __restrict__ g,
                                                  const float* __restrict__ be,
                                                  float* __restrict__ out) {
    int r = blockIdx.x;
    int tid = threadIdx.x;
    float y[3];
    float s = 0.f;
#pragma unroll
    for (int i = 0; i < 3; ++i) {
        int o = tid + i * 256;
        size_t idx = (size_t)r * 768 + o;
        y[i] = CE[idx] + SE[idx] + EMB[idx];
        s += y[i];
    }
    __shared__ float red[256];
    red[tid] = s; __syncthreads();
    for (int st = 128; st > 0; st >>= 1) {
        if (tid < st) red[tid] += red[tid + st];
        __syncthreads();
    }
    float mu = red[0] * (1.f / 768.f);
    __syncthreads();
    float vs = 0.f;
#pragma unroll
    for (int i = 0; i < 3; ++i) { float d = y[i] - mu; vs += d * d; }
    red[tid] = vs; __syncthreads();
    for (int st = 128; st > 0; st >>= 1) {
        if (tid < st) red[tid] += red[tid + st];
        __syncthreads();
    }
    float var = red[0] * (1.f / 768.f);
    float rstd = rsqrtf(var + 1e-12f);
#pragma unroll
    for (int i = 0; i < 3; ++i) {
        int o = tid + i * 256;
        size_t idx = (size_t)r * 768 + o;
        out[idx] = (y[i] - mu) * rstd * g[o] + be[o];
    }
}

extern "C" void kernel_launch(void* const* d_in, const int* in_sizes, int n_in,
                              void* d_out, int out_size, void* d_ws, size_t ws_size,
                              hipStream_t stream) {
    const float* emb     = (const float*)d_in[0];
    const float* pre_w   = (const float*)d_in[1];
    const float* pre_b   = (const float*)d_in[2];
    const float* psfs    = (const float*)d_in[3];
    const float* post_w  = (const float*)d_in[4];
    const float* post_b  = (const float*)d_in[5];
    const float* spmat   = (const float*)d_in[6];
    const float* ln_g    = (const float*)d_in[7];
    const float* ln_b    = (const float*)d_in[8];
    float* out = (float*)d_out;
    float* ws = (float*)d_ws;

    float* p    = ws + O_P;
    float* psfh = ws + O_PSFH;
    float* qh   = ws + O_QH;
    float* q    = ws + O_SIG + 8;         // 768 floats after sigma slot
    float* x    = ws + O_X;
    float* XH   = ws + O_XH;
    float* YH   = ws + O_YH;
    float* spe  = ws + O_SPE;
    float* phf  = ws + O_SPE;             // PHF aliased onto spe (dead before spe is written)
    float* v    = ws + O_V;
    float* urw  = ws + O_UR;
    float* sig  = ws + O_SIG;
    float* G    = XH;    // reuse: XH dead after k_conv_fft
    float* CE   = YH;    // reuse: YH dead after k_idft_gelu

    // PSF preprocessing
    k_psf_softmax<<<Hn * 64, 256, 0, stream>>>(psfs, p, q);
    k_psf_dft<<<Hn * 1024, 64, 0, stream>>>(p, psfh);
    k_q_dft<<<Hn, 64, 0, stream>>>(q, qh);
    k_tap_fft<<<NHK, 256, 0, stream>>>(psfh, qh, phf);

    // pre-projection
    k_gemm_abt<<<dim3(6, 128), 256, 0, stream>>>(emb, pre_w, pre_b, x, Bn * Ln, Dn, Dn);

    // head-dim DFT of x
    k_dft_d<<<Bn * Ln, 512, 0, stream>>>(x, XH);

    // causal conv + uniform suffix term via circular-2048 FFT, per (b,h,k) bin
    k_conv_fft<<<Bn * NHK, 256, 0, stream>>>(XH, phf, YH);

    // inverse DFT + gelu -> G (reuses XH)
    k_idft_gelu<<<Bn * Ln, 512, 0, stream>>>(YH, G);

    // post-projection -> conv_emb (reuses YH)
    k_gemm_abt<<<dim3(6, 128), 256, 0, stream>>>(G, post_w, post_b, CE, Bn * Ln, Dn, Dn);

    // spectral norm scalar
    k_sn_v<<<1, 1024, 0, stream>>>(spmat, v);
    k_sn_u<<<1024, 64, 0, stream>>>(spmat, v, urw);
    k_sn_sigma<<<1, 1024, 0, stream>>>(urw, sig);

    // sparse branch (overwrites phf region — phf is dead by now)
    k_gemm_sparse<<<dim3(6, 8, Bn), 256, 0, stream>>>(spmat, x, sig, spe);

    // residual + LayerNorm
    k_final_ln<<<Bn * Ln, 256, 0, stream>>>(CE, spe, emb, ln_g, ln_b, out);
}

// Round 3
// 629.169 us; speedup vs baseline: 5.0505x; 3.0102x over previous
//
#include <hip/hip_runtime.h>
#include <math.h>

// Problem constants
#define Bn 16
#define Ln 1024
#define Dn 768
#define Hn 12
#define PHDn 64
#define NK 33                 // Hermitian bins for 64-pt DFT (k=0..32)
#define NHK (Hn * NK)         // 396
#define TWOPI_64 0.09817477042468103f   // 2*pi/64

typedef short s16x8 __attribute__((ext_vector_type(8)));
typedef float f32x4 __attribute__((ext_vector_type(4)));
typedef unsigned short u16x4 __attribute__((ext_vector_type(4)));

__device__ __forceinline__ unsigned short f2bf(float f) {
    unsigned int u = __float_as_uint(f);
    unsigned int r = (u + 0x7FFFu + ((u >> 16) & 1u)) >> 16;
    return (unsigned short)r;
}

// ---------------- workspace layout (float offsets) ----------------
static const size_t O_P    = 0;          // psf taps [H][1024][64]; later SPbf (bf16 1024x1024)
static const size_t O_PSFH = 786432;     // psf-hat; later pre_w_bf + post_w_bf
static const size_t O_QH   = 1597440;    // q-hat
static const size_t O_X    = 1598240;    // x = pre-proj [B*L][768] f32
static const size_t O_XH   = 14181152;   // X-hat; later G_bf (first half) + xT_bf (second half)
static const size_t O_YH   = 27157280;   // emb_bf early; Y-hat; later conv_emb (CE f32)
static const size_t O_SPE  = 40146080;   // phf early; sparse_emb later
static const size_t O_V    = 52728992;
static const size_t O_UR   = 52730016;
static const size_t O_SIG  = 52731040;   // inv_sigma + q[768] after

// ---------------- psf softmax over 2047 taps (1023 are zeros) ----------------
__global__ __launch_bounds__(256) void k_psf_softmax(const float* __restrict__ psfs,
                                                     float* __restrict__ p,
                                                     float* __restrict__ q) {
    int he = blockIdx.x;            // h*64+e
    int h = he >> 6, e = he & 63;
    int tid = threadIdx.x;
    float ev[4];
    float s = 0.f;
#pragma unroll
    for (int i = 0; i < 4; ++i) {
        int t = tid + 256 * i;
        float v = psfs[((size_t)h * 2047 + t) * 64 + e];
        ev[i] = expf(v);
        s += ev[i];
    }
    __shared__ float red[256];
    red[tid] = s; __syncthreads();
    for (int st = 128; st > 0; st >>= 1) {
        if (tid < st) red[tid] += red[tid + st];
        __syncthreads();
    }
    float denom = red[0] + 1023.0f;
    float inv = 1.0f / denom;
#pragma unroll
    for (int i = 0; i < 4; ++i) {
        int t = tid + 256 * i;
        p[((size_t)h * 1024 + t) * 64 + e] = ev[i] * inv;
    }
    if (tid == 0) q[he] = inv;
}

// ---------------- DFT over head-dim of psf taps ----------------
__global__ __launch_bounds__(64) void k_psf_dft(const float* __restrict__ p,
                                                float* __restrict__ psfh) {
    int ht = blockIdx.x;            // h*1024+t
    int h = ht >> 10, t = ht & 1023;
    int tid = threadIdx.x;          // 64
    __shared__ float pv[64], cc[64], ssn[64];
    pv[tid] = p[((size_t)h * 1024 + t) * 64 + tid];
    float ang = TWOPI_64 * tid;
    cc[tid] = cosf(ang); ssn[tid] = sinf(ang);
    __syncthreads();
    if (tid < NK) {
        float re = 0.f, im = 0.f;
#pragma unroll 8
        for (int e = 0; e < 64; ++e) {
            int j = (tid * e) & 63;
            float v = pv[e];
            re += v * cc[j];
            im -= v * ssn[j];
        }
        size_t o = (((size_t)h * NK + tid) * 1024 + t) * 2;
        psfh[o] = re; psfh[o + 1] = im;
    }
}

// ---------------- DFT of uniform tap value q[h][e] ----------------
__global__ __launch_bounds__(64) void k_q_dft(const float* __restrict__ q,
                                              float* __restrict__ qh) {
    int h = blockIdx.x;
    int tid = threadIdx.x;
    __shared__ float qv[64], cc[64], ssn[64];
    qv[tid] = q[h * 64 + tid];
    float ang = TWOPI_64 * tid;
    cc[tid] = cosf(ang); ssn[tid] = sinf(ang);
    __syncthreads();
    if (tid < NK) {
        float re = 0.f, im = 0.f;
        for (int e = 0; e < 64; ++e) {
            int j = (tid * e) & 63;
            re += qv[e] * cc[j];
            im -= qv[e] * ssn[j];
        }
        qh[(h * NK + tid) * 2] = re;
        qh[(h * NK + tid) * 2 + 1] = im;
    }
}

// ---------------- 2048-pt radix-2 Stockham FFT stages (ping-pong LDS) ----------------
__device__ __forceinline__ void fft_stages(float2* __restrict__ A,
                                           float2* __restrict__ B,
                                           const float2* __restrict__ tw,
                                           int tid) {
    float2* X = A;
    float2* Y = B;
#pragma unroll 1
    for (int s = 0; s < 11; ++s) {
        int m = 1 << s;
        int mask = ~(m - 1);
#pragma unroll
        for (int it = 0; it < 4; ++it) {
            int i = tid + it * 256;
            float2 c0 = X[i];
            float2 c1 = X[i + 1024];
            float2 w = tw[i & mask];
            float dr = c0.x - c1.x, di = c0.y - c1.y;
            int o0 = i + (i & mask);
            Y[o0] = make_float2(c0.x + c1.x, c0.y + c1.y);
            Y[o0 + m] = make_float2(w.x * dr - w.y * di, w.x * di + w.y * dr);
        }
        __syncthreads();
        float2* t = X; X = Y; Y = t;
    }
}

__device__ __forceinline__ void build_twiddles(float2* tw, int tid) {
#pragma unroll
    for (int it = 0; it < 4; ++it) {
        int j = tid + it * 256;
        float a = (float)j * 3.0679615757712823e-3f;   // 2*pi/2048
        float sv, cv;
        __sincosf(a, &sv, &cv);
        tw[j] = make_float2(cv, -sv);
    }
}

// ---------------- FFT of tap vector per (h,k) ----------------
__global__ __launch_bounds__(256) void k_tap_fft(const float* __restrict__ psfh,
                                                 const float* __restrict__ qh,
                                                 float* __restrict__ phf) {
    __shared__ float2 A[2048], Bf[2048], tw[1024];
    int hk = blockIdx.x, tid = threadIdx.x;
    build_twiddles(tw, tid);
    float2 q = make_float2(qh[hk * 2], qh[hk * 2 + 1]);
    const float2* Pg = (const float2*)(psfh + (size_t)hk * 2048);
#pragma unroll
    for (int it = 0; it < 8; ++it) {
        int t = tid + it * 256;
        float2 v;
        if (t < 1024)       v = Pg[t];
        else if (t == 1024) v = make_float2(0.f, 0.f);
        else                v = q;
        A[t] = v;
    }
    __syncthreads();
    fft_stages(A, Bf, tw, tid);
    float2* out = (float2*)(phf + (size_t)hk * 4096);
#pragma unroll
    for (int it = 0; it < 8; ++it) {
        int t = tid + it * 256;
        out[t] = Bf[t];
    }
}

// ---------------- per-(b,h,k) conv via circular-2048 FFT ----------------
__global__ __launch_bounds__(256) void k_conv_fft(const float* __restrict__ XH,
                                                  const float* __restrict__ PHF,
                                                  float* __restrict__ YH) {
    __shared__ float2 A[2048], Bf[2048], tw[1024];
    int bhk = blockIdx.x, tid = threadIdx.x;
    int hk = bhk % NHK;
    build_twiddles(tw, tid);
    const float2* Xg = (const float2*)(XH + (size_t)bhk * 2048);
#pragma unroll
    for (int it = 0; it < 8; ++it) {
        int t = tid + it * 256;
        A[t] = (t < 1024) ? Xg[t] : make_float2(0.f, 0.f);
    }
    __syncthreads();
    fft_stages(A, Bf, tw, tid);        // X-hat in Bf
    const float2* P = (const float2*)(PHF + (size_t)hk * 4096);
#pragma unroll
    for (int it = 0; it < 8; ++it) {
        int t = tid + it * 256;
        float2 u = Bf[t], pv = P[t];
        float vr = u.x * pv.x - u.y * pv.y;
        float vi = u.x * pv.y + u.y * pv.x;
        A[t] = make_float2(vr, -vi);   // conj for inverse-FFT trick
    }
    __syncthreads();
    fft_stages(A, Bf, tw, tid);
    float2* Yg = (float2*)(YH + (size_t)bhk * 2048);
    const float inv_n = 1.0f / 2048.0f;
#pragma unroll
    for (int it = 0; it < 4; ++it) {
        int s = tid + it * 256;
        float2 r = Bf[s];
        Yg[s] = make_float2(r.x * inv_n, -r.y * inv_n);
    }
}

// ---------------- bf16 MFMA GEMM: C = A(MxK)bf16 @ W(NxK)bf16^T + bias ----------------
// 128x128 tile, BK=32, 4 waves 2x2, XOR slot swizzle (slot ^= (row>>1)&3)
__global__ __launch_bounds__(256) void k_mfma_abt(const unsigned short* __restrict__ A,
                                                  const unsigned short* __restrict__ W,
                                                  const float* __restrict__ bias,
                                                  float* __restrict__ C,
                                                  int M, int N, int K) {
    int n0 = blockIdx.x * 128, m0 = blockIdx.y * 128;
    int tid = threadIdx.x;
    int lane = tid & 63, wave = tid >> 6;
    int wr = wave >> 1, wc = wave & 1;
    __shared__ unsigned short As[4096], Bs[4096];
    f32x4 acc[4][4] = {};
    int r0 = tid >> 2, sl = tid & 3;
    int wof = r0 * 32 + ((sl ^ ((r0 >> 1) & 3)) << 3);
    const unsigned short* gA0 = A + (size_t)(m0 + r0) * K + sl * 8;
    const unsigned short* gB0 = W + (size_t)(n0 + r0) * K + sl * 8;
    size_t rstep = (size_t)64 * K;
    int fra[4], frb[4];
    int kg = lane >> 4, cl = lane & 15;
#pragma unroll
    for (int i = 0; i < 4; ++i) {
        int ra = wr * 64 + i * 16 + cl;
        fra[i] = ra * 32 + ((kg ^ ((ra >> 1) & 3)) << 3);
        int rb = wc * 64 + i * 16 + cl;
        frb[i] = rb * 32 + ((kg ^ ((rb >> 1) & 3)) << 3);
    }
    int nkt = K >> 5;
    s16x8 a0 = *(const s16x8*)(gA0);
    s16x8 a1 = *(const s16x8*)(gA0 + rstep);
    s16x8 b0 = *(const s16x8*)(gB0);
    s16x8 b1 = *(const s16x8*)(gB0 + rstep);
    for (int kt = 0; kt < nkt; ++kt) {
        __syncthreads();
        *(s16x8*)&As[wof] = a0;
        *(s16x8*)&As[wof + 2048] = a1;
        *(s16x8*)&Bs[wof] = b0;
        *(s16x8*)&Bs[wof + 2048] = b1;
        __syncthreads();
        if (kt + 1 < nkt) {
            int ko = (kt + 1) << 5;
            a0 = *(const s16x8*)(gA0 + ko);
            a1 = *(const s16x8*)(gA0 + rstep + ko);
            b0 = *(const s16x8*)(gB0 + ko);
            b1 = *(const s16x8*)(gB0 + rstep + ko);
        }
        s16x8 af[4], bfr[4];
#pragma unroll
        for (int i = 0; i < 4; ++i) af[i] = *(const s16x8*)&As[fra[i]];
#pragma unroll
        for (int i = 0; i < 4; ++i) bfr[i] = *(const s16x8*)&Bs[frb[i]];
#pragma unroll
        for (int mi = 0; mi < 4; ++mi)
#pragma unroll
            for (int ni = 0; ni < 4; ++ni)
                acc[mi][ni] = __builtin_amdgcn_mfma_f32_16x16x32_bf16(af[mi], bfr[ni], acc[mi][ni], 0, 0, 0);
    }
    int rg = lane >> 4;
#pragma unroll
    for (int ni = 0; ni < 4; ++ni) {
        int gn = n0 + wc * 64 + ni * 16 + cl;
        float bv = bias ? bias[gn] : 0.f;
#pragma unroll
        for (int mi = 0; mi < 4; ++mi) {
            int gm = m0 + wr * 64 + mi * 16 + rg * 4;
            f32x4 v = acc[mi][ni];
#pragma unroll
            for (int ri = 0; ri < 4; ++ri)
                C[(size_t)(gm + ri) * N + gn] = v[ri] + bv;
        }
    }
}

// ---------------- sparse: C_b = (tril(SP)/sigma) @ x_b via xT bf16, MFMA ----------------
__global__ __launch_bounds__(256) void k_mfma_sparse(const unsigned short* __restrict__ SP,
                                                     const unsigned short* __restrict__ XT,
                                                     const float* __restrict__ sigbuf,
                                                     float* __restrict__ C) {
    int bx = blockIdx.x;
    int mt = bx & 7, nt = (bx >> 3) % 6, b = bx / 48;
    int m0 = mt * 128, n0 = nt * 128;
    const unsigned short* Xb = XT + (size_t)b * Dn * Ln;
    float* Cb = C + (size_t)b * Ln * Dn;
    int tid = threadIdx.x;
    int lane = tid & 63, wave = tid >> 6;
    int wr = wave >> 1, wc = wave & 1;
    __shared__ unsigned short As[4096], Bs[4096];
    f32x4 acc[4][4] = {};
    int r0 = tid >> 2, sl = tid & 3;
    int wof = r0 * 32 + ((sl ^ ((r0 >> 1) & 3)) << 3);
    const unsigned short* gA0 = SP + (size_t)(m0 + r0) * Ln + sl * 8;
    const unsigned short* gB0 = Xb + (size_t)(n0 + r0) * Ln + sl * 8;
    size_t rstep = (size_t)64 * Ln;
    int fra[4], frb[4];
    int kg = lane >> 4, cl = lane & 15;
#pragma unroll
    for (int i = 0; i < 4; ++i) {
        int ra = wr * 64 + i * 16 + cl;
        fra[i] = ra * 32 + ((kg ^ ((ra >> 1) & 3)) << 3);
        int rb = wc * 64 + i * 16 + cl;
        frb[i] = rb * 32 + ((kg ^ ((rb >> 1) & 3)) << 3);
    }
    int nkt = mt * 4 + 4;             // only k-tiles with t0 <= m0+127 (tril)
    s16x8 a0 = *(const s16x8*)(gA0);
    s16x8 a1 = *(const s16x8*)(gA0 + rstep);
    s16x8 b0 = *(const s16x8*)(gB0);
    s16x8 b1 = *(const s16x8*)(gB0 + rstep);
    for (int kt = 0; kt < nkt; ++kt) {
        __syncthreads();
        *(s16x8*)&As[wof] = a0;
        *(s16x8*)&As[wof + 2048] = a1;
        *(s16x8*)&Bs[wof] = b0;
        *(s16x8*)&Bs[wof + 2048] = b1;
        __syncthreads();
        if (kt + 1 < nkt) {
            int ko = (kt + 1) << 5;
            a0 = *(const s16x8*)(gA0 + ko);
            a1 = *(const s16x8*)(gA0 + rstep + ko);
            b0 = *(const s16x8*)(gB0 + ko);
            b1 = *(const s16x8*)(gB0 + rstep + ko);
        }
        s16x8 af[4], bfr[4];
#pragma unroll
        for (int i = 0; i < 4; ++i) af[i] = *(const s16x8*)&As[fra[i]];
#pragma unroll
        for (int i = 0; i < 4; ++i) bfr[i] = *(const s16x8*)&Bs[frb[i]];
#pragma unroll
        for (int mi = 0; mi < 4; ++mi)
#pragma unroll
            for (int ni = 0; ni < 4; ++ni)
                acc[mi][ni] = __builtin_amdgcn_mfma_f32_16x16x32_bf16(af[mi], bfr[ni], acc[mi][ni], 0, 0, 0);
    }
    float invs = sigbuf[0];
    int rg = lane >> 4;
#pragma unroll
    for (int ni = 0; ni < 4; ++ni) {
        int gn = n0 + wc * 64 + ni * 16 + cl;
#pragma unroll
        for (int mi = 0; mi < 4; ++mi) {
            int gm = m0 + wr * 64 + mi * 16 + rg * 4;
            f32x4 v = acc[mi][ni];
#pragma unroll
            for (int ri = 0; ri < 4; ++ri)
                Cb[(size_t)(gm + ri) * Dn + gn] = v[ri] * invs;
        }
    }
}

// ---------------- conversions ----------------
__global__ __launch_bounds__(256) void k_cvt_bf16(const float* __restrict__ in,
                                                  unsigned short* __restrict__ out, int n4) {
    int i = blockIdx.x * 256 + threadIdx.x;
    if (i < n4) {
        float4 v = ((const float4*)in)[i];
        u16x4 o;
        o[0] = f2bf(v.x); o[1] = f2bf(v.y); o[2] = f2bf(v.z); o[3] = f2bf(v.w);
        *(u16x4*)&out[(size_t)i * 4] = o;
    }
}

__global__ __launch_bounds__(256) void k_cvt_sp(const float* __restrict__ SP,
                                                unsigned short* __restrict__ O) {
    int s = blockIdx.x;
    int t0 = threadIdx.x * 4;
    float4 v = *(const float4*)&SP[(size_t)s * 1024 + t0];
    u16x4 o;
    o[0] = (t0 + 0 <= s) ? f2bf(v.x) : 0;
    o[1] = (t0 + 1 <= s) ? f2bf(v.y) : 0;
    o[2] = (t0 + 2 <= s) ? f2bf(v.z) : 0;
    o[3] = (t0 + 3 <= s) ? f2bf(v.w) : 0;
    *(u16x4*)&O[(size_t)s * 1024 + t0] = o;
}

// ---------------- x[b][t][d] f32 -> xT[b][d][t] bf16, 64x64 LDS tile ----------------
__global__ __launch_bounds__(256) void k_transpose_x(const float* __restrict__ X,
                                                     unsigned short* __restrict__ XT) {
    int d0 = blockIdx.x * 64, t0 = blockIdx.y * 64, b = blockIdx.z;
    const float* Xb = X + (size_t)b * Ln * Dn;
    unsigned short* Tb = XT + (size_t)b * Dn * Ln;
    __shared__ float tile[64][65];
    int tx = threadIdx.x & 63, ty = threadIdx.x >> 6;
#pragma unroll
    for (int i = 0; i < 16; ++i) {
        int t = ty + i * 4;
        tile[t][tx] = Xb[(size_t)(t0 + t) * Dn + d0 + tx];
    }
    __syncthreads();
#pragma unroll
    for (int i = 0; i < 16; ++i) {
        int d = ty + i * 4;
        Tb[(size_t)(d0 + d) * Ln + t0 + tx] = f2bf(tile[tx][d]);
    }
}

// ---------------- forward DFT over head-dim of x ----------------
__global__ __launch_bounds__(512) void k_dft_d(const float* __restrict__ X,
                                               float* __restrict__ XH) {
    int r = blockIdx.x;                  // b*1024+u
    int b = r >> 10, u = r & 1023;
    int tid = threadIdx.x;               // 512
    __shared__ float xs[12 * 65], cc[64], ssn[64];
    if (tid < 64) {
        float ang = TWOPI_64 * tid;
        cc[tid] = cosf(ang); ssn[tid] = sinf(ang);
    }
    for (int o = tid; o < 768; o += 512)
        xs[(o >> 6) * 65 + (o & 63)] = X[(size_t)r * 768 + o];
    __syncthreads();
    if (tid < Hn * NK) {
        int h = tid / NK, k = tid - h * NK;
        float re = 0.f, im = 0.f;
#pragma unroll 8
        for (int d = 0; d < 64; ++d) {
            float v = xs[h * 65 + d];
            int j = (k * d) & 63;
            re += v * cc[j];
            im -= v * ssn[j];
        }
        size_t o = (((size_t)(b * Hn + h) * NK + k) * 1024 + u) * 2;
        XH[o] = re; XH[o + 1] = im;
    }
}

// ---------------- inverse DFT over head-dim + exact GELU -> bf16 ----------------
__global__ __launch_bounds__(512) void k_idft_gelu(const float* __restrict__ YH,
                                                   unsigned short* __restrict__ G) {
    int r = blockIdx.x;                 // b*1024+s
    int b = r >> 10, s = r & 1023;
    int tid = threadIdx.x;
    __shared__ float Ys[Hn * NK * 2], cc[64], ssn[64];
    if (tid < 64) {
        float ang = TWOPI_64 * tid;
        cc[tid] = cosf(ang); ssn[tid] = sinf(ang);
    }
    if (tid < Hn * NK) {
        size_t o = (((size_t)b * (Hn * NK) + tid) * 1024 + s) * 2;
        Ys[tid * 2] = YH[o]; Ys[tid * 2 + 1] = YH[o + 1];
    }
    __syncthreads();
    for (int o = tid; o < 768; o += 512) {
        int h = o >> 6, d = o & 63;
        const float* Yh = &Ys[(h * NK) * 2];
        float acc = Yh[0];
        {
            int j = (32 * d) & 63;
            acc += Yh[32 * 2] * cc[j] - Yh[32 * 2 + 1] * ssn[j];
        }
#pragma unroll 8
        for (int k = 1; k < 32; ++k) {
            int j = (k * d) & 63;
            acc += 2.f * (Yh[k * 2] * cc[j] - Yh[k * 2 + 1] * ssn[j]);
        }
        float conv = acc * (1.0f / 64.0f);
        float g = conv * 0.5f * (1.0f + erff(conv * 0.70710678118f));
        G[(size_t)r * 768 + o] = f2bf(g);
    }
}

// ---------------- spectral norm pieces ----------------
__global__ __launch_bounds__(1024) void k_sn_v(const float* __restrict__ Wm,
                                               float* __restrict__ v) {
    int j = threadIdx.x;
    float s = 0.f;
    for (int i = 0; i < 1024; ++i) s += Wm[(size_t)i * 1024 + j];
    s *= 0.03125f;
    __shared__ float red[1024];
    red[j] = s * s; __syncthreads();
    for (int st = 512; st > 0; st >>= 1) {
        if (j < st) red[j] += red[j + st];
        __syncthreads();
    }
    float nrm = sqrtf(red[0]);
    v[j] = s / (nrm + 1e-12f);
}

__global__ __launch_bounds__(64) void k_sn_u(const float* __restrict__ Wm,
                                             const float* __restrict__ v,
                                             float* __restrict__ ur) {
    int i = blockIdx.x;
    int lane = threadIdx.x;
    float s = 0.f;
    for (int j = lane; j < 1024; j += 64) s += Wm[(size_t)i * 1024 + j] * v[j];
#pragma unroll
    for (int off = 32; off > 0; off >>= 1) s += __shfl_down(s, off);
    if (lane == 0) ur[i] = s;
}

__global__ __launch_bounds__(1024) void k_sn_sigma(const float* __restrict__ ur,
                                                   float* __restrict__ sig) {
    int i = threadIdx.x;
    __shared__ float red[1024];
    float u = ur[i];
    red[i] = u * u; __syncthreads();
    for (int st = 512; st > 0; st >>= 1) {
        if (i < st) red[i] += red[i + st];
        __syncthreads();
    }
    if (i == 0) {
        float ss = red[0];
        float sigma = ss / (sqrtf(ss) + 1e-12f);
        sig[0] = 1.0f / sigma;
    }
}

// ---------------- final residual + LayerNorm ----------------
__global__ __launch_bounds__(256) void k_final_ln(const float* __restrict__ CE,
                                                  const float* __restrict__ SE,
                                                  const float* __restrict__ EMB,
                                                  const float* __restrict__ g,
                                                  const float* __restrict__ be,
                                                  float* __restrict__ out) {
    int r = blockIdx.x;
    int tid = threadIdx.x;
    float y[3];
    float s = 0.f;
#pragma unroll
    for (int i = 0; i < 3; ++i) {
        int o = tid + i * 256;
        size_t idx = (size_t)r * 768 + o;
        y[i] = CE[idx] + SE[idx] + EMB[idx];
        s += y[i];
    }
    __shared__ float red[256];
    red[tid] = s; __syncthreads();
    for (int st = 128; st > 0; st >>= 1) {
        if (tid < st) red[tid] += red[tid + st];
        __syncthreads();
    }
    float mu = red[0] * (1.f / 768.f);
    __syncthreads();
    float vs = 0.f;
#pragma unroll
    for (int i = 0; i < 3; ++i) { float d = y[i] - mu; vs += d * d; }
    red[tid] = vs; __syncthreads();
    for (int st = 128; st > 0; st >>= 1) {
        if (tid < st) red[tid] += red[tid + st];
        __syncthreads();
    }
    float var = red[0] * (1.f / 768.f);
    float rstd = rsqrtf(var + 1e-12f);
#pragma unroll
    for (int i = 0; i < 3; ++i) {
        int o = tid + i * 256;
        size_t idx = (size_t)r * 768 + o;
        out[idx] = (y[i] - mu) * rstd * g[o] + be[o];
    }
}

extern "C" void kernel_launch(void* const* d_in, const int* in_sizes, int n_in,
                              void* d_out, int out_size, void* d_ws, size_t ws_size,
                              hipStream_t stream) {
    const float* emb     = (const float*)d_in[0];
    const float* pre_w   = (const float*)d_in[1];
    const float* pre_b   = (const float*)d_in[2];
    const float* psfs    = (const float*)d_in[3];
    const float* post_w  = (const float*)d_in[4];
    const float* post_b  = (const float*)d_in[5];
    const float* spmat   = (const float*)d_in[6];
    const float* ln_g    = (const float*)d_in[7];
    const float* ln_b    = (const float*)d_in[8];
    float* out = (float*)d_out;
    float* ws = (float*)d_ws;

    float* p      = ws + O_P;
    float* psfh   = ws + O_PSFH;
    float* qh     = ws + O_QH;
    float* q      = ws + O_SIG + 8;
    float* x      = ws + O_X;
    float* XH     = ws + O_XH;
    float* YH     = ws + O_YH;
    float* spe    = ws + O_SPE;
    float* phf    = ws + O_SPE;                      // alias (dead before spe)
    float* v      = ws + O_V;
    float* urw    = ws + O_UR;
    float* sig    = ws + O_SIG;
    float* CE     = ws + O_YH;                       // post-GEMM output (YH dead)
    unsigned short* emb_bf   = (unsigned short*)(ws + O_YH);          // dead before YH written
    unsigned short* G_bf     = (unsigned short*)(ws + O_XH);          // XH dead after conv
    unsigned short* xT_bf    = (unsigned short*)(ws + O_XH + 6400000);
    unsigned short* SP_bf    = (unsigned short*)(ws + O_P);           // p dead after psf_dft
    unsigned short* pre_w_bf = (unsigned short*)(ws + O_PSFH);        // psfh dead after tap_fft
    unsigned short* post_w_bf= (unsigned short*)(ws + O_PSFH + 294912);

    // PSF preprocessing
    k_psf_softmax<<<Hn * 64, 256, 0, stream>>>(psfs, p, q);
    k_psf_dft<<<Hn * 1024, 64, 0, stream>>>(p, psfh);
    k_q_dft<<<Hn, 64, 0, stream>>>(q, qh);
    k_tap_fft<<<NHK, 256, 0, stream>>>(psfh, qh, phf);

    // spectral norm scalar
    k_sn_v<<<1, 1024, 0, stream>>>(spmat, v);
    k_sn_u<<<1024, 64, 0, stream>>>(spmat, v, urw);
    k_sn_sigma<<<1, 1024, 0, stream>>>(urw, sig);

    // conversions (after their aliased regions are dead)
    k_cvt_sp<<<1024, 256, 0, stream>>>(spmat, SP_bf);
    k_cvt_bf16<<<576, 256, 0, stream>>>(pre_w, pre_w_bf, 147456);
    k_cvt_bf16<<<576, 256, 0, stream>>>(post_w, post_w_bf, 147456);
    k_cvt_bf16<<<12288, 256, 0, stream>>>(emb, emb_bf, 3145728);

    // pre-projection (MFMA bf16)
    k_mfma_abt<<<dim3(6, 128), 256, 0, stream>>>(emb_bf, pre_w_bf, pre_b, x, Bn * Ln, Dn, Dn);

    // head-dim DFT of x
    k_dft_d<<<Bn * Ln, 512, 0, stream>>>(x, XH);

    // causal conv + uniform suffix via circular-2048 FFT
    k_conv_fft<<<Bn * NHK, 256, 0, stream>>>(XH, phf, YH);

    // inverse DFT + gelu -> G_bf (reuses XH region)
    k_idft_gelu<<<Bn * Ln, 512, 0, stream>>>(YH, G_bf);

    // transpose x -> xT bf16 (second half of XH region)
    k_transpose_x<<<dim3(12, 16, Bn), 256, 0, stream>>>(x, xT_bf);

    // post-projection (MFMA bf16) -> CE (reuses YH region)
    k_mfma_abt<<<dim3(6, 128), 256, 0, stream>>>(G_bf, post_w_bf, post_b, CE, Bn * Ln, Dn, Dn);

    // sparse branch (MFMA bf16, triangular k-loop, m-fastest for balance)
    k_mfma_sparse<<<768, 256, 0, stream>>>(SP_bf, xT_bf, sig, spe);

    // residual + LayerNorm
    k_final_ln<<<Bn * Ln, 256, 0, stream>>>(CE, spe, emb, ln_g, ln_b, out);
}

// Round 5
// 502.580 us; speedup vs baseline: 6.3226x; 1.2519x over previous
//
#include <hip/hip_runtime.h>
#include <math.h>

// Problem constants
#define Bn 16
#define Ln 1024
#define Dn 768
#define Hn 12
#define PHDn 64
#define NK 33                 // Hermitian bins for 64-pt DFT (k=0..32)
#define NHK (Hn * NK)         // 396
#define TWOPI_64 0.09817477042468103f   // 2*pi/64

typedef short s16x8 __attribute__((ext_vector_type(8)));
typedef float f32x4 __attribute__((ext_vector_type(4)));
typedef unsigned short u16x4 __attribute__((ext_vector_type(4)));

__device__ __forceinline__ unsigned short f2bf(float f) {
    unsigned int u = __float_as_uint(f);
    unsigned int r = (u + 0x7FFFu + ((u >> 16) & 1u)) >> 16;
    return (unsigned short)r;
}

// ---------------- workspace layout (float offsets) ----------------
static const size_t O_P    = 0;          // psf taps; later SP_bf
static const size_t O_PSFH = 786432;     // psf-hat; later pre_w_bf + post_w_bf
static const size_t O_QH   = 1597440;    // q-hat
static const size_t O_X    = 1598240;    // x_bf (6291456) + Wbig (344064) + Wi (307200)
static const size_t O_XH   = 14181152;   // XHre/XHim planes; later YT + G_bf; later xT_bf
static const size_t O_YH   = 27157280;   // emb_bf early; YHre/YHim planes; later CE f32
static const size_t O_SPE  = 40146080;   // phf early; sparse_emb later
static const size_t O_V    = 52728992;
static const size_t O_UR   = 52730016;
static const size_t O_SIG  = 52731040;   // inv_sigma + q[768] after

// ---------------- psf softmax over 2047 taps (1023 are zeros) ----------------
__global__ __launch_bounds__(256) void k_psf_softmax(const float* __restrict__ psfs,
                                                     float* __restrict__ p,
                                                     float* __restrict__ q) {
    int he = blockIdx.x;            // h*64+e
    int h = he >> 6, e = he & 63;
    int tid = threadIdx.x;
    float ev[4];
    float s = 0.f;
#pragma unroll
    for (int i = 0; i < 4; ++i) {
        int t = tid + 256 * i;
        float v = psfs[((size_t)h * 2047 + t) * 64 + e];
        ev[i] = expf(v);
        s += ev[i];
    }
    __shared__ float red[256];
    red[tid] = s; __syncthreads();
    for (int st = 128; st > 0; st >>= 1) {
        if (tid < st) red[tid] += red[tid + st];
        __syncthreads();
    }
    float denom = red[0] + 1023.0f;
    float inv = 1.0f / denom;
#pragma unroll
    for (int i = 0; i < 4; ++i) {
        int t = tid + 256 * i;
        p[((size_t)h * 1024 + t) * 64 + e] = ev[i] * inv;
    }
    if (tid == 0) q[he] = inv;
}

// ---------------- DFT over head-dim of psf taps ----------------
__global__ __launch_bounds__(64) void k_psf_dft(const float* __restrict__ p,
                                                float* __restrict__ psfh) {
    int ht = blockIdx.x;            // h*1024+t
    int h = ht >> 10, t = ht & 1023;
    int tid = threadIdx.x;          // 64
    __shared__ float pv[64], cc[64], ssn[64];
    pv[tid] = p[((size_t)h * 1024 + t) * 64 + tid];
    float ang = TWOPI_64 * tid;
    cc[tid] = cosf(ang); ssn[tid] = sinf(ang);
    __syncthreads();
    if (tid < NK) {
        float re = 0.f, im = 0.f;
#pragma unroll 8
        for (int e = 0; e < 64; ++e) {
            int j = (tid * e) & 63;
            float v = pv[e];
            re += v * cc[j];
            im -= v * ssn[j];
        }
        size_t o = (((size_t)h * NK + tid) * 1024 + t) * 2;
        psfh[o] = re; psfh[o + 1] = im;
    }
}

// ---------------- DFT of uniform tap value q[h][e] ----------------
__global__ __launch_bounds__(64) void k_q_dft(const float* __restrict__ q,
                                              float* __restrict__ qh) {
    int h = blockIdx.x;
    int tid = threadIdx.x;
    __shared__ float qv[64], cc[64], ssn[64];
    qv[tid] = q[h * 64 + tid];
    float ang = TWOPI_64 * tid;
    cc[tid] = cosf(ang); ssn[tid] = sinf(ang);
    __syncthreads();
    if (tid < NK) {
        float re = 0.f, im = 0.f;
        for (int e = 0; e < 64; ++e) {
            int j = (tid * e) & 63;
            re += qv[e] * cc[j];
            im -= qv[e] * ssn[j];
        }
        qh[(h * NK + tid) * 2] = re;
        qh[(h * NK + tid) * 2 + 1] = im;
    }
}

// ---------------- 2048-pt radix-2 Stockham FFT stages (ping-pong LDS) ----------------
__device__ __forceinline__ void fft_stages(float2* __restrict__ A,
                                           float2* __restrict__ B,
                                           const float2* __restrict__ tw,
                                           int tid) {
    float2* X = A;
    float2* Y = B;
#pragma unroll 1
    for (int s = 0; s < 11; ++s) {
        int m = 1 << s;
        int mask = ~(m - 1);
#pragma unroll
        for (int it = 0; it < 4; ++it) {
            int i = tid + it * 256;
            float2 c0 = X[i];
            float2 c1 = X[i + 1024];
            float2 w = tw[i & mask];
            float dr = c0.x - c1.x, di = c0.y - c1.y;
            int o0 = i + (i & mask);
            Y[o0] = make_float2(c0.x + c1.x, c0.y + c1.y);
            Y[o0 + m] = make_float2(w.x * dr - w.y * di, w.x * di + w.y * dr);
        }
        __syncthreads();
        float2* t = X; X = Y; Y = t;
    }
}

__device__ __forceinline__ void build_twiddles(float2* tw, int tid) {
#pragma unroll
    for (int it = 0; it < 4; ++it) {
        int j = tid + it * 256;
        float a = (float)j * 3.0679615757712823e-3f;   // 2*pi/2048
        float sv, cv;
        __sincosf(a, &sv, &cv);
        tw[j] = make_float2(cv, -sv);
    }
}

// ---------------- FFT of tap vector per (h,k) ----------------
__global__ __launch_bounds__(256) void k_tap_fft(const float* __restrict__ psfh,
                                                 const float* __restrict__ qh,
                                                 float* __restrict__ phf) {
    __shared__ float2 A[2048], Bf[2048], tw[1024];
    int hk = blockIdx.x, tid = threadIdx.x;
    build_twiddles(tw, tid);
    float2 q = make_float2(qh[hk * 2], qh[hk * 2 + 1]);
    const float2* Pg = (const float2*)(psfh + (size_t)hk * 2048);
#pragma unroll
    for (int it = 0; it < 8; ++it) {
        int t = tid + it * 256;
        float2 v;
        if (t < 1024)       v = Pg[t];
        else if (t == 1024) v = make_float2(0.f, 0.f);
        else                v = q;
        A[t] = v;
    }
    __syncthreads();
    fft_stages(A, Bf, tw, tid);
    float2* out = (float2*)(phf + (size_t)hk * 4096);
#pragma unroll
    for (int it = 0; it < 8; ++it) {
        int t = tid + it * 256;
        out[t] = Bf[t];
    }
}

// ---------------- per-(b,h,k) conv via circular-2048 FFT (split re/im planes) ----------------
__global__ __launch_bounds__(256) void k_conv_fft(const float* __restrict__ XHre,
                                                  const float* __restrict__ XHim,
                                                  const float* __restrict__ PHF,
                                                  float* __restrict__ YHre,
                                                  float* __restrict__ YHim) {
    __shared__ float2 A[2048], Bf[2048], tw[1024];
    int bhk = blockIdx.x, tid = threadIdx.x;
    int hk = bhk % NHK;
    build_twiddles(tw, tid);
    const float* Rg = XHre + (size_t)bhk * 1024;
    const float* Ig = XHim + (size_t)bhk * 1024;
#pragma unroll
    for (int it = 0; it < 8; ++it) {
        int t = tid + it * 256;
        A[t] = (t < 1024) ? make_float2(Rg[t], Ig[t]) : make_float2(0.f, 0.f);
    }
    __syncthreads();
    fft_stages(A, Bf, tw, tid);        // X-hat in Bf
    const float2* P = (const float2*)(PHF + (size_t)hk * 4096);
#pragma unroll
    for (int it = 0; it < 8; ++it) {
        int t = tid + it * 256;
        float2 u = Bf[t], pv = P[t];
        float vr = u.x * pv.x - u.y * pv.y;
        float vi = u.x * pv.y + u.y * pv.x;
        A[t] = make_float2(vr, -vi);   // conj for inverse-FFT trick
    }
    __syncthreads();
    fft_stages(A, Bf, tw, tid);
    const float inv_n = 1.0f / 2048.0f;
#pragma unroll
    for (int it = 0; it < 4; ++it) {
        int s = tid + it * 256;
        float2 r = Bf[s];
        YHre[(size_t)bhk * 1024 + s] = r.x * inv_n;
        YHim[(size_t)bhk * 1024 + s] = -r.y * inv_n;
    }
}

// ---------------- build block-diagonal forward DFT matrix Wbig [896][768] bf16 ----------------
__global__ __launch_bounds__(256) void k_build_wbig(unsigned short* __restrict__ W) {
    int m = blockIdx.x;                  // 0..895
    int tid = threadIdx.x;
    int h = m / 66, rem = m - h * 66;
    int k = rem >> 1, od = rem & 1;
    bool valid = (m < 792);
#pragma unroll
    for (int i = 0; i < 3; ++i) {
        int d = tid + i * 256;
        int dh = d >> 6, dd = d & 63;
        float val = 0.f;
        if (valid && dh == h) {
            int j = (k * dd) & 63;
            float ang = TWOPI_64 * (float)j;
            val = od ? -sinf(ang) : cosf(ang);
        }
        W[(size_t)m * 768 + d] = f2bf(val);
    }
}

// ---------------- build inverse DFT matrix Wi [768][800] bf16 (1/64 + Hermitian 2x folded) ----------------
__global__ __launch_bounds__(256) void k_build_wi(unsigned short* __restrict__ W) {
    int hd = blockIdx.x;                 // 0..767
    int tid = threadIdx.x;
    int h = hd >> 6, d = hd & 63;
#pragma unroll
    for (int i = 0; i < 4; ++i) {
        int col = tid + i * 256;
        if (col < 800) {
            float val = 0.f;
            if (col < 792) {
                int h2 = col / 66, rem = col - h2 * 66;
                int k = rem >> 1, od = rem & 1;
                if (h2 == h) {
                    int j = (k * d) & 63;
                    float ang = TWOPI_64 * (float)j;
                    float ck = ((k == 0) || (k == 32)) ? (1.f / 64.f) : (2.f / 64.f);
                    val = od ? -sinf(ang) * ck : cosf(ang) * ck;
                }
            }
            W[(size_t)hd * 800 + col] = f2bf(val);
        }
    }
}

// ---------------- bf16 MFMA GEMM: C(f32) = A@W^T + bias ----------------
__global__ __launch_bounds__(256) void k_mfma_abt(const unsigned short* __restrict__ A,
                                                  const unsigned short* __restrict__ W,
                                                  const float* __restrict__ bias,
                                                  float* __restrict__ C,
                                                  int M, int N, int K) {
    int n0 = blockIdx.x * 128, m0 = blockIdx.y * 128;
    int tid = threadIdx.x;
    int lane = tid & 63, wave = tid >> 6;
    int wr = wave >> 1, wc = wave & 1;
    __shared__ unsigned short As[4096], Bs[4096];
    f32x4 acc[4][4] = {};
    int r0 = tid >> 2, sl = tid & 3;
    int wof = r0 * 32 + ((sl ^ ((r0 >> 1) & 3)) << 3);
    const unsigned short* gA0 = A + (size_t)(m0 + r0) * K + sl * 8;
    const unsigned short* gB0 = W + (size_t)(n0 + r0) * K + sl * 8;
    size_t rstep = (size_t)64 * K;
    int fra[4], frb[4];
    int kg = lane >> 4, cl = lane & 15;
#pragma unroll
    for (int i = 0; i < 4; ++i) {
        int ra = wr * 64 + i * 16 + cl;
        fra[i] = ra * 32 + ((kg ^ ((ra >> 1) & 3)) << 3);
        int rb = wc * 64 + i * 16 + cl;
        frb[i] = rb * 32 + ((kg ^ ((rb >> 1) & 3)) << 3);
    }
    int nkt = K >> 5;
    s16x8 a0 = *(const s16x8*)(gA0);
    s16x8 a1 = *(const s16x8*)(gA0 + rstep);
    s16x8 b0 = *(const s16x8*)(gB0);
    s16x8 b1 = *(const s16x8*)(gB0 + rstep);
    for (int kt = 0; kt < nkt; ++kt) {
        __syncthreads();
        *(s16x8*)&As[wof] = a0;
        *(s16x8*)&As[wof + 2048] = a1;
        *(s16x8*)&Bs[wof] = b0;
        *(s16x8*)&Bs[wof + 2048] = b1;
        __syncthreads();
        if (kt + 1 < nkt) {
            int ko = (kt + 1) << 5;
            a0 = *(const s16x8*)(gA0 + ko);
            a1 = *(const s16x8*)(gA0 + rstep + ko);
            b0 = *(const s16x8*)(gB0 + ko);
            b1 = *(const s16x8*)(gB0 + rstep + ko);
        }
        s16x8 af[4], bfr[4];
#pragma unroll
        for (int i = 0; i < 4; ++i) af[i] = *(const s16x8*)&As[fra[i]];
#pragma unroll
        for (int i = 0; i < 4; ++i) bfr[i] = *(const s16x8*)&Bs[frb[i]];
#pragma unroll
        for (int mi = 0; mi < 4; ++mi)
#pragma unroll
            for (int ni = 0; ni < 4; ++ni)
                acc[mi][ni] = __builtin_amdgcn_mfma_f32_16x16x32_bf16(af[mi], bfr[ni], acc[mi][ni], 0, 0, 0);
    }
    int rg = lane >> 4;
#pragma unroll
    for (int ni = 0; ni < 4; ++ni) {
        int gn = n0 + wc * 64 + ni * 16 + cl;
        float bv = bias ? bias[gn] : 0.f;
#pragma unroll
        for (int mi = 0; mi < 4; ++mi) {
            int gm = m0 + wr * 64 + mi * 16 + rg * 4;
            f32x4 v = acc[mi][ni];
#pragma unroll
            for (int ri = 0; ri < 4; ++ri)
                C[(size_t)(gm + ri) * N + gn] = v[ri] + bv;
        }
    }
}

// ---------------- bf16 MFMA GEMM with bf16 output (pre-projection) ----------------
__global__ __launch_bounds__(256) void k_mfma_abt_bf(const unsigned short* __restrict__ A,
                                                     const unsigned short* __restrict__ W,
                                                     const float* __restrict__ bias,
                                                     unsigned short* __restrict__ C,
                                                     int M, int N, int K) {
    int n0 = blockIdx.x * 128, m0 = blockIdx.y * 128;
    int tid = threadIdx.x;
    int lane = tid & 63, wave = tid >> 6;
    int wr = wave >> 1, wc = wave & 1;
    __shared__ unsigned short As[4096], Bs[4096];
    f32x4 acc[4][4] = {};
    int r0 = tid >> 2, sl = tid & 3;
    int wof = r0 * 32 + ((sl ^ ((r0 >> 1) & 3)) << 3);
    const unsigned short* gA0 = A + (size_t)(m0 + r0) * K + sl * 8;
    const unsigned short* gB0 = W + (size_t)(n0 + r0) * K + sl * 8;
    size_t rstep = (size_t)64 * K;
    int fra[4], frb[4];
    int kg = lane >> 4, cl = lane & 15;
#pragma unroll
    for (int i = 0; i < 4; ++i) {
        int ra = wr * 64 + i * 16 + cl;
        fra[i] = ra * 32 + ((kg ^ ((ra >> 1) & 3)) << 3);
        int rb = wc * 64 + i * 16 + cl;
        frb[i] = rb * 32 + ((kg ^ ((rb >> 1) & 3)) << 3);
    }
    int nkt = K >> 5;
    s16x8 a0 = *(const s16x8*)(gA0);
    s16x8 a1 = *(const s16x8*)(gA0 + rstep);
    s16x8 b0 = *(const s16x8*)(gB0);
    s16x8 b1 = *(const s16x8*)(gB0 + rstep);
    for (int kt = 0; kt < nkt; ++kt) {
        __syncthreads();
        *(s16x8*)&As[wof] = a0;
        *(s16x8*)&As[wof + 2048] = a1;
        *(s16x8*)&Bs[wof] = b0;
        *(s16x8*)&Bs[wof + 2048] = b1;
        __syncthreads();
        if (kt + 1 < nkt) {
            int ko = (kt + 1) << 5;
            a0 = *(const s16x8*)(gA0 + ko);
            a1 = *(const s16x8*)(gA0 + rstep + ko);
            b0 = *(const s16x8*)(gB0 + ko);
            b1 = *(const s16x8*)(gB0 + rstep + ko);
        }
        s16x8 af[4], bfr[4];
#pragma unroll
        for (int i = 0; i < 4; ++i) af[i] = *(const s16x8*)&As[fra[i]];
#pragma unroll
        for (int i = 0; i < 4; ++i) bfr[i] = *(const s16x8*)&Bs[frb[i]];
#pragma unroll
        for (int mi = 0; mi < 4; ++mi)
#pragma unroll
            for (int ni = 0; ni < 4; ++ni)
                acc[mi][ni] = __builtin_amdgcn_mfma_f32_16x16x32_bf16(af[mi], bfr[ni], acc[mi][ni], 0, 0, 0);
    }
    int rg = lane >> 4;
#pragma unroll
    for (int ni = 0; ni < 4; ++ni) {
        int gn = n0 + wc * 64 + ni * 16 + cl;
        float bv = bias ? bias[gn] : 0.f;
#pragma unroll
        for (int mi = 0; mi < 4; ++mi) {
            int gm = m0 + wr * 64 + mi * 16 + rg * 4;
            f32x4 v = acc[mi][ni];
#pragma unroll
            for (int ri = 0; ri < 4; ++ri)
                C[(size_t)(gm + ri) * N + gn] = f2bf(v[ri] + bv);
        }
    }
}

// ---------------- forward head-dim DFT as MFMA GEMM: planes = Wbig @ x^T ----------------
__global__ __launch_bounds__(256) void k_mfma_dft(const unsigned short* __restrict__ Wb,
                                                  const unsigned short* __restrict__ Xb,
                                                  float* __restrict__ XHre,
                                                  float* __restrict__ XHim) {
    int n0 = blockIdx.x * 128, m0 = blockIdx.y * 128;
    const int K = 768;
    int tid = threadIdx.x;
    int lane = tid & 63, wave = tid >> 6;
    int wr = wave >> 1, wc = wave & 1;
    __shared__ unsigned short As[4096], Bs[4096];
    f32x4 acc[4][4] = {};
    int r0 = tid >> 2, sl = tid & 3;
    int wof = r0 * 32 + ((sl ^ ((r0 >> 1) & 3)) << 3);
    const unsigned short* gA0 = Wb + (size_t)(m0 + r0) * K + sl * 8;
    const unsigned short* gB0 = Xb + (size_t)(n0 + r0) * K + sl * 8;
    size_t rstep = (size_t)64 * K;
    int fra[4], frb[4];
    int kg = lane >> 4, cl = lane & 15;
#pragma unroll
    for (int i = 0; i < 4; ++i) {
        int ra = wr * 64 + i * 16 + cl;
        fra[i] = ra * 32 + ((kg ^ ((ra >> 1) & 3)) << 3);
        int rb = wc * 64 + i * 16 + cl;
        frb[i] = rb * 32 + ((kg ^ ((rb >> 1) & 3)) << 3);
    }
    const int nkt = 24;
    s16x8 a0 = *(const s16x8*)(gA0);
    s16x8 a1 = *(const s16x8*)(gA0 + rstep);
    s16x8 b0 = *(const s16x8*)(gB0);
    s16x8 b1 = *(const s16x8*)(gB0 + rstep);
    for (int kt = 0; kt < nkt; ++kt) {
        __syncthreads();
        *(s16x8*)&As[wof] = a0;
        *(s16x8*)&As[wof + 2048] = a1;
        *(s16x8*)&Bs[wof] = b0;
        *(s16x8*)&Bs[wof + 2048] = b1;
        __syncthreads();
        if (kt + 1 < nkt) {
            int ko = (kt + 1) << 5;
            a0 = *(const s16x8*)(gA0 + ko);
            a1 = *(const s16x8*)(gA0 + rstep + ko);
            b0 = *(const s16x8*)(gB0 + ko);
            b1 = *(const s16x8*)(gB0 + rstep + ko);
        }
        s16x8 af[4], bfr[4];
#pragma unroll
        for (int i = 0; i < 4; ++i) af[i] = *(const s16x8*)&As[fra[i]];
#pragma unroll
        for (int i = 0; i < 4; ++i) bfr[i] = *(const s16x8*)&Bs[frb[i]];
#pragma unroll
        for (int mi = 0; mi < 4; ++mi)
#pragma unroll
            for (int ni = 0; ni < 4; ++ni)
                acc[mi][ni] = __builtin_amdgcn_mfma_f32_16x16x32_bf16(af[mi], bfr[ni], acc[mi][ni], 0, 0, 0);
    }
    int rg = lane >> 4;
#pragma unroll
    for (int ni = 0; ni < 4; ++ni) {
        int gn = n0 + wc * 64 + ni * 16 + cl;   // global row index of x
        int b = gn >> 10, u = gn & 1023;
#pragma unroll
        for (int mi = 0; mi < 4; ++mi) {
            int gmb = m0 + wr * 64 + mi * 16 + rg * 4;
            f32x4 v = acc[mi][ni];
#pragma unroll
            for (int ri = 0; ri < 4; ++ri) {
                int m = gmb + ri;
                if (m < 792) {
                    int h = m / 66, rem = m - h * 66;
                    size_t plane = (size_t)(b * Hn + h) * NK + (rem >> 1);
                    float* dst = (rem & 1) ? XHim : XHre;
                    dst[plane * 1024 + u] = v[ri];
                }
            }
        }
    }
}

// ---------------- Y planes -> row-major bf16 YT [16384][800] ----------------
__global__ __launch_bounds__(256) void k_transpose_yh(const float* __restrict__ YHre,
                                                      const float* __restrict__ YHim,
                                                      unsigned short* __restrict__ YT) {
    int ut = blockIdx.x & 7;
    int h = (blockIdx.x >> 3) % 12;
    int b = blockIdx.x / 96;
    int u0 = ut * 128;
    __shared__ unsigned short T[128 * 66];
    int tid = threadIdx.x;
    int planeBase = (b * Hn + h) * NK;
#pragma unroll
    for (int i = 0; i < 33; ++i) {
        int idx = tid + i * 256;        // 0..8447
        int kc = idx >> 7, uo = idx & 127;
        const float* src = (kc & 1) ? YHim : YHre;
        float v = src[(size_t)(planeBase + (kc >> 1)) * 1024 + u0 + uo];
        T[uo * 66 + kc] = f2bf(v);
    }
    __syncthreads();
    unsigned int* out = (unsigned int*)YT;
    for (int i = 0; i < 17; ++i) {
        int idx = tid + i * 256;
        if (idx < 4224) {
            int uo = idx / 33;
            int w = idx - uo * 33;
            unsigned int lo = T[uo * 66 + 2 * w];
            unsigned int hi = T[uo * 66 + 2 * w + 1];
            size_t r = (size_t)b * 1024 + u0 + uo;
            out[r * 400 + h * 33 + w] = lo | (hi << 16);
        }
    }
    // FIX: zero-fill padding uints 396..399 (u16 cols 792..799) — stale data there
    // reinterpreted as bf16 can be NaN; NaN*0 in MFMA poisons the accumulator.
    if (h == 0) {
        for (int i = tid; i < 512; i += 256) {
            int uo = i >> 2, w = 396 + (i & 3);
            size_t r = (size_t)b * 1024 + u0 + uo;
            out[r * 400 + w] = 0u;
        }
    }
}

// ---------------- inverse DFT + GELU as MFMA GEMM: G = gelu(YT @ Wi^T) bf16 ----------------
__global__ __launch_bounds__(256) void k_mfma_idft(const unsigned short* __restrict__ YT,
                                                   const unsigned short* __restrict__ Wi,
                                                   unsigned short* __restrict__ G) {
    int n0 = blockIdx.x * 128, m0 = blockIdx.y * 128;
    const int K = 800;
    int tid = threadIdx.x;
    int lane = tid & 63, wave = tid >> 6;
    int wr = wave >> 1, wc = wave & 1;
    __shared__ unsigned short As[4096], Bs[4096];
    f32x4 acc[4][4] = {};
    int r0 = tid >> 2, sl = tid & 3;
    int wof = r0 * 32 + ((sl ^ ((r0 >> 1) & 3)) << 3);
    const unsigned short* gA0 = YT + (size_t)(m0 + r0) * K + sl * 8;
    const unsigned short* gB0 = Wi + (size_t)(n0 + r0) * K + sl * 8;
    size_t rstep = (size_t)64 * K;
    int fra[4], frb[4];
    int kg = lane >> 4, cl = lane & 15;
#pragma unroll
    for (int i = 0; i < 4; ++i) {
        int ra = wr * 64 + i * 16 + cl;
        fra[i] = ra * 32 + ((kg ^ ((ra >> 1) & 3)) << 3);
        int rb = wc * 64 + i * 16 + cl;
        frb[i] = rb * 32 + ((kg ^ ((rb >> 1) & 3)) << 3);
    }
    const int nkt = 25;
    s16x8 a0 = *(const s16x8*)(gA0);
    s16x8 a1 = *(const s16x8*)(gA0 + rstep);
    s16x8 b0 = *(const s16x8*)(gB0);
    s16x8 b1 = *(const s16x8*)(gB0 + rstep);
    for (int kt = 0; kt < nkt; ++kt) {
        __syncthreads();
        *(s16x8*)&As[wof] = a0;
        *(s16x8*)&As[wof + 2048] = a1;
        *(s16x8*)&Bs[wof] = b0;
        *(s16x8*)&Bs[wof + 2048] = b1;
        __syncthreads();
        if (kt + 1 < nkt) {
            int ko = (kt + 1) << 5;
            a0 = *(const s16x8*)(gA0 + ko);
            a1 = *(const s16x8*)(gA0 + rstep + ko);
            b0 = *(const s16x8*)(gB0 + ko);
            b1 = *(const s16x8*)(gB0 + rstep + ko);
        }
        s16x8 af[4], bfr[4];
#pragma unroll
        for (int i = 0; i < 4; ++i) af[i] = *(const s16x8*)&As[fra[i]];
#pragma unroll
        for (int i = 0; i < 4; ++i) bfr[i] = *(const s16x8*)&Bs[frb[i]];
#pragma unroll
        for (int mi = 0; mi < 4; ++mi)
#pragma unroll
            for (int ni = 0; ni < 4; ++ni)
                acc[mi][ni] = __builtin_amdgcn_mfma_f32_16x16x32_bf16(af[mi], bfr[ni], acc[mi][ni], 0, 0, 0);
    }
    int rg = lane >> 4;
#pragma unroll
    for (int ni = 0; ni < 4; ++ni) {
        int gn = n0 + wc * 64 + ni * 16 + cl;
#pragma unroll
        for (int mi = 0; mi < 4; ++mi) {
            int gm = m0 + wr * 64 + mi * 16 + rg * 4;
            f32x4 v = acc[mi][ni];
#pragma unroll
            for (int ri = 0; ri < 4; ++ri) {
                float c = v[ri];
                float g = c * 0.5f * (1.0f + erff(c * 0.70710678118f));
                G[(size_t)(gm + ri) * 768 + gn] = f2bf(g);
            }
        }
    }
}

// ---------------- sparse: C_b = (tril(SP)/sigma) @ x_b via xT bf16, MFMA ----------------
__global__ __launch_bounds__(256) void k_mfma_sparse(const unsigned short* __restrict__ SP,
                                                     const unsigned short* __restrict__ XT,
                                                     const float* __restrict__ sigbuf,
                                                     float* __restrict__ C) {
    int bx = blockIdx.x;
    int mt = bx & 7, nt = (bx >> 3) % 6, b = bx / 48;
    int m0 = mt * 128, n0 = nt * 128;
    const unsigned short* Xb = XT + (size_t)b * Dn * Ln;
    float* Cb = C + (size_t)b * Ln * Dn;
    int tid = threadIdx.x;
    int lane = tid & 63, wave = tid >> 6;
    int wr = wave >> 1, wc = wave & 1;
    __shared__ unsigned short As[4096], Bs[4096];
    f32x4 acc[4][4] = {};
    int r0 = tid >> 2, sl = tid & 3;
    int wof = r0 * 32 + ((sl ^ ((r0 >> 1) & 3)) << 3);
    const unsigned short* gA0 = SP + (size_t)(m0 + r0) * Ln + sl * 8;
    const unsigned short* gB0 = Xb + (size_t)(n0 + r0) * Ln + sl * 8;
    size_t rstep = (size_t)64 * Ln;
    int fra[4], frb[4];
    int kg = lane >> 4, cl = lane & 15;
#pragma unroll
    for (int i = 0; i < 4; ++i) {
        int ra = wr * 64 + i * 16 + cl;
        fra[i] = ra * 32 + ((kg ^ ((ra >> 1) & 3)) << 3);
        int rb = wc * 64 + i * 16 + cl;
        frb[i] = rb * 32 + ((kg ^ ((rb >> 1) & 3)) << 3);
    }
    int nkt = mt * 4 + 4;             // only k-tiles with t0 <= m0+127 (tril)
    s16x8 a0 = *(const s16x8*)(gA0);
    s16x8 a1 = *(const s16x8*)(gA0 + rstep);
    s16x8 b0 = *(const s16x8*)(gB0);
    s16x8 b1 = *(const s16x8*)(gB0 + rstep);
    for (int kt = 0; kt < nkt; ++kt) {
        __syncthreads();
        *(s16x8*)&As[wof] = a0;
        *(s16x8*)&As[wof + 2048] = a1;
        *(s16x8*)&Bs[wof] = b0;
        *(s16x8*)&Bs[wof + 2048] = b1;
        __syncthreads();
        if (kt + 1 < nkt) {
            int ko = (kt + 1) << 5;
            a0 = *(const s16x8*)(gA0 + ko);
            a1 = *(const s16x8*)(gA0 + rstep + ko);
            b0 = *(const s16x8*)(gB0 + ko);
            b1 = *(const s16x8*)(gB0 + rstep + ko);
        }
        s16x8 af[4], bfr[4];
#pragma unroll
        for (int i = 0; i < 4; ++i) af[i] = *(const s16x8*)&As[fra[i]];
#pragma unroll
        for (int i = 0; i < 4; ++i) bfr[i] = *(const s16x8*)&Bs[frb[i]];
#pragma unroll
        for (int mi = 0; mi < 4; ++mi)
#pragma unroll
            for (int ni = 0; ni < 4; ++ni)
                acc[mi][ni] = __builtin_amdgcn_mfma_f32_16x16x32_bf16(af[mi], bfr[ni], acc[mi][ni], 0, 0, 0);
    }
    float invs = sigbuf[0];
    int rg = lane >> 4;
#pragma unroll
    for (int ni = 0; ni < 4; ++ni) {
        int gn = n0 + wc * 64 + ni * 16 + cl;
#pragma unroll
        for (int mi = 0; mi < 4; ++mi) {
            int gm = m0 + wr * 64 + mi * 16 + rg * 4;
            f32x4 v = acc[mi][ni];
#pragma unroll
            for (int ri = 0; ri < 4; ++ri)
                Cb[(size_t)(gm + ri) * Dn + gn] = v[ri] * invs;
        }
    }
}

// ---------------- conversions ----------------
__global__ __launch_bounds__(256) void k_cvt_bf16(const float* __restrict__ in,
                                                  unsigned short* __restrict__ out, int n4) {
    int i = blockIdx.x * 256 + threadIdx.x;
    if (i < n4) {
        float4 v = ((const float4*)in)[i];
        u16x4 o;
        o[0] = f2bf(v.x); o[1] = f2bf(v.y); o[2] = f2bf(v.z); o[3] = f2bf(v.w);
        *(u16x4*)&out[(size_t)i * 4] = o;
    }
}

__global__ __launch_bounds__(256) void k_cvt_sp(const float* __restrict__ SP,
                                                unsigned short* __restrict__ O) {
    int s = blockIdx.x;
    int t0 = threadIdx.x * 4;
    float4 v = *(const float4*)&SP[(size_t)s * 1024 + t0];
    u16x4 o;
    o[0] = (t0 + 0 <= s) ? f2bf(v.x) : 0;
    o[1] = (t0 + 1 <= s) ? f2bf(v.y) : 0;
    o[2] = (t0 + 2 <= s) ? f2bf(v.z) : 0;
    o[3] = (t0 + 3 <= s) ? f2bf(v.w) : 0;
    *(u16x4*)&O[(size_t)s * 1024 + t0] = o;
}

// ---------------- x_bf[b][t][d] -> xT[b][d][t] bf16, 64x64 LDS tile ----------------
__global__ __launch_bounds__(256) void k_transpose_x(const unsigned short* __restrict__ X,
                                                     unsigned short* __restrict__ XT) {
    int d0 = blockIdx.x * 64, t0 = blockIdx.y * 64, b = blockIdx.z;
    const unsigned short* Xb = X + (size_t)b * Ln * Dn;
    unsigned short* Tb = XT + (size_t)b * Dn * Ln;
    __shared__ unsigned short tile[64 * 65];
    int tx = threadIdx.x & 63, ty = threadIdx.x >> 6;
#pragma unroll
    for (int i = 0; i < 16; ++i) {
        int t = ty + i * 4;
        tile[t * 65 + tx] = Xb[(size_t)(t0 + t) * Dn + d0 + tx];
    }
    __syncthreads();
#pragma unroll
    for (int i = 0; i < 16; ++i) {
        int d = ty + i * 4;
        Tb[(size_t)(d0 + d) * Ln + t0 + tx] = tile[tx * 65 + d];
    }
}

// ---------------- spectral norm pieces ----------------
__global__ __launch_bounds__(1024) void k_sn_v(const float* __restrict__ Wm,
                                               float* __restrict__ v) {
    int j = threadIdx.x;
    float s = 0.f;
    for (int i = 0; i < 1024; ++i) s += Wm[(size_t)i * 1024 + j];
    s *= 0.03125f;
    __shared__ float red[1024];
    red[j] = s * s; __syncthreads();
    for (int st = 512; st > 0; st >>= 1) {
        if (j < st) red[j] += red[j + st];
        __syncthreads();
    }
    float nrm = sqrtf(red[0]);
    v[j] = s / (nrm + 1e-12f);
}

__global__ __launch_bounds__(64) void k_sn_u(const float* __restrict__ Wm,
                                             const float* __restrict__ v,
                                             float* __restrict__ ur) {
    int i = blockIdx.x;
    int lane = threadIdx.x;
    float s = 0.f;
    for (int j = lane; j < 1024; j += 64) s += Wm[(size_t)i * 1024 + j] * v[j];
#pragma unroll
    for (int off = 32; off > 0; off >>= 1) s += __shfl_down(s, off);
    if (lane == 0) ur[i] = s;
}

__global__ __launch_bounds__(1024) void k_sn_sigma(const float* __restrict__ ur,
                                                   float* __restrict__ sig) {
    int i = threadIdx.x;
    __shared__ float red[1024];
    float u = ur[i];
    red[i] = u * u; __syncthreads();
    for (int st = 512; st > 0; st >>= 1) {
        if (i < st) red[i] += red[i + st];
        __syncthreads();
    }
    if (i == 0) {
        float ss = red[0];
        float sigma = ss / (sqrtf(ss) + 1e-12f);
        sig[0] = 1.0f / sigma;
    }
}

// ---------------- final residual + LayerNorm ----------------
__global__ __launch_bounds__(256) void k_final_ln(const float* __restrict__ CE,
                                                  const float* __restrict__ SE,
                                                  const float* __restrict__ EMB,
                                                  const float* __restrict__ g,
                                                  const float* __restrict__ be,
                                                  float* __restrict__ out) {
    int r = blockIdx.x;
    int tid = threadIdx.x;
    float y[3];
    float s = 0.f;
#pragma unroll
    for (int i = 0; i < 3; ++i) {
        int o = tid + i * 256;
        size_t idx = (size_t)r * 768 + o;
        y[i] = CE[idx] + SE[idx] + EMB[idx];
        s += y[i];
    }
    __shared__ float red[256];
    red[tid] = s; __syncthreads();
    for (int st = 128; st > 0; st >>= 1) {
        if (tid < st) red[tid] += red[tid + st];
        __syncthreads();
    }
    float mu = red[0] * (1.f / 768.f);
    __syncthreads();
    float vs = 0.f;
#pragma unroll
    for (int i = 0; i < 3; ++i) { float d = y[i] - mu; vs += d * d; }
    red[tid] = vs; __syncthreads();
    for (int st = 128; st > 0; st >>= 1) {
        if (tid < st) red[tid] += red[tid + st];
        __syncthreads();
    }
    float var = red[0] * (1.f / 768.f);
    float rstd = rsqrtf(var + 1e-12f);
#pragma unroll
    for (int i = 0; i < 3; ++i) {
        int o = tid + i * 256;
        size_t idx = (size_t)r * 768 + o;
        out[idx] = (y[i] - mu) * rstd * g[o] + be[o];
    }
}

extern "C" void kernel_launch(void* const* d_in, const int* in_sizes, int n_in,
                              void* d_out, int out_size, void* d_ws, size_t ws_size,
                              hipStream_t stream) {
    const float* emb     = (const float*)d_in[0];
    const float* pre_w   = (const float*)d_in[1];
    const float* pre_b   = (const float*)d_in[2];
    const float* psfs    = (const float*)d_in[3];
    const float* post_w  = (const float*)d_in[4];
    const float* post_b  = (const float*)d_in[5];
    const float* spmat   = (const float*)d_in[6];
    const float* ln_g    = (const float*)d_in[7];
    const float* ln_b    = (const float*)d_in[8];
    float* out = (float*)d_out;
    float* ws = (float*)d_ws;

    float* p      = ws + O_P;
    float* psfh   = ws + O_PSFH;
    float* qh     = ws + O_QH;
    float* q      = ws + O_SIG + 8;
    float* XHre   = ws + O_XH;
    float* XHim   = ws + O_XH + 6488064;
    float* YHre   = ws + O_YH;
    float* YHim   = ws + O_YH + 6488064;
    float* spe    = ws + O_SPE;
    float* phf    = ws + O_SPE;                      // alias (dead before spe)
    float* v      = ws + O_V;
    float* urw    = ws + O_UR;
    float* sig    = ws + O_SIG;
    float* CE     = ws + O_YH;                       // after YH planes dead

    unsigned short* x_bf      = (unsigned short*)(ws + O_X);
    unsigned short* Wbig      = (unsigned short*)(ws + O_X + 6291456);
    unsigned short* Wi        = (unsigned short*)(ws + O_X + 6635520);
    unsigned short* YT        = (unsigned short*)(ws + O_XH);            // over dead XH planes
    unsigned short* G_bf      = (unsigned short*)(ws + O_XH + 6553600);
    unsigned short* xT_bf     = (unsigned short*)(ws + O_XH);            // over dead YT
    unsigned short* emb_bf    = (unsigned short*)(ws + O_YH);            // dead before YH planes
    unsigned short* SP_bf     = (unsigned short*)(ws + O_P);             // over dead p
    unsigned short* pre_w_bf  = (unsigned short*)(ws + O_PSFH);          // over dead psfh
    unsigned short* post_w_bf = (unsigned short*)(ws + O_PSFH + 294912);

    // PSF preprocessing
    k_psf_softmax<<<Hn * 64, 256, 0, stream>>>(psfs, p, q);
    k_psf_dft<<<Hn * 1024, 64, 0, stream>>>(p, psfh);
    k_q_dft<<<Hn, 64, 0, stream>>>(q, qh);
    k_tap_fft<<<NHK, 256, 0, stream>>>(psfh, qh, phf);

    // spectral norm scalar
    k_sn_v<<<1, 1024, 0, stream>>>(spmat, v);
    k_sn_u<<<1024, 64, 0, stream>>>(spmat, v, urw);
    k_sn_sigma<<<1, 1024, 0, stream>>>(urw, sig);

    // conversions + DFT matrix builds
    k_cvt_sp<<<1024, 256, 0, stream>>>(spmat, SP_bf);
    k_cvt_bf16<<<576, 256, 0, stream>>>(pre_w, pre_w_bf, 147456);
    k_cvt_bf16<<<576, 256, 0, stream>>>(post_w, post_w_bf, 147456);
    k_cvt_bf16<<<12288, 256, 0, stream>>>(emb, emb_bf, 3145728);
    k_build_wbig<<<896, 256, 0, stream>>>(Wbig);
    k_build_wi<<<768, 256, 0, stream>>>(Wi);

    // pre-projection (MFMA bf16 -> bf16 x)
    k_mfma_abt_bf<<<dim3(6, 128), 256, 0, stream>>>(emb_bf, pre_w_bf, pre_b, x_bf, Bn * Ln, Dn, Dn);

    // head-dim DFT of x as MFMA GEMM -> split re/im planes
    k_mfma_dft<<<dim3(128, 7), 256, 0, stream>>>(Wbig, x_bf, XHre, XHim);

    // causal conv + uniform suffix via circular-2048 FFT
    k_conv_fft<<<Bn * NHK, 256, 0, stream>>>(XHre, XHim, phf, YHre, YHim);

    // Y planes -> row-major bf16 (K-contiguous for idft GEMM)
    k_transpose_yh<<<Bn * Hn * 8, 256, 0, stream>>>(YHre, YHim, YT);

    // inverse DFT + GELU as MFMA GEMM -> G bf16
    k_mfma_idft<<<dim3(6, 128), 256, 0, stream>>>(YT, Wi, G_bf);

    // transpose x -> xT bf16 (over dead YT region)
    k_transpose_x<<<dim3(12, 16, Bn), 256, 0, stream>>>(x_bf, xT_bf);

    // post-projection (MFMA bf16) -> CE f32 (over dead YH planes)
    k_mfma_abt<<<dim3(6, 128), 256, 0, stream>>>(G_bf, post_w_bf, post_b, CE, Bn * Ln, Dn, Dn);

    // sparse branch (MFMA bf16, triangular k-loop)
    k_mfma_sparse<<<768, 256, 0, stream>>>(SP_bf, xT_bf, sig, spe);

    // residual + LayerNorm
    k_final_ln<<<Bn * Ln, 256, 0, stream>>>(CE, spe, emb, ln_g, ln_b, out);
}

// Round 6
// 456.699 us; speedup vs baseline: 6.9578x; 1.1005x over previous
//
#include <hip/hip_runtime.h>
#include <math.h>

// Problem constants
#define Bn 16
#define Ln 1024
#define Dn 768
#define Hn 12
#define PHDn 64
#define NK 33                 // Hermitian bins for 64-pt DFT (k=0..32)
#define NHK (Hn * NK)         // 396
#define TWOPI_64 0.09817477042468103f   // 2*pi/64

typedef short s16x8 __attribute__((ext_vector_type(8)));
typedef float f32x4 __attribute__((ext_vector_type(4)));
typedef unsigned short u16x4 __attribute__((ext_vector_type(4)));

__device__ __forceinline__ unsigned short f2bf(float f) {
    unsigned int u = __float_as_uint(f);
    unsigned int r = (u + 0x7FFFu + ((u >> 16) & 1u)) >> 16;
    return (unsigned short)r;
}

__device__ __forceinline__ float2 cmul(float2 a, float2 b) {
    return make_float2(a.x * b.x - a.y * b.y, a.x * b.y + a.y * b.x);
}

// ---------------- workspace layout (float offsets) ----------------
static const size_t O_P    = 0;          // psf taps; later SP_bf
static const size_t O_PSFH = 786432;     // psf-hat; later pre_w_bf + post_w_bf
static const size_t O_QH   = 1597440;    // q-hat
static const size_t O_X    = 1598240;    // x_bf (6291456) + Wbig (344064) + Wi (307200)
static const size_t O_XH   = 14181152;   // XHre/XHim planes; later YT + G_bf; later xT_bf
static const size_t O_YH   = 27157280;   // emb_bf early; YHre/YHim planes; later CE f32
static const size_t O_SPE  = 40146080;   // phf early; sparse_emb later
static const size_t O_V    = 52728992;
static const size_t O_UR   = 52730016;
static const size_t O_SIG  = 52731040;   // inv_sigma + q[768] after

// ---------------- psf softmax over 2047 taps (1023 are zeros) ----------------
__global__ __launch_bounds__(256) void k_psf_softmax(const float* __restrict__ psfs,
                                                     float* __restrict__ p,
                                                     float* __restrict__ q) {
    int he = blockIdx.x;            // h*64+e
    int h = he >> 6, e = he & 63;
    int tid = threadIdx.x;
    float ev[4];
    float s = 0.f;
#pragma unroll
    for (int i = 0; i < 4; ++i) {
        int t = tid + 256 * i;
        float v = psfs[((size_t)h * 2047 + t) * 64 + e];
        ev[i] = expf(v);
        s += ev[i];
    }
    __shared__ float red[256];
    red[tid] = s; __syncthreads();
    for (int st = 128; st > 0; st >>= 1) {
        if (tid < st) red[tid] += red[tid + st];
        __syncthreads();
    }
    float denom = red[0] + 1023.0f;
    float inv = 1.0f / denom;
#pragma unroll
    for (int i = 0; i < 4; ++i) {
        int t = tid + 256 * i;
        p[((size_t)h * 1024 + t) * 64 + e] = ev[i] * inv;
    }
    if (tid == 0) q[he] = inv;
}

// ---------------- DFT over head-dim of psf taps ----------------
__global__ __launch_bounds__(64) void k_psf_dft(const float* __restrict__ p,
                                                float* __restrict__ psfh) {
    int ht = blockIdx.x;            // h*1024+t
    int h = ht >> 10, t = ht & 1023;
    int tid = threadIdx.x;          // 64
    __shared__ float pv[64], cc[64], ssn[64];
    pv[tid] = p[((size_t)h * 1024 + t) * 64 + tid];
    float ang = TWOPI_64 * tid;
    cc[tid] = cosf(ang); ssn[tid] = sinf(ang);
    __syncthreads();
    if (tid < NK) {
        float re = 0.f, im = 0.f;
#pragma unroll 8
        for (int e = 0; e < 64; ++e) {
            int j = (tid * e) & 63;
            float v = pv[e];
            re += v * cc[j];
            im -= v * ssn[j];
        }
        size_t o = (((size_t)h * NK + tid) * 1024 + t) * 2;
        psfh[o] = re; psfh[o + 1] = im;
    }
}

// ---------------- DFT of uniform tap value q[h][e] ----------------
__global__ __launch_bounds__(64) void k_q_dft(const float* __restrict__ q,
                                              float* __restrict__ qh) {
    int h = blockIdx.x;
    int tid = threadIdx.x;
    __shared__ float qv[64], cc[64], ssn[64];
    qv[tid] = q[h * 64 + tid];
    float ang = TWOPI_64 * tid;
    cc[tid] = cosf(ang); ssn[tid] = sinf(ang);
    __syncthreads();
    if (tid < NK) {
        float re = 0.f, im = 0.f;
        for (int e = 0; e < 64; ++e) {
            int j = (tid * e) & 63;
            re += qv[e] * cc[j];
            im -= qv[e] * ssn[j];
        }
        qh[(h * NK + tid) * 2] = re;
        qh[(h * NK + tid) * 2 + 1] = im;
    }
}

__device__ __forceinline__ void build_twiddles(float2* tw, int tid) {
#pragma unroll
    for (int it = 0; it < 4; ++it) {
        int j = tid + it * 256;
        float a = (float)j * 3.0679615757712823e-3f;   // 2*pi/2048
        float sv, cv;
        __sincosf(a, &sv, &cv);
        tw[j] = make_float2(cv, -sv);
    }
}

// ---------------- fused radix-2 stage-pair (stages s,s+1 of 2048-pt Stockham) ----------------
// m = 2^s. Reads X[i],X[i+512],X[i+1024],X[i+1536] (i=fb<512), writes Y[4am+r+{0,m,2m,3m}].
__device__ __forceinline__ void fft_pair(const float2* __restrict__ X,
                                         float2* __restrict__ Y,
                                         const float2* __restrict__ tw,
                                         int tid, int m) {
#pragma unroll
    for (int it = 0; it < 2; ++it) {
        int i = tid + it * 256;
        int r = i & (m - 1);
        int am = i - r;
        float2 w1 = tw[am];
        float2 w1b = make_float2(w1.y, -w1.x);   // tw[am+512] = -j*w1
        float2 w2 = tw[2 * am];
        float2 x0 = X[i], x1 = X[i + 512], x2 = X[i + 1024], x3 = X[i + 1536];
        float2 y0 = make_float2(x0.x + x2.x, x0.y + x2.y);
        float2 y1 = cmul(make_float2(x0.x - x2.x, x0.y - x2.y), w1);
        float2 y2 = make_float2(x1.x + x3.x, x1.y + x3.y);
        float2 y3 = cmul(make_float2(x1.x - x3.x, x1.y - x3.y), w1b);
        int o = 4 * am + r;
        Y[o] = make_float2(y0.x + y2.x, y0.y + y2.y);
        Y[o + m] = make_float2(y1.x + y3.x, y1.y + y3.y);
        Y[o + 2 * m] = cmul(make_float2(y0.x - y2.x, y0.y - y2.y), w2);
        Y[o + 3 * m] = cmul(make_float2(y1.x - y3.x, y1.y - y3.y), w2);
    }
}

// ---------------- FFT of tap vector per (h,k): taps at [0,1024), q at [1025,2048) ----------------
__global__ __launch_bounds__(256) void k_tap_fft(const float* __restrict__ psfh,
                                                 const float* __restrict__ qh,
                                                 float* __restrict__ phf) {
    __shared__ float2 A[2048], B[2048], tw[1024];
    int hk = blockIdx.x, tid = threadIdx.x;
    build_twiddles(tw, tid);
    float2 qv = make_float2(qh[hk * 2], qh[hk * 2 + 1]);
    const float2* Pg = (const float2*)(psfh + (size_t)hk * 2048);
    __syncthreads();
    // fused pair (0,1), m=1: x2 = (i==0 ? 0 : q), x3 = q
#pragma unroll
    for (int it = 0; it < 2; ++it) {
        int i = tid + it * 256;
        float2 x0 = Pg[i], x1 = Pg[i + 512];
        float2 x2 = (i == 0) ? make_float2(0.f, 0.f) : qv;
        float2 x3 = qv;
        float2 w1 = tw[i];
        float2 w1b = make_float2(w1.y, -w1.x);
        float2 w2 = tw[2 * i];
        float2 y0 = make_float2(x0.x + x2.x, x0.y + x2.y);
        float2 y1 = cmul(make_float2(x0.x - x2.x, x0.y - x2.y), w1);
        float2 y2 = make_float2(x1.x + x3.x, x1.y + x3.y);
        float2 y3 = cmul(make_float2(x1.x - x3.x, x1.y - x3.y), w1b);
        int o = 4 * i;
        A[o] = make_float2(y0.x + y2.x, y0.y + y2.y);
        A[o + 1] = make_float2(y1.x + y3.x, y1.y + y3.y);
        A[o + 2] = cmul(make_float2(y0.x - y2.x, y0.y - y2.y), w2);
        A[o + 3] = cmul(make_float2(y1.x - y3.x, y1.y - y3.y), w2);
    }
    __syncthreads();
    fft_pair(A, B, tw, tid, 4);   __syncthreads();
    fft_pair(B, A, tw, tid, 16);  __syncthreads();
    fft_pair(A, B, tw, tid, 64);  __syncthreads();
    fft_pair(B, A, tw, tid, 256); __syncthreads();
    // final stage (m=1024, tw[0]=1): out[t]=A[t]+A[t+1024], out[t+1024]=A[t]-A[t+1024]
    float2* out = (float2*)(phf + (size_t)hk * 4096);
#pragma unroll
    for (int it = 0; it < 4; ++it) {
        int t = tid + it * 256;
        float2 lo = A[t], hi = A[t + 1024];
        out[t] = make_float2(lo.x + hi.x, lo.y + hi.y);
        out[t + 1024] = make_float2(lo.x - hi.x, lo.y - hi.y);
    }
}

// ---------------- per-(b,h,k) conv via circular-2048 FFT, fused-pair stages ----------------
__global__ __launch_bounds__(256) void k_conv_fft(const float* __restrict__ XHre,
                                                  const float* __restrict__ XHim,
                                                  const float* __restrict__ PHF,
                                                  float* __restrict__ YHre,
                                                  float* __restrict__ YHim) {
    __shared__ float2 A[2048], B[2048], tw[1024];
    int bhk = blockIdx.x, tid = threadIdx.x;
    int hk = bhk % NHK;
    build_twiddles(tw, tid);
    const float* Rg = XHre + (size_t)bhk * 1024;
    const float* Ig = XHim + (size_t)bhk * 1024;
    __syncthreads();
    // forward fused pair (0,1), m=1, upper half zero (x2=x3=0) -> from global
#pragma unroll
    for (int it = 0; it < 2; ++it) {
        int i = tid + it * 256;
        float2 x0 = make_float2(Rg[i], Ig[i]);
        float2 x1 = make_float2(Rg[i + 512], Ig[i + 512]);
        float2 w1 = tw[i];
        float2 w1b = make_float2(w1.y, -w1.x);
        float2 w2 = tw[2 * i];
        float2 y1 = cmul(x0, w1);
        float2 y3 = cmul(x1, w1b);
        int o = 4 * i;
        A[o] = make_float2(x0.x + x1.x, x0.y + x1.y);
        A[o + 1] = make_float2(y1.x + y3.x, y1.y + y3.y);
        A[o + 2] = cmul(make_float2(x0.x - x1.x, x0.y - x1.y), w2);
        A[o + 3] = cmul(make_float2(y1.x - y3.x, y1.y - y3.y), w2);
    }
    __syncthreads();
    fft_pair(A, B, tw, tid, 4);   __syncthreads();
    fft_pair(B, A, tw, tid, 16);  __syncthreads();
    fft_pair(A, B, tw, tid, 64);  __syncthreads();
    fft_pair(B, A, tw, tid, 256); __syncthreads();
    // forward final stage folded into register multiply; conj for inverse trick
    const float2* P = (const float2*)(PHF + (size_t)hk * 4096);
    float2 q[8];
#pragma unroll
    for (int it = 0; it < 4; ++it) {
        int t = tid + it * 256;
        float2 lo = A[t], hi = A[t + 1024];
        float2 fl = make_float2(lo.x + hi.x, lo.y + hi.y);     // F[t]
        float2 fh = make_float2(lo.x - hi.x, lo.y - hi.y);     // F[t+1024]
        float2 vl = cmul(fl, P[t]);
        float2 vh = cmul(fh, P[t + 1024]);
        q[it] = make_float2(vl.x, -vl.y);
        q[it + 4] = make_float2(vh.x, -vh.y);
    }
    // inverse fused pair (0,1) m=1 entirely from registers:
    // fb=tid uses slots {0,2,4,6}; fb=tid+256 uses {1,3,5,7}
#pragma unroll
    for (int it = 0; it < 2; ++it) {
        int i = tid + it * 256;
        float2 x0 = q[it], x1 = q[it + 2], x2 = q[it + 4], x3 = q[it + 6];
        float2 w1 = tw[i];
        float2 w1b = make_float2(w1.y, -w1.x);
        float2 w2 = tw[2 * i];
        float2 y0 = make_float2(x0.x + x2.x, x0.y + x2.y);
        float2 y1 = cmul(make_float2(x0.x - x2.x, x0.y - x2.y), w1);
        float2 y2 = make_float2(x1.x + x3.x, x1.y + x3.y);
        float2 y3 = cmul(make_float2(x1.x - x3.x, x1.y - x3.y), w1b);
        int o = 4 * i;
        B[o] = make_float2(y0.x + y2.x, y0.y + y2.y);
        B[o + 1] = make_float2(y1.x + y3.x, y1.y + y3.y);
        B[o + 2] = cmul(make_float2(y0.x - y2.x, y0.y - y2.y), w2);
        B[o + 3] = cmul(make_float2(y1.x - y3.x, y1.y - y3.y), w2);
    }
    __syncthreads();
    fft_pair(B, A, tw, tid, 4);   __syncthreads();
    fft_pair(A, B, tw, tid, 16);  __syncthreads();
    fft_pair(B, A, tw, tid, 64);  __syncthreads();
    fft_pair(A, B, tw, tid, 256); __syncthreads();
    // inverse final stage: only s<1024 needed; tw[0]=1 -> sum; scale + conj
    const float inv_n = 1.0f / 2048.0f;
#pragma unroll
    for (int it = 0; it < 4; ++it) {
        int s = tid + it * 256;
        float2 lo = B[s], hi = B[s + 1024];
        YHre[(size_t)bhk * 1024 + s] = (lo.x + hi.x) * inv_n;
        YHim[(size_t)bhk * 1024 + s] = -(lo.y + hi.y) * inv_n;
    }
}

// ---------------- build block-diagonal forward DFT matrix Wbig [896][768] bf16 ----------------
__global__ __launch_bounds__(256) void k_build_wbig(unsigned short* __restrict__ W) {
    int m = blockIdx.x;                  // 0..895
    int tid = threadIdx.x;
    int h = m / 66, rem = m - h * 66;
    int k = rem >> 1, od = rem & 1;
    bool valid = (m < 792);
#pragma unroll
    for (int i = 0; i < 3; ++i) {
        int d = tid + i * 256;
        int dh = d >> 6, dd = d & 63;
        float val = 0.f;
        if (valid && dh == h) {
            int j = (k * dd) & 63;
            float ang = TWOPI_64 * (float)j;
            val = od ? -sinf(ang) : cosf(ang);
        }
        W[(size_t)m * 768 + d] = f2bf(val);
    }
}

// ---------------- build inverse DFT matrix Wi [768][800] bf16 (1/64 + Hermitian 2x folded) ----------------
__global__ __launch_bounds__(256) void k_build_wi(unsigned short* __restrict__ W) {
    int hd = blockIdx.x;                 // 0..767
    int tid = threadIdx.x;
    int h = hd >> 6, d = hd & 63;
#pragma unroll
    for (int i = 0; i < 4; ++i) {
        int col = tid + i * 256;
        if (col < 800) {
            float val = 0.f;
            if (col < 792) {
                int h2 = col / 66, rem = col - h2 * 66;
                int k = rem >> 1, od = rem & 1;
                if (h2 == h) {
                    int j = (k * d) & 63;
                    float ang = TWOPI_64 * (float)j;
                    float ck = ((k == 0) || (k == 32)) ? (1.f / 64.f) : (2.f / 64.f);
                    val = od ? -sinf(ang) * ck : cosf(ang) * ck;
                }
            }
            W[(size_t)hd * 800 + col] = f2bf(val);
        }
    }
}

// ---------------- bf16 MFMA GEMM: C(f32) = A@W^T + bias ----------------
__global__ __launch_bounds__(256) void k_mfma_abt(const unsigned short* __restrict__ A,
                                                  const unsigned short* __restrict__ W,
                                                  const float* __restrict__ bias,
                                                  float* __restrict__ C,
                                                  int M, int N, int K) {
    int n0 = blockIdx.x * 128, m0 = blockIdx.y * 128;
    int tid = threadIdx.x;
    int lane = tid & 63, wave = tid >> 6;
    int wr = wave >> 1, wc = wave & 1;
    __shared__ unsigned short As[4096], Bs[4096];
    f32x4 acc[4][4] = {};
    int r0 = tid >> 2, sl = tid & 3;
    int wof = r0 * 32 + ((sl ^ ((r0 >> 1) & 3)) << 3);
    const unsigned short* gA0 = A + (size_t)(m0 + r0) * K + sl * 8;
    const unsigned short* gB0 = W + (size_t)(n0 + r0) * K + sl * 8;
    size_t rstep = (size_t)64 * K;
    int fra[4], frb[4];
    int kg = lane >> 4, cl = lane & 15;
#pragma unroll
    for (int i = 0; i < 4; ++i) {
        int ra = wr * 64 + i * 16 + cl;
        fra[i] = ra * 32 + ((kg ^ ((ra >> 1) & 3)) << 3);
        int rb = wc * 64 + i * 16 + cl;
        frb[i] = rb * 32 + ((kg ^ ((rb >> 1) & 3)) << 3);
    }
    int nkt = K >> 5;
    s16x8 a0 = *(const s16x8*)(gA0);
    s16x8 a1 = *(const s16x8*)(gA0 + rstep);
    s16x8 b0 = *(const s16x8*)(gB0);
    s16x8 b1 = *(const s16x8*)(gB0 + rstep);
    for (int kt = 0; kt < nkt; ++kt) {
        __syncthreads();
        *(s16x8*)&As[wof] = a0;
        *(s16x8*)&As[wof + 2048] = a1;
        *(s16x8*)&Bs[wof] = b0;
        *(s16x8*)&Bs[wof + 2048] = b1;
        __syncthreads();
        if (kt + 1 < nkt) {
            int ko = (kt + 1) << 5;
            a0 = *(const s16x8*)(gA0 + ko);
            a1 = *(const s16x8*)(gA0 + rstep + ko);
            b0 = *(const s16x8*)(gB0 + ko);
            b1 = *(const s16x8*)(gB0 + rstep + ko);
        }
        s16x8 af[4], bfr[4];
#pragma unroll
        for (int i = 0; i < 4; ++i) af[i] = *(const s16x8*)&As[fra[i]];
#pragma unroll
        for (int i = 0; i < 4; ++i) bfr[i] = *(const s16x8*)&Bs[frb[i]];
#pragma unroll
        for (int mi = 0; mi < 4; ++mi)
#pragma unroll
            for (int ni = 0; ni < 4; ++ni)
                acc[mi][ni] = __builtin_amdgcn_mfma_f32_16x16x32_bf16(af[mi], bfr[ni], acc[mi][ni], 0, 0, 0);
    }
    int rg = lane >> 4;
#pragma unroll
    for (int ni = 0; ni < 4; ++ni) {
        int gn = n0 + wc * 64 + ni * 16 + cl;
        float bv = bias ? bias[gn] : 0.f;
#pragma unroll
        for (int mi = 0; mi < 4; ++mi) {
            int gm = m0 + wr * 64 + mi * 16 + rg * 4;
            f32x4 v = acc[mi][ni];
#pragma unroll
            for (int ri = 0; ri < 4; ++ri)
                C[(size_t)(gm + ri) * N + gn] = v[ri] + bv;
        }
    }
}

// ---------------- bf16 MFMA GEMM with bf16 output (pre-projection) ----------------
__global__ __launch_bounds__(256) void k_mfma_abt_bf(const unsigned short* __restrict__ A,
                                                     const unsigned short* __restrict__ W,
                                                     const float* __restrict__ bias,
                                                     unsigned short* __restrict__ C,
                                                     int M, int N, int K) {
    int n0 = blockIdx.x * 128, m0 = blockIdx.y * 128;
    int tid = threadIdx.x;
    int lane = tid & 63, wave = tid >> 6;
    int wr = wave >> 1, wc = wave & 1;
    __shared__ unsigned short As[4096], Bs[4096];
    f32x4 acc[4][4] = {};
    int r0 = tid >> 2, sl = tid & 3;
    int wof = r0 * 32 + ((sl ^ ((r0 >> 1) & 3)) << 3);
    const unsigned short* gA0 = A + (size_t)(m0 + r0) * K + sl * 8;
    const unsigned short* gB0 = W + (size_t)(n0 + r0) * K + sl * 8;
    size_t rstep = (size_t)64 * K;
    int fra[4], frb[4];
    int kg = lane >> 4, cl = lane & 15;
#pragma unroll
    for (int i = 0; i < 4; ++i) {
        int ra = wr * 64 + i * 16 + cl;
        fra[i] = ra * 32 + ((kg ^ ((ra >> 1) & 3)) << 3);
        int rb = wc * 64 + i * 16 + cl;
        frb[i] = rb * 32 + ((kg ^ ((rb >> 1) & 3)) << 3);
    }
    int nkt = K >> 5;
    s16x8 a0 = *(const s16x8*)(gA0);
    s16x8 a1 = *(const s16x8*)(gA0 + rstep);
    s16x8 b0 = *(const s16x8*)(gB0);
    s16x8 b1 = *(const s16x8*)(gB0 + rstep);
    for (int kt = 0; kt < nkt; ++kt) {
        __syncthreads();
        *(s16x8*)&As[wof] = a0;
        *(s16x8*)&As[wof + 2048] = a1;
        *(s16x8*)&Bs[wof] = b0;
        *(s16x8*)&Bs[wof + 2048] = b1;
        __syncthreads();
        if (kt + 1 < nkt) {
            int ko = (kt + 1) << 5;
            a0 = *(const s16x8*)(gA0 + ko);
            a1 = *(const s16x8*)(gA0 + rstep + ko);
            b0 = *(const s16x8*)(gB0 + ko);
            b1 = *(const s16x8*)(gB0 + rstep + ko);
        }
        s16x8 af[4], bfr[4];
#pragma unroll
        for (int i = 0; i < 4; ++i) af[i] = *(const s16x8*)&As[fra[i]];
#pragma unroll
        for (int i = 0; i < 4; ++i) bfr[i] = *(const s16x8*)&Bs[frb[i]];
#pragma unroll
        for (int mi = 0; mi < 4; ++mi)
#pragma unroll
            for (int ni = 0; ni < 4; ++ni)
                acc[mi][ni] = __builtin_amdgcn_mfma_f32_16x16x32_bf16(af[mi], bfr[ni], acc[mi][ni], 0, 0, 0);
    }
    int rg = lane >> 4;
#pragma unroll
    for (int ni = 0; ni < 4; ++ni) {
        int gn = n0 + wc * 64 + ni * 16 + cl;
        float bv = bias ? bias[gn] : 0.f;
#pragma unroll
        for (int mi = 0; mi < 4; ++mi) {
            int gm = m0 + wr * 64 + mi * 16 + rg * 4;
            f32x4 v = acc[mi][ni];
#pragma unroll
            for (int ri = 0; ri < 4; ++ri)
                C[(size_t)(gm + ri) * N + gn] = f2bf(v[ri] + bv);
        }
    }
}

// ---------------- forward head-dim DFT as MFMA GEMM: planes = Wbig @ x^T ----------------
__global__ __launch_bounds__(256) void k_mfma_dft(const unsigned short* __restrict__ Wb,
                                                  const unsigned short* __restrict__ Xb,
                                                  float* __restrict__ XHre,
                                                  float* __restrict__ XHim) {
    int n0 = blockIdx.x * 128, m0 = blockIdx.y * 128;
    const int K = 768;
    int tid = threadIdx.x;
    int lane = tid & 63, wave = tid >> 6;
    int wr = wave >> 1, wc = wave & 1;
    __shared__ unsigned short As[4096], Bs[4096];
    f32x4 acc[4][4] = {};
    int r0 = tid >> 2, sl = tid & 3;
    int wof = r0 * 32 + ((sl ^ ((r0 >> 1) & 3)) << 3);
    const unsigned short* gA0 = Wb + (size_t)(m0 + r0) * K + sl * 8;
    const unsigned short* gB0 = Xb + (size_t)(n0 + r0) * K + sl * 8;
    size_t rstep = (size_t)64 * K;
    int fra[4], frb[4];
    int kg = lane >> 4, cl = lane & 15;
#pragma unroll
    for (int i = 0; i < 4; ++i) {
        int ra = wr * 64 + i * 16 + cl;
        fra[i] = ra * 32 + ((kg ^ ((ra >> 1) & 3)) << 3);
        int rb = wc * 64 + i * 16 + cl;
        frb[i] = rb * 32 + ((kg ^ ((rb >> 1) & 3)) << 3);
    }
    const int nkt = 24;
    s16x8 a0 = *(const s16x8*)(gA0);
    s16x8 a1 = *(const s16x8*)(gA0 + rstep);
    s16x8 b0 = *(const s16x8*)(gB0);
    s16x8 b1 = *(const s16x8*)(gB0 + rstep);
    for (int kt = 0; kt < nkt; ++kt) {
        __syncthreads();
        *(s16x8*)&As[wof] = a0;
        *(s16x8*)&As[wof + 2048] = a1;
        *(s16x8*)&Bs[wof] = b0;
        *(s16x8*)&Bs[wof + 2048] = b1;
        __syncthreads();
        if (kt + 1 < nkt) {
            int ko = (kt + 1) << 5;
            a0 = *(const s16x8*)(gA0 + ko);
            a1 = *(const s16x8*)(gA0 + rstep + ko);
            b0 = *(const s16x8*)(gB0 + ko);
            b1 = *(const s16x8*)(gB0 + rstep + ko);
        }
        s16x8 af[4], bfr[4];
#pragma unroll
        for (int i = 0; i < 4; ++i) af[i] = *(const s16x8*)&As[fra[i]];
#pragma unroll
        for (int i = 0; i < 4; ++i) bfr[i] = *(const s16x8*)&Bs[frb[i]];
#pragma unroll
        for (int mi = 0; mi < 4; ++mi)
#pragma unroll
            for (int ni = 0; ni < 4; ++ni)
                acc[mi][ni] = __builtin_amdgcn_mfma_f32_16x16x32_bf16(af[mi], bfr[ni], acc[mi][ni], 0, 0, 0);
    }
    int rg = lane >> 4;
#pragma unroll
    for (int ni = 0; ni < 4; ++ni) {
        int gn = n0 + wc * 64 + ni * 16 + cl;   // global row index of x
        int b = gn >> 10, u = gn & 1023;
#pragma unroll
        for (int mi = 0; mi < 4; ++mi) {
            int gmb = m0 + wr * 64 + mi * 16 + rg * 4;
            f32x4 v = acc[mi][ni];
#pragma unroll
            for (int ri = 0; ri < 4; ++ri) {
                int m = gmb + ri;
                if (m < 792) {
                    int h = m / 66, rem = m - h * 66;
                    size_t plane = (size_t)(b * Hn + h) * NK + (rem >> 1);
                    float* dst = (rem & 1) ? XHim : XHre;
                    dst[plane * 1024 + u] = v[ri];
                }
            }
        }
    }
}

// ---------------- Y planes -> row-major bf16 YT [16384][800] ----------------
__global__ __launch_bounds__(256) void k_transpose_yh(const float* __restrict__ YHre,
                                                      const float* __restrict__ YHim,
                                                      unsigned short* __restrict__ YT) {
    int ut = blockIdx.x & 7;
    int h = (blockIdx.x >> 3) % 12;
    int b = blockIdx.x / 96;
    int u0 = ut * 128;
    __shared__ unsigned short T[128 * 66];
    int tid = threadIdx.x;
    int planeBase = (b * Hn + h) * NK;
#pragma unroll
    for (int i = 0; i < 33; ++i) {
        int idx = tid + i * 256;        // 0..8447
        int kc = idx >> 7, uo = idx & 127;
        const float* src = (kc & 1) ? YHim : YHre;
        float v = src[(size_t)(planeBase + (kc >> 1)) * 1024 + u0 + uo];
        T[uo * 66 + kc] = f2bf(v);
    }
    __syncthreads();
    unsigned int* out = (unsigned int*)YT;
    for (int i = 0; i < 17; ++i) {
        int idx = tid + i * 256;
        if (idx < 4224) {
            int uo = idx / 33;
            int w = idx - uo * 33;
            unsigned int lo = T[uo * 66 + 2 * w];
            unsigned int hi = T[uo * 66 + 2 * w + 1];
            size_t r = (size_t)b * 1024 + u0 + uo;
            out[r * 400 + h * 33 + w] = lo | (hi << 16);
        }
    }
    // zero-fill padding uints 396..399 (u16 cols 792..799): stale bf16 NaN guard
    if (h == 0) {
        for (int i = tid; i < 512; i += 256) {
            int uo = i >> 2, w = 396 + (i & 3);
            size_t r = (size_t)b * 1024 + u0 + uo;
            out[r * 400 + w] = 0u;
        }
    }
}

// ---------------- inverse DFT + GELU as MFMA GEMM: G = gelu(YT @ Wi^T) bf16 ----------------
__global__ __launch_bounds__(256) void k_mfma_idft(const unsigned short* __restrict__ YT,
                                                   const unsigned short* __restrict__ Wi,
                                                   unsigned short* __restrict__ G) {
    int n0 = blockIdx.x * 128, m0 = blockIdx.y * 128;
    const int K = 800;
    int tid = threadIdx.x;
    int lane = tid & 63, wave = tid >> 6;
    int wr = wave >> 1, wc = wave & 1;
    __shared__ unsigned short As[4096], Bs[4096];
    f32x4 acc[4][4] = {};
    int r0 = tid >> 2, sl = tid & 3;
    int wof = r0 * 32 + ((sl ^ ((r0 >> 1) & 3)) << 3);
    const unsigned short* gA0 = YT + (size_t)(m0 + r0) * K + sl * 8;
    const unsigned short* gB0 = Wi + (size_t)(n0 + r0) * K + sl * 8;
    size_t rstep = (size_t)64 * K;
    int fra[4], frb[4];
    int kg = lane >> 4, cl = lane & 15;
#pragma unroll
    for (int i = 0; i < 4; ++i) {
        int ra = wr * 64 + i * 16 + cl;
        fra[i] = ra * 32 + ((kg ^ ((ra >> 1) & 3)) << 3);
        int rb = wc * 64 + i * 16 + cl;
        frb[i] = rb * 32 + ((kg ^ ((rb >> 1) & 3)) << 3);
    }
    const int nkt = 25;
    s16x8 a0 = *(const s16x8*)(gA0);
    s16x8 a1 = *(const s16x8*)(gA0 + rstep);
    s16x8 b0 = *(const s16x8*)(gB0);
    s16x8 b1 = *(const s16x8*)(gB0 + rstep);
    for (int kt = 0; kt < nkt; ++kt) {
        __syncthreads();
        *(s16x8*)&As[wof] = a0;
        *(s16x8*)&As[wof + 2048] = a1;
        *(s16x8*)&Bs[wof] = b0;
        *(s16x8*)&Bs[wof + 2048] = b1;
        __syncthreads();
        if (kt + 1 < nkt) {
            int ko = (kt + 1) << 5;
            a0 = *(const s16x8*)(gA0 + ko);
            a1 = *(const s16x8*)(gA0 + rstep + ko);
            b0 = *(const s16x8*)(gB0 + ko);
            b1 = *(const s16x8*)(gB0 + rstep + ko);
        }
        s16x8 af[4], bfr[4];
#pragma unroll
        for (int i = 0; i < 4; ++i) af[i] = *(const s16x8*)&As[fra[i]];
#pragma unroll
        for (int i = 0; i < 4; ++i) bfr[i] = *(const s16x8*)&Bs[frb[i]];
#pragma unroll
        for (int mi = 0; mi < 4; ++mi)
#pragma unroll
            for (int ni = 0; ni < 4; ++ni)
                acc[mi][ni] = __builtin_amdgcn_mfma_f32_16x16x32_bf16(af[mi], bfr[ni], acc[mi][ni], 0, 0, 0);
    }
    int rg = lane >> 4;
#pragma unroll
    for (int ni = 0; ni < 4; ++ni) {
        int gn = n0 + wc * 64 + ni * 16 + cl;
#pragma unroll
        for (int mi = 0; mi < 4; ++mi) {
            int gm = m0 + wr * 64 + mi * 16 + rg * 4;
            f32x4 v = acc[mi][ni];
#pragma unroll
            for (int ri = 0; ri < 4; ++ri) {
                float c = v[ri];
                float g = c * 0.5f * (1.0f + erff(c * 0.70710678118f));
                G[(size_t)(gm + ri) * 768 + gn] = f2bf(g);
            }
        }
    }
}

// ---------------- sparse: C_b = (tril(SP)/sigma) @ x_b via xT bf16, MFMA ----------------
__global__ __launch_bounds__(256) void k_mfma_sparse(const unsigned short* __restrict__ SP,
                                                     const unsigned short* __restrict__ XT,
                                                     const float* __restrict__ sigbuf,
                                                     float* __restrict__ C) {
    int bx = blockIdx.x;
    int mt = bx & 7, nt = (bx >> 3) % 6, b = bx / 48;
    int m0 = mt * 128, n0 = nt * 128;
    const unsigned short* Xb = XT + (size_t)b * Dn * Ln;
    float* Cb = C + (size_t)b * Ln * Dn;
    int tid = threadIdx.x;
    int lane = tid & 63, wave = tid >> 6;
    int wr = wave >> 1, wc = wave & 1;
    __shared__ unsigned short As[4096], Bs[4096];
    f32x4 acc[4][4] = {};
    int r0 = tid >> 2, sl = tid & 3;
    int wof = r0 * 32 + ((sl ^ ((r0 >> 1) & 3)) << 3);
    const unsigned short* gA0 = SP + (size_t)(m0 + r0) * Ln + sl * 8;
    const unsigned short* gB0 = Xb + (size_t)(n0 + r0) * Ln + sl * 8;
    size_t rstep = (size_t)64 * Ln;
    int fra[4], frb[4];
    int kg = lane >> 4, cl = lane & 15;
#pragma unroll
    for (int i = 0; i < 4; ++i) {
        int ra = wr * 64 + i * 16 + cl;
        fra[i] = ra * 32 + ((kg ^ ((ra >> 1) & 3)) << 3);
        int rb = wc * 64 + i * 16 + cl;
        frb[i] = rb * 32 + ((kg ^ ((rb >> 1) & 3)) << 3);
    }
    int nkt = mt * 4 + 4;             // only k-tiles with t0 <= m0+127 (tril)
    s16x8 a0 = *(const s16x8*)(gA0);
    s16x8 a1 = *(const s16x8*)(gA0 + rstep);
    s16x8 b0 = *(const s16x8*)(gB0);
    s16x8 b1 = *(const s16x8*)(gB0 + rstep);
    for (int kt = 0; kt < nkt; ++kt) {
        __syncthreads();
        *(s16x8*)&As[wof] = a0;
        *(s16x8*)&As[wof + 2048] = a1;
        *(s16x8*)&Bs[wof] = b0;
        *(s16x8*)&Bs[wof + 2048] = b1;
        __syncthreads();
        if (kt + 1 < nkt) {
            int ko = (kt + 1) << 5;
            a0 = *(const s16x8*)(gA0 + ko);
            a1 = *(const s16x8*)(gA0 + rstep + ko);
            b0 = *(const s16x8*)(gB0 + ko);
            b1 = *(const s16x8*)(gB0 + rstep + ko);
        }
        s16x8 af[4], bfr[4];
#pragma unroll
        for (int i = 0; i < 4; ++i) af[i] = *(const s16x8*)&As[fra[i]];
#pragma unroll
        for (int i = 0; i < 4; ++i) bfr[i] = *(const s16x8*)&Bs[frb[i]];
#pragma unroll
        for (int mi = 0; mi < 4; ++mi)
#pragma unroll
            for (int ni = 0; ni < 4; ++ni)
                acc[mi][ni] = __builtin_amdgcn_mfma_f32_16x16x32_bf16(af[mi], bfr[ni], acc[mi][ni], 0, 0, 0);
    }
    float invs = sigbuf[0];
    int rg = lane >> 4;
#pragma unroll
    for (int ni = 0; ni < 4; ++ni) {
        int gn = n0 + wc * 64 + ni * 16 + cl;
#pragma unroll
        for (int mi = 0; mi < 4; ++mi) {
            int gm = m0 + wr * 64 + mi * 16 + rg * 4;
            f32x4 v = acc[mi][ni];
#pragma unroll
            for (int ri = 0; ri < 4; ++ri)
                Cb[(size_t)(gm + ri) * Dn + gn] = v[ri] * invs;
        }
    }
}

// ---------------- conversions ----------------
__global__ __launch_bounds__(256) void k_cvt_bf16(const float* __restrict__ in,
                                                  unsigned short* __restrict__ out, int n4) {
    int i = blockIdx.x * 256 + threadIdx.x;
    if (i < n4) {
        float4 v = ((const float4*)in)[i];
        u16x4 o;
        o[0] = f2bf(v.x); o[1] = f2bf(v.y); o[2] = f2bf(v.z); o[3] = f2bf(v.w);
        *(u16x4*)&out[(size_t)i * 4] = o;
    }
}

__global__ __launch_bounds__(256) void k_cvt_sp(const float* __restrict__ SP,
                                                unsigned short* __restrict__ O) {
    int s = blockIdx.x;
    int t0 = threadIdx.x * 4;
    float4 v = *(const float4*)&SP[(size_t)s * 1024 + t0];
    u16x4 o;
    o[0] = (t0 + 0 <= s) ? f2bf(v.x) : 0;
    o[1] = (t0 + 1 <= s) ? f2bf(v.y) : 0;
    o[2] = (t0 + 2 <= s) ? f2bf(v.z) : 0;
    o[3] = (t0 + 3 <= s) ? f2bf(v.w) : 0;
    *(u16x4*)&O[(size_t)s * 1024 + t0] = o;
}

// ---------------- x_bf[b][t][d] -> xT[b][d][t] bf16, 64x64 LDS tile ----------------
__global__ __launch_bounds__(256) void k_transpose_x(const unsigned short* __restrict__ X,
                                                     unsigned short* __restrict__ XT) {
    int d0 = blockIdx.x * 64, t0 = blockIdx.y * 64, b = blockIdx.z;
    const unsigned short* Xb = X + (size_t)b * Ln * Dn;
    unsigned short* Tb = XT + (size_t)b * Dn * Ln;
    __shared__ unsigned short tile[64 * 65];
    int tx = threadIdx.x & 63, ty = threadIdx.x >> 6;
#pragma unroll
    for (int i = 0; i < 16; ++i) {
        int t = ty + i * 4;
        tile[t * 65 + tx] = Xb[(size_t)(t0 + t) * Dn + d0 + tx];
    }
    __syncthreads();
#pragma unroll
    for (int i = 0; i < 16; ++i) {
        int d = ty + i * 4;
        Tb[(size_t)(d0 + d) * Ln + t0 + tx] = tile[tx * 65 + d];
    }
}

// ---------------- spectral norm pieces ----------------
__global__ __launch_bounds__(1024) void k_sn_v(const float* __restrict__ Wm,
                                               float* __restrict__ v) {
    int j = threadIdx.x;
    float s = 0.f;
    for (int i = 0; i < 1024; ++i) s += Wm[(size_t)i * 1024 + j];
    s *= 0.03125f;
    __shared__ float red[1024];
    red[j] = s * s; __syncthreads();
    for (int st = 512; st > 0; st >>= 1) {
        if (j < st) red[j] += red[j + st];
        __syncthreads();
    }
    float nrm = sqrtf(red[0]);
    v[j] = s / (nrm + 1e-12f);
}

__global__ __launch_bounds__(64) void k_sn_u(const float* __restrict__ Wm,
                                             const float* __restrict__ v,
                                             float* __restrict__ ur) {
    int i = blockIdx.x;
    int lane = threadIdx.x;
    float s = 0.f;
    for (int j = lane; j < 1024; j += 64) s += Wm[(size_t)i * 1024 + j] * v[j];
#pragma unroll
    for (int off = 32; off > 0; off >>= 1) s += __shfl_down(s, off);
    if (lane == 0) ur[i] = s;
}

__global__ __launch_bounds__(1024) void k_sn_sigma(const float* __restrict__ ur,
                                                   float* __restrict__ sig) {
    int i = threadIdx.x;
    __shared__ float red[1024];
    float u = ur[i];
    red[i] = u * u; __syncthreads();
    for (int st = 512; st > 0; st >>= 1) {
        if (i < st) red[i] += red[i + st];
        __syncthreads();
    }
    if (i == 0) {
        float ss = red[0];
        float sigma = ss / (sqrtf(ss) + 1e-12f);
        sig[0] = 1.0f / sigma;
    }
}

// ---------------- final residual + LayerNorm ----------------
__global__ __launch_bounds__(256) void k_final_ln(const float* __restrict__ CE,
                                                  const float* __restrict__ SE,
                                                  const float* __restrict__ EMB,
                                                  const float* __restrict__ g,
                                                  const float* __restrict__ be,
                                                  float* __restrict__ out) {
    int r = blockIdx.x;
    int tid = threadIdx.x;
    float y[3];
    float s = 0.f;
#pragma unroll
    for (int i = 0; i < 3; ++i) {
        int o = tid + i * 256;
        size_t idx = (size_t)r * 768 + o;
        y[i] = CE[idx] + SE[idx] + EMB[idx];
        s += y[i];
    }
    __shared__ float red[256];
    red[tid] = s; __syncthreads();
    for (int st = 128; st > 0; st >>= 1) {
        if (tid < st) red[tid] += red[tid + st];
        __syncthreads();
    }
    float mu = red[0] * (1.f / 768.f);
    __syncthreads();
    float vs = 0.f;
#pragma unroll
    for (int i = 0; i < 3; ++i) { float d = y[i] - mu; vs += d * d; }
    red[tid] = vs; __syncthreads();
    for (int st = 128; st > 0; st >>= 1) {
        if (tid < st) red[tid] += red[tid + st];
        __syncthreads();
    }
    float var = red[0] * (1.f / 768.f);
    float rstd = rsqrtf(var + 1e-12f);
#pragma unroll
    for (int i = 0; i < 3; ++i) {
        int o = tid + i * 256;
        size_t idx = (size_t)r * 768 + o;
        out[idx] = (y[i] - mu) * rstd * g[o] + be[o];
    }
}

extern "C" void kernel_launch(void* const* d_in, const int* in_sizes, int n_in,
                              void* d_out, int out_size, void* d_ws, size_t ws_size,
                              hipStream_t stream) {
    const float* emb     = (const float*)d_in[0];
    const float* pre_w   = (const float*)d_in[1];
    const float* pre_b   = (const float*)d_in[2];
    const float* psfs    = (const float*)d_in[3];
    const float* post_w  = (const float*)d_in[4];
    const float* post_b  = (const float*)d_in[5];
    const float* spmat   = (const float*)d_in[6];
    const float* ln_g    = (const float*)d_in[7];
    const float* ln_b    = (const float*)d_in[8];
    float* out = (float*)d_out;
    float* ws = (float*)d_ws;

    float* p      = ws + O_P;
    float* psfh   = ws + O_PSFH;
    float* qh     = ws + O_QH;
    float* q      = ws + O_SIG + 8;
    float* XHre   = ws + O_XH;
    float* XHim   = ws + O_XH + 6488064;
    float* YHre   = ws + O_YH;
    float* YHim   = ws + O_YH + 6488064;
    float* spe    = ws + O_SPE;
    float* phf    = ws + O_SPE;                      // alias (dead before spe)
    float* v      = ws + O_V;
    float* urw    = ws + O_UR;
    float* sig    = ws + O_SIG;
    float* CE     = ws + O_YH;                       // after YH planes dead

    unsigned short* x_bf      = (unsigned short*)(ws + O_X);
    unsigned short* Wbig      = (unsigned short*)(ws + O_X + 6291456);
    unsigned short* Wi        = (unsigned short*)(ws + O_X + 6635520);
    unsigned short* YT        = (unsigned short*)(ws + O_XH);            // over dead XH planes
    unsigned short* G_bf      = (unsigned short*)(ws + O_XH + 6553600);
    unsigned short* xT_bf     = (unsigned short*)(ws + O_XH);            // over dead YT
    unsigned short* emb_bf    = (unsigned short*)(ws + O_YH);            // dead before YH planes
    unsigned short* SP_bf     = (unsigned short*)(ws + O_P);             // over dead p
    unsigned short* pre_w_bf  = (unsigned short*)(ws + O_PSFH);          // over dead psfh
    unsigned short* post_w_bf = (unsigned short*)(ws + O_PSFH + 294912);

    // PSF preprocessing
    k_psf_softmax<<<Hn * 64, 256, 0, stream>>>(psfs, p, q);
    k_psf_dft<<<Hn * 1024, 64, 0, stream>>>(p, psfh);
    k_q_dft<<<Hn, 64, 0, stream>>>(q, qh);
    k_tap_fft<<<NHK, 256, 0, stream>>>(psfh, qh, phf);

    // spectral norm scalar
    k_sn_v<<<1, 1024, 0, stream>>>(spmat, v);
    k_sn_u<<<1024, 64, 0, stream>>>(spmat, v, urw);
    k_sn_sigma<<<1, 1024, 0, stream>>>(urw, sig);

    // conversions + DFT matrix builds
    k_cvt_sp<<<1024, 256, 0, stream>>>(spmat, SP_bf);
    k_cvt_bf16<<<576, 256, 0, stream>>>(pre_w, pre_w_bf, 147456);
    k_cvt_bf16<<<576, 256, 0, stream>>>(post_w, post_w_bf, 147456);
    k_cvt_bf16<<<12288, 256, 0, stream>>>(emb, emb_bf, 3145728);
    k_build_wbig<<<896, 256, 0, stream>>>(Wbig);
    k_build_wi<<<768, 256, 0, stream>>>(Wi);

    // pre-projection (MFMA bf16 -> bf16 x)
    k_mfma_abt_bf<<<dim3(6, 128), 256, 0, stream>>>(emb_bf, pre_w_bf, pre_b, x_bf, Bn * Ln, Dn, Dn);

    // head-dim DFT of x as MFMA GEMM -> split re/im planes
    k_mfma_dft<<<dim3(128, 7), 256, 0, stream>>>(Wbig, x_bf, XHre, XHim);

    // causal conv + uniform suffix via circular-2048 FFT (fused-pair stages)
    k_conv_fft<<<Bn * NHK, 256, 0, stream>>>(XHre, XHim, phf, YHre, YHim);

    // Y planes -> row-major bf16 (K-contiguous for idft GEMM)
    k_transpose_yh<<<Bn * Hn * 8, 256, 0, stream>>>(YHre, YHim, YT);

    // inverse DFT + GELU as MFMA GEMM -> G bf16
    k_mfma_idft<<<dim3(6, 128), 256, 0, stream>>>(YT, Wi, G_bf);

    // transpose x -> xT bf16 (over dead YT region)
    k_transpose_x<<<dim3(12, 16, Bn), 256, 0, stream>>>(x_bf, xT_bf);

    // post-projection (MFMA bf16) -> CE f32 (over dead YH planes)
    k_mfma_abt<<<dim3(6, 128), 256, 0, stream>>>(G_bf, post_w_bf, post_b, CE, Bn * Ln, Dn, Dn);

    // sparse branch (MFMA bf16, triangular k-loop)
    k_mfma_sparse<<<768, 256, 0, stream>>>(SP_bf, xT_bf, sig, spe);

    // residual + LayerNorm
    k_final_ln<<<Bn * Ln, 256, 0, stream>>>(CE, spe, emb, ln_g, ln_b, out);
}

// Round 7
// 397.181 us; speedup vs baseline: 8.0004x; 1.1499x over previous
//
#include <hip/hip_runtime.h>
#include <math.h>

// Problem constants
#define Bn 16
#define Ln 1024
#define Dn 768
#define Hn 12
#define PHDn 64
#define NK 33                 // Hermitian bins for 64-pt DFT (k=0..32)
#define NHK (Hn * NK)         // 396
#define TWOPI_64 0.09817477042468103f   // 2*pi/64

typedef short s16x8 __attribute__((ext_vector_type(8)));
typedef float f32x4 __attribute__((ext_vector_type(4)));
typedef unsigned short u16x4 __attribute__((ext_vector_type(4)));

__device__ __forceinline__ unsigned short f2bf(float f) {
    unsigned int u = __float_as_uint(f);
    unsigned int r = (u + 0x7FFFu + ((u >> 16) & 1u)) >> 16;
    return (unsigned short)r;
}

__device__ __forceinline__ float2 cmul(float2 a, float2 b) {
    return make_float2(a.x * b.x - a.y * b.y, a.x * b.y + a.y * b.x);
}

// ---------------- workspace layout (float offsets) ----------------
static const size_t O_P    = 0;          // psf taps; later SP_bf
static const size_t O_PSFH = 786432;     // psf-hat; later pre_w_bf + post_w_bf
static const size_t O_PART = 1376256;    // sn column-sum partials [64][1024] (dead psfh tail)
static const size_t O_QH   = 1597440;    // q-hat
static const size_t O_X    = 1598240;    // x_bf (6291456) + Wbig (344064) + Wi (307200)
static const size_t O_XH   = 14181152;   // XHre/XHim planes; later YT + G_bf; later xT_bf
static const size_t O_YH   = 27157280;   // emb_bf early; YHre/YHim planes; later CE f32
static const size_t O_SPE  = 40146080;   // phf early; sparse_emb later
static const size_t O_V    = 52728992;
static const size_t O_UR   = 52730016;
static const size_t O_SIG  = 52731040;   // inv_sigma + q[768] after

// ---------------- psf softmax over 2047 taps (1023 are zeros) ----------------
__global__ __launch_bounds__(256) void k_psf_softmax(const float* __restrict__ psfs,
                                                     float* __restrict__ p,
                                                     float* __restrict__ q) {
    int he = blockIdx.x;            // h*64+e
    int h = he >> 6, e = he & 63;
    int tid = threadIdx.x;
    float ev[4];
    float s = 0.f;
#pragma unroll
    for (int i = 0; i < 4; ++i) {
        int t = tid + 256 * i;
        float v = psfs[((size_t)h * 2047 + t) * 64 + e];
        ev[i] = expf(v);
        s += ev[i];
    }
    __shared__ float red[256];
    red[tid] = s; __syncthreads();
    for (int st = 128; st > 0; st >>= 1) {
        if (tid < st) red[tid] += red[tid + st];
        __syncthreads();
    }
    float denom = red[0] + 1023.0f;
    float inv = 1.0f / denom;
#pragma unroll
    for (int i = 0; i < 4; ++i) {
        int t = tid + 256 * i;
        p[((size_t)h * 1024 + t) * 64 + e] = ev[i] * inv;
    }
    if (tid == 0) q[he] = inv;
}

// ---------------- DFT over head-dim of psf taps ----------------
__global__ __launch_bounds__(64) void k_psf_dft(const float* __restrict__ p,
                                                float* __restrict__ psfh) {
    int ht = blockIdx.x;            // h*1024+t
    int h = ht >> 10, t = ht & 1023;
    int tid = threadIdx.x;          // 64
    __shared__ float pv[64], cc[64], ssn[64];
    pv[tid] = p[((size_t)h * 1024 + t) * 64 + tid];
    float ang = TWOPI_64 * tid;
    cc[tid] = cosf(ang); ssn[tid] = sinf(ang);
    __syncthreads();
    if (tid < NK) {
        float re = 0.f, im = 0.f;
#pragma unroll 8
        for (int e = 0; e < 64; ++e) {
            int j = (tid * e) & 63;
            float v = pv[e];
            re += v * cc[j];
            im -= v * ssn[j];
        }
        size_t o = (((size_t)h * NK + tid) * 1024 + t) * 2;
        psfh[o] = re; psfh[o + 1] = im;
    }
}

// ---------------- DFT of uniform tap value q[h][e] ----------------
__global__ __launch_bounds__(64) void k_q_dft(const float* __restrict__ q,
                                              float* __restrict__ qh) {
    int h = blockIdx.x;
    int tid = threadIdx.x;
    __shared__ float qv[64], cc[64], ssn[64];
    qv[tid] = q[h * 64 + tid];
    float ang = TWOPI_64 * tid;
    cc[tid] = cosf(ang); ssn[tid] = sinf(ang);
    __syncthreads();
    if (tid < NK) {
        float re = 0.f, im = 0.f;
        for (int e = 0; e < 64; ++e) {
            int j = (tid * e) & 63;
            re += qv[e] * cc[j];
            im -= qv[e] * ssn[j];
        }
        qh[(h * NK + tid) * 2] = re;
        qh[(h * NK + tid) * 2 + 1] = im;
    }
}

__device__ __forceinline__ void build_twiddles(float2* tw, int tid) {
#pragma unroll
    for (int it = 0; it < 4; ++it) {
        int j = tid + it * 256;
        float a = (float)j * 3.0679615757712823e-3f;   // 2*pi/2048
        float sv, cv;
        __sincosf(a, &sv, &cv);
        tw[j] = make_float2(cv, -sv);
    }
}

// ---------------- fused radix-2 stage-pair (stages s,s+1 of 2048-pt Stockham) ----------------
__device__ __forceinline__ void fft_pair(const float2* __restrict__ X,
                                         float2* __restrict__ Y,
                                         const float2* __restrict__ tw,
                                         int tid, int m) {
#pragma unroll
    for (int it = 0; it < 2; ++it) {
        int i = tid + it * 256;
        int r = i & (m - 1);
        int am = i - r;
        float2 w1 = tw[am];
        float2 w1b = make_float2(w1.y, -w1.x);   // tw[am+512] = -j*w1
        float2 w2 = tw[2 * am];
        float2 x0 = X[i], x1 = X[i + 512], x2 = X[i + 1024], x3 = X[i + 1536];
        float2 y0 = make_float2(x0.x + x2.x, x0.y + x2.y);
        float2 y1 = cmul(make_float2(x0.x - x2.x, x0.y - x2.y), w1);
        float2 y2 = make_float2(x1.x + x3.x, x1.y + x3.y);
        float2 y3 = cmul(make_float2(x1.x - x3.x, x1.y - x3.y), w1b);
        int o = 4 * am + r;
        Y[o] = make_float2(y0.x + y2.x, y0.y + y2.y);
        Y[o + m] = make_float2(y1.x + y3.x, y1.y + y3.y);
        Y[o + 2 * m] = cmul(make_float2(y0.x - y2.x, y0.y - y2.y), w2);
        Y[o + 3 * m] = cmul(make_float2(y1.x - y3.x, y1.y - y3.y), w2);
    }
}

// ---------------- FFT of tap vector per (h,k): taps at [0,1024), q at [1025,2048) ----------------
__global__ __launch_bounds__(256) void k_tap_fft(const float* __restrict__ psfh,
                                                 const float* __restrict__ qh,
                                                 float* __restrict__ phf) {
    __shared__ float2 A[2048], B[2048], tw[1024];
    int hk = blockIdx.x, tid = threadIdx.x;
    build_twiddles(tw, tid);
    float2 qv = make_float2(qh[hk * 2], qh[hk * 2 + 1]);
    const float2* Pg = (const float2*)(psfh + (size_t)hk * 2048);
    __syncthreads();
#pragma unroll
    for (int it = 0; it < 2; ++it) {
        int i = tid + it * 256;
        float2 x0 = Pg[i], x1 = Pg[i + 512];
        float2 x2 = (i == 0) ? make_float2(0.f, 0.f) : qv;
        float2 x3 = qv;
        float2 w1 = tw[i];
        float2 w1b = make_float2(w1.y, -w1.x);
        float2 w2 = tw[2 * i];
        float2 y0 = make_float2(x0.x + x2.x, x0.y + x2.y);
        float2 y1 = cmul(make_float2(x0.x - x2.x, x0.y - x2.y), w1);
        float2 y2 = make_float2(x1.x + x3.x, x1.y + x3.y);
        float2 y3 = cmul(make_float2(x1.x - x3.x, x1.y - x3.y), w1b);
        int o = 4 * i;
        A[o] = make_float2(y0.x + y2.x, y0.y + y2.y);
        A[o + 1] = make_float2(y1.x + y3.x, y1.y + y3.y);
        A[o + 2] = cmul(make_float2(y0.x - y2.x, y0.y - y2.y), w2);
        A[o + 3] = cmul(make_float2(y1.x - y3.x, y1.y - y3.y), w2);
    }
    __syncthreads();
    fft_pair(A, B, tw, tid, 4);   __syncthreads();
    fft_pair(B, A, tw, tid, 16);  __syncthreads();
    fft_pair(A, B, tw, tid, 64);  __syncthreads();
    fft_pair(B, A, tw, tid, 256); __syncthreads();
    float2* out = (float2*)(phf + (size_t)hk * 4096);
#pragma unroll
    for (int it = 0; it < 4; ++it) {
        int t = tid + it * 256;
        float2 lo = A[t], hi = A[t + 1024];
        out[t] = make_float2(lo.x + hi.x, lo.y + hi.y);
        out[t + 1024] = make_float2(lo.x - hi.x, lo.y - hi.y);
    }
}

// ---------------- per-(b,h,k) conv via circular-2048 FFT, fused-pair stages ----------------
__global__ __launch_bounds__(256) void k_conv_fft(const float* __restrict__ XHre,
                                                  const float* __restrict__ XHim,
                                                  const float* __restrict__ PHF,
                                                  float* __restrict__ YHre,
                                                  float* __restrict__ YHim) {
    __shared__ float2 A[2048], B[2048], tw[1024];
    int bhk = blockIdx.x, tid = threadIdx.x;
    int hk = bhk % NHK;
    build_twiddles(tw, tid);
    const float* Rg = XHre + (size_t)bhk * 1024;
    const float* Ig = XHim + (size_t)bhk * 1024;
    __syncthreads();
#pragma unroll
    for (int it = 0; it < 2; ++it) {
        int i = tid + it * 256;
        float2 x0 = make_float2(Rg[i], Ig[i]);
        float2 x1 = make_float2(Rg[i + 512], Ig[i + 512]);
        float2 w1 = tw[i];
        float2 w1b = make_float2(w1.y, -w1.x);
        float2 w2 = tw[2 * i];
        float2 y1 = cmul(x0, w1);
        float2 y3 = cmul(x1, w1b);
        int o = 4 * i;
        A[o] = make_float2(x0.x + x1.x, x0.y + x1.y);
        A[o + 1] = make_float2(y1.x + y3.x, y1.y + y3.y);
        A[o + 2] = cmul(make_float2(x0.x - x1.x, x0.y - x1.y), w2);
        A[o + 3] = cmul(make_float2(y1.x - y3.x, y1.y - y3.y), w2);
    }
    __syncthreads();
    fft_pair(A, B, tw, tid, 4);   __syncthreads();
    fft_pair(B, A, tw, tid, 16);  __syncthreads();
    fft_pair(A, B, tw, tid, 64);  __syncthreads();
    fft_pair(B, A, tw, tid, 256); __syncthreads();
    const float2* P = (const float2*)(PHF + (size_t)hk * 4096);
    float2 q[8];
#pragma unroll
    for (int it = 0; it < 4; ++it) {
        int t = tid + it * 256;
        float2 lo = A[t], hi = A[t + 1024];
        float2 fl = make_float2(lo.x + hi.x, lo.y + hi.y);
        float2 fh = make_float2(lo.x - hi.x, lo.y - hi.y);
        float2 vl = cmul(fl, P[t]);
        float2 vh = cmul(fh, P[t + 1024]);
        q[it] = make_float2(vl.x, -vl.y);
        q[it + 4] = make_float2(vh.x, -vh.y);
    }
#pragma unroll
    for (int it = 0; it < 2; ++it) {
        int i = tid + it * 256;
        float2 x0 = q[it], x1 = q[it + 2], x2 = q[it + 4], x3 = q[it + 6];
        float2 w1 = tw[i];
        float2 w1b = make_float2(w1.y, -w1.x);
        float2 w2 = tw[2 * i];
        float2 y0 = make_float2(x0.x + x2.x, x0.y + x2.y);
        float2 y1 = cmul(make_float2(x0.x - x2.x, x0.y - x2.y), w1);
        float2 y2 = make_float2(x1.x + x3.x, x1.y + x3.y);
        float2 y3 = cmul(make_float2(x1.x - x3.x, x1.y - x3.y), w1b);
        int o = 4 * i;
        B[o] = make_float2(y0.x + y2.x, y0.y + y2.y);
        B[o + 1] = make_float2(y1.x + y3.x, y1.y + y3.y);
        B[o + 2] = cmul(make_float2(y0.x - y2.x, y0.y - y2.y), w2);
        B[o + 3] = cmul(make_float2(y1.x - y3.x, y1.y - y3.y), w2);
    }
    __syncthreads();
    fft_pair(B, A, tw, tid, 4);   __syncthreads();
    fft_pair(A, B, tw, tid, 16);  __syncthreads();
    fft_pair(B, A, tw, tid, 64);  __syncthreads();
    fft_pair(A, B, tw, tid, 256); __syncthreads();
    const float inv_n = 1.0f / 2048.0f;
#pragma unroll
    for (int it = 0; it < 4; ++it) {
        int s = tid + it * 256;
        float2 lo = B[s], hi = B[s + 1024];
        YHre[(size_t)bhk * 1024 + s] = (lo.x + hi.x) * inv_n;
        YHim[(size_t)bhk * 1024 + s] = -(lo.y + hi.y) * inv_n;
    }
}

// ---------------- build block-diagonal forward DFT matrix Wbig [896][768] bf16 ----------------
__global__ __launch_bounds__(256) void k_build_wbig(unsigned short* __restrict__ W) {
    int m = blockIdx.x;                  // 0..895
    int tid = threadIdx.x;
    int h = m / 66, rem = m - h * 66;
    int k = rem >> 1, od = rem & 1;
    bool valid = (m < 792);
#pragma unroll
    for (int i = 0; i < 3; ++i) {
        int d = tid + i * 256;
        int dh = d >> 6, dd = d & 63;
        float val = 0.f;
        if (valid && dh == h) {
            int j = (k * dd) & 63;
            float ang = TWOPI_64 * (float)j;
            val = od ? -sinf(ang) : cosf(ang);
        }
        W[(size_t)m * 768 + d] = f2bf(val);
    }
}

// ---------------- build inverse DFT matrix Wi [768][800] bf16 (1/64 + Hermitian 2x folded) ----------------
__global__ __launch_bounds__(256) void k_build_wi(unsigned short* __restrict__ W) {
    int hd = blockIdx.x;                 // 0..767
    int tid = threadIdx.x;
    int h = hd >> 6, d = hd & 63;
#pragma unroll
    for (int i = 0; i < 4; ++i) {
        int col = tid + i * 256;
        if (col < 800) {
            float val = 0.f;
            if (col < 792) {
                int h2 = col / 66, rem = col - h2 * 66;
                int k = rem >> 1, od = rem & 1;
                if (h2 == h) {
                    int j = (k * d) & 63;
                    float ang = TWOPI_64 * (float)j;
                    float ck = ((k == 0) || (k == 32)) ? (1.f / 64.f) : (2.f / 64.f);
                    val = od ? -sinf(ang) * ck : cosf(ang) * ck;
                }
            }
            W[(size_t)hd * 800 + col] = f2bf(val);
        }
    }
}

// ---------------- bf16 MFMA GEMM: C(f32) = A@W^T + bias ----------------
__global__ __launch_bounds__(256) void k_mfma_abt(const unsigned short* __restrict__ A,
                                                  const unsigned short* __restrict__ W,
                                                  const float* __restrict__ bias,
                                                  float* __restrict__ C,
                                                  int M, int N, int K) {
    int n0 = blockIdx.x * 128, m0 = blockIdx.y * 128;
    int tid = threadIdx.x;
    int lane = tid & 63, wave = tid >> 6;
    int wr = wave >> 1, wc = wave & 1;
    __shared__ unsigned short As[4096], Bs[4096];
    f32x4 acc[4][4] = {};
    int r0 = tid >> 2, sl = tid & 3;
    int wof = r0 * 32 + ((sl ^ ((r0 >> 1) & 3)) << 3);
    const unsigned short* gA0 = A + (size_t)(m0 + r0) * K + sl * 8;
    const unsigned short* gB0 = W + (size_t)(n0 + r0) * K + sl * 8;
    size_t rstep = (size_t)64 * K;
    int fra[4], frb[4];
    int kg = lane >> 4, cl = lane & 15;
#pragma unroll
    for (int i = 0; i < 4; ++i) {
        int ra = wr * 64 + i * 16 + cl;
        fra[i] = ra * 32 + ((kg ^ ((ra >> 1) & 3)) << 3);
        int rb = wc * 64 + i * 16 + cl;
        frb[i] = rb * 32 + ((kg ^ ((rb >> 1) & 3)) << 3);
    }
    int nkt = K >> 5;
    s16x8 a0 = *(const s16x8*)(gA0);
    s16x8 a1 = *(const s16x8*)(gA0 + rstep);
    s16x8 b0 = *(const s16x8*)(gB0);
    s16x8 b1 = *(const s16x8*)(gB0 + rstep);
    for (int kt = 0; kt < nkt; ++kt) {
        __syncthreads();
        *(s16x8*)&As[wof] = a0;
        *(s16x8*)&As[wof + 2048] = a1;
        *(s16x8*)&Bs[wof] = b0;
        *(s16x8*)&Bs[wof + 2048] = b1;
        __syncthreads();
        if (kt + 1 < nkt) {
            int ko = (kt + 1) << 5;
            a0 = *(const s16x8*)(gA0 + ko);
            a1 = *(const s16x8*)(gA0 + rstep + ko);
            b0 = *(const s16x8*)(gB0 + ko);
            b1 = *(const s16x8*)(gB0 + rstep + ko);
        }
        s16x8 af[4], bfr[4];
#pragma unroll
        for (int i = 0; i < 4; ++i) af[i] = *(const s16x8*)&As[fra[i]];
#pragma unroll
        for (int i = 0; i < 4; ++i) bfr[i] = *(const s16x8*)&Bs[frb[i]];
#pragma unroll
        for (int mi = 0; mi < 4; ++mi)
#pragma unroll
            for (int ni = 0; ni < 4; ++ni)
                acc[mi][ni] = __builtin_amdgcn_mfma_f32_16x16x32_bf16(af[mi], bfr[ni], acc[mi][ni], 0, 0, 0);
    }
    int rg = lane >> 4;
#pragma unroll
    for (int ni = 0; ni < 4; ++ni) {
        int gn = n0 + wc * 64 + ni * 16 + cl;
        float bv = bias ? bias[gn] : 0.f;
#pragma unroll
        for (int mi = 0; mi < 4; ++mi) {
            int gm = m0 + wr * 64 + mi * 16 + rg * 4;
            f32x4 v = acc[mi][ni];
#pragma unroll
            for (int ri = 0; ri < 4; ++ri)
                C[(size_t)(gm + ri) * N + gn] = v[ri] + bv;
        }
    }
}

// ---------------- bf16 MFMA GEMM with bf16 output (pre-projection) ----------------
__global__ __launch_bounds__(256) void k_mfma_abt_bf(const unsigned short* __restrict__ A,
                                                     const unsigned short* __restrict__ W,
                                                     const float* __restrict__ bias,
                                                     unsigned short* __restrict__ C,
                                                     int M, int N, int K) {
    int n0 = blockIdx.x * 128, m0 = blockIdx.y * 128;
    int tid = threadIdx.x;
    int lane = tid & 63, wave = tid >> 6;
    int wr = wave >> 1, wc = wave & 1;
    __shared__ unsigned short As[4096], Bs[4096];
    f32x4 acc[4][4] = {};
    int r0 = tid >> 2, sl = tid & 3;
    int wof = r0 * 32 + ((sl ^ ((r0 >> 1) & 3)) << 3);
    const unsigned short* gA0 = A + (size_t)(m0 + r0) * K + sl * 8;
    const unsigned short* gB0 = W + (size_t)(n0 + r0) * K + sl * 8;
    size_t rstep = (size_t)64 * K;
    int fra[4], frb[4];
    int kg = lane >> 4, cl = lane & 15;
#pragma unroll
    for (int i = 0; i < 4; ++i) {
        int ra = wr * 64 + i * 16 + cl;
        fra[i] = ra * 32 + ((kg ^ ((ra >> 1) & 3)) << 3);
        int rb = wc * 64 + i * 16 + cl;
        frb[i] = rb * 32 + ((kg ^ ((rb >> 1) & 3)) << 3);
    }
    int nkt = K >> 5;
    s16x8 a0 = *(const s16x8*)(gA0);
    s16x8 a1 = *(const s16x8*)(gA0 + rstep);
    s16x8 b0 = *(const s16x8*)(gB0);
    s16x8 b1 = *(const s16x8*)(gB0 + rstep);
    for (int kt = 0; kt < nkt; ++kt) {
        __syncthreads();
        *(s16x8*)&As[wof] = a0;
        *(s16x8*)&As[wof + 2048] = a1;
        *(s16x8*)&Bs[wof] = b0;
        *(s16x8*)&Bs[wof + 2048] = b1;
        __syncthreads();
        if (kt + 1 < nkt) {
            int ko = (kt + 1) << 5;
            a0 = *(const s16x8*)(gA0 + ko);
            a1 = *(const s16x8*)(gA0 + rstep + ko);
            b0 = *(const s16x8*)(gB0 + ko);
            b1 = *(const s16x8*)(gB0 + rstep + ko);
        }
        s16x8 af[4], bfr[4];
#pragma unroll
        for (int i = 0; i < 4; ++i) af[i] = *(const s16x8*)&As[fra[i]];
#pragma unroll
        for (int i = 0; i < 4; ++i) bfr[i] = *(const s16x8*)&Bs[frb[i]];
#pragma unroll
        for (int mi = 0; mi < 4; ++mi)
#pragma unroll
            for (int ni = 0; ni < 4; ++ni)
                acc[mi][ni] = __builtin_amdgcn_mfma_f32_16x16x32_bf16(af[mi], bfr[ni], acc[mi][ni], 0, 0, 0);
    }
    int rg = lane >> 4;
#pragma unroll
    for (int ni = 0; ni < 4; ++ni) {
        int gn = n0 + wc * 64 + ni * 16 + cl;
        float bv = bias ? bias[gn] : 0.f;
#pragma unroll
        for (int mi = 0; mi < 4; ++mi) {
            int gm = m0 + wr * 64 + mi * 16 + rg * 4;
            f32x4 v = acc[mi][ni];
#pragma unroll
            for (int ri = 0; ri < 4; ++ri)
                C[(size_t)(gm + ri) * N + gn] = f2bf(v[ri] + bv);
        }
    }
}

// ---------------- forward head-dim DFT as MFMA GEMM: planes = Wbig @ x^T ----------------
__global__ __launch_bounds__(256) void k_mfma_dft(const unsigned short* __restrict__ Wb,
                                                  const unsigned short* __restrict__ Xb,
                                                  float* __restrict__ XHre,
                                                  float* __restrict__ XHim) {
    int n0 = blockIdx.x * 128, m0 = blockIdx.y * 128;
    const int K = 768;
    int tid = threadIdx.x;
    int lane = tid & 63, wave = tid >> 6;
    int wr = wave >> 1, wc = wave & 1;
    __shared__ unsigned short As[4096], Bs[4096];
    f32x4 acc[4][4] = {};
    int r0 = tid >> 2, sl = tid & 3;
    int wof = r0 * 32 + ((sl ^ ((r0 >> 1) & 3)) << 3);
    const unsigned short* gA0 = Wb + (size_t)(m0 + r0) * K + sl * 8;
    const unsigned short* gB0 = Xb + (size_t)(n0 + r0) * K + sl * 8;
    size_t rstep = (size_t)64 * K;
    int fra[4], frb[4];
    int kg = lane >> 4, cl = lane & 15;
#pragma unroll
    for (int i = 0; i < 4; ++i) {
        int ra = wr * 64 + i * 16 + cl;
        fra[i] = ra * 32 + ((kg ^ ((ra >> 1) & 3)) << 3);
        int rb = wc * 64 + i * 16 + cl;
        frb[i] = rb * 32 + ((kg ^ ((rb >> 1) & 3)) << 3);
    }
    const int nkt = 24;
    s16x8 a0 = *(const s16x8*)(gA0);
    s16x8 a1 = *(const s16x8*)(gA0 + rstep);
    s16x8 b0 = *(const s16x8*)(gB0);
    s16x8 b1 = *(const s16x8*)(gB0 + rstep);
    for (int kt = 0; kt < nkt; ++kt) {
        __syncthreads();
        *(s16x8*)&As[wof] = a0;
        *(s16x8*)&As[wof + 2048] = a1;
        *(s16x8*)&Bs[wof] = b0;
        *(s16x8*)&Bs[wof + 2048] = b1;
        __syncthreads();
        if (kt + 1 < nkt) {
            int ko = (kt + 1) << 5;
            a0 = *(const s16x8*)(gA0 + ko);
            a1 = *(const s16x8*)(gA0 + rstep + ko);
            b0 = *(const s16x8*)(gB0 + ko);
            b1 = *(const s16x8*)(gB0 + rstep + ko);
        }
        s16x8 af[4], bfr[4];
#pragma unroll
        for (int i = 0; i < 4; ++i) af[i] = *(const s16x8*)&As[fra[i]];
#pragma unroll
        for (int i = 0; i < 4; ++i) bfr[i] = *(const s16x8*)&Bs[frb[i]];
#pragma unroll
        for (int mi = 0; mi < 4; ++mi)
#pragma unroll
            for (int ni = 0; ni < 4; ++ni)
                acc[mi][ni] = __builtin_amdgcn_mfma_f32_16x16x32_bf16(af[mi], bfr[ni], acc[mi][ni], 0, 0, 0);
    }
    int rg = lane >> 4;
#pragma unroll
    for (int ni = 0; ni < 4; ++ni) {
        int gn = n0 + wc * 64 + ni * 16 + cl;   // global row index of x
        int b = gn >> 10, u = gn & 1023;
#pragma unroll
        for (int mi = 0; mi < 4; ++mi) {
            int gmb = m0 + wr * 64 + mi * 16 + rg * 4;
            f32x4 v = acc[mi][ni];
#pragma unroll
            for (int ri = 0; ri < 4; ++ri) {
                int m = gmb + ri;
                if (m < 792) {
                    int h = m / 66, rem = m - h * 66;
                    size_t plane = (size_t)(b * Hn + h) * NK + (rem >> 1);
                    float* dst = (rem & 1) ? XHim : XHre;
                    dst[plane * 1024 + u] = v[ri];
                }
            }
        }
    }
}

// ---------------- Y planes -> row-major bf16 YT [16384][800] ----------------
__global__ __launch_bounds__(256) void k_transpose_yh(const float* __restrict__ YHre,
                                                      const float* __restrict__ YHim,
                                                      unsigned short* __restrict__ YT) {
    int ut = blockIdx.x & 7;
    int h = (blockIdx.x >> 3) % 12;
    int b = blockIdx.x / 96;
    int u0 = ut * 128;
    __shared__ unsigned short T[128 * 66];
    int tid = threadIdx.x;
    int planeBase = (b * Hn + h) * NK;
#pragma unroll
    for (int i = 0; i < 33; ++i) {
        int idx = tid + i * 256;        // 0..8447
        int kc = idx >> 7, uo = idx & 127;
        const float* src = (kc & 1) ? YHim : YHre;
        float v = src[(size_t)(planeBase + (kc >> 1)) * 1024 + u0 + uo];
        T[uo * 66 + kc] = f2bf(v);
    }
    __syncthreads();
    unsigned int* out = (unsigned int*)YT;
    for (int i = 0; i < 17; ++i) {
        int idx = tid + i * 256;
        if (idx < 4224) {
            int uo = idx / 33;
            int w = idx - uo * 33;
            unsigned int lo = T[uo * 66 + 2 * w];
            unsigned int hi = T[uo * 66 + 2 * w + 1];
            size_t r = (size_t)b * 1024 + u0 + uo;
            out[r * 400 + h * 33 + w] = lo | (hi << 16);
        }
    }
    // zero-fill padding uints 396..399 (u16 cols 792..799): stale bf16 NaN guard
    if (h == 0) {
        for (int i = tid; i < 512; i += 256) {
            int uo = i >> 2, w = 396 + (i & 3);
            size_t r = (size_t)b * 1024 + u0 + uo;
            out[r * 400 + w] = 0u;
        }
    }
}

// ---------------- inverse DFT + GELU as MFMA GEMM: G = gelu(YT @ Wi^T) bf16 ----------------
__global__ __launch_bounds__(256) void k_mfma_idft(const unsigned short* __restrict__ YT,
                                                   const unsigned short* __restrict__ Wi,
                                                   unsigned short* __restrict__ G) {
    int n0 = blockIdx.x * 128, m0 = blockIdx.y * 128;
    const int K = 800;
    int tid = threadIdx.x;
    int lane = tid & 63, wave = tid >> 6;
    int wr = wave >> 1, wc = wave & 1;
    __shared__ unsigned short As[4096], Bs[4096];
    f32x4 acc[4][4] = {};
    int r0 = tid >> 2, sl = tid & 3;
    int wof = r0 * 32 + ((sl ^ ((r0 >> 1) & 3)) << 3);
    const unsigned short* gA0 = YT + (size_t)(m0 + r0) * K + sl * 8;
    const unsigned short* gB0 = Wi + (size_t)(n0 + r0) * K + sl * 8;
    size_t rstep = (size_t)64 * K;
    int fra[4], frb[4];
    int kg = lane >> 4, cl = lane & 15;
#pragma unroll
    for (int i = 0; i < 4; ++i) {
        int ra = wr * 64 + i * 16 + cl;
        fra[i] = ra * 32 + ((kg ^ ((ra >> 1) & 3)) << 3);
        int rb = wc * 64 + i * 16 + cl;
        frb[i] = rb * 32 + ((kg ^ ((rb >> 1) & 3)) << 3);
    }
    const int nkt = 25;
    s16x8 a0 = *(const s16x8*)(gA0);
    s16x8 a1 = *(const s16x8*)(gA0 + rstep);
    s16x8 b0 = *(const s16x8*)(gB0);
    s16x8 b1 = *(const s16x8*)(gB0 + rstep);
    for (int kt = 0; kt < nkt; ++kt) {
        __syncthreads();
        *(s16x8*)&As[wof] = a0;
        *(s16x8*)&As[wof + 2048] = a1;
        *(s16x8*)&Bs[wof] = b0;
        *(s16x8*)&Bs[wof + 2048] = b1;
        __syncthreads();
        if (kt + 1 < nkt) {
            int ko = (kt + 1) << 5;
            a0 = *(const s16x8*)(gA0 + ko);
            a1 = *(const s16x8*)(gA0 + rstep + ko);
            b0 = *(const s16x8*)(gB0 + ko);
            b1 = *(const s16x8*)(gB0 + rstep + ko);
        }
        s16x8 af[4], bfr[4];
#pragma unroll
        for (int i = 0; i < 4; ++i) af[i] = *(const s16x8*)&As[fra[i]];
#pragma unroll
        for (int i = 0; i < 4; ++i) bfr[i] = *(const s16x8*)&Bs[frb[i]];
#pragma unroll
        for (int mi = 0; mi < 4; ++mi)
#pragma unroll
            for (int ni = 0; ni < 4; ++ni)
                acc[mi][ni] = __builtin_amdgcn_mfma_f32_16x16x32_bf16(af[mi], bfr[ni], acc[mi][ni], 0, 0, 0);
    }
    int rg = lane >> 4;
#pragma unroll
    for (int ni = 0; ni < 4; ++ni) {
        int gn = n0 + wc * 64 + ni * 16 + cl;
#pragma unroll
        for (int mi = 0; mi < 4; ++mi) {
            int gm = m0 + wr * 64 + mi * 16 + rg * 4;
            f32x4 v = acc[mi][ni];
#pragma unroll
            for (int ri = 0; ri < 4; ++ri) {
                float c = v[ri];
                float g = c * 0.5f * (1.0f + erff(c * 0.70710678118f));
                G[(size_t)(gm + ri) * 768 + gn] = f2bf(g);
            }
        }
    }
}

// ---------------- sparse: C_b = (tril(SP)/sigma) @ x_b via xT bf16, MFMA ----------------
__global__ __launch_bounds__(256) void k_mfma_sparse(const unsigned short* __restrict__ SP,
                                                     const unsigned short* __restrict__ XT,
                                                     const float* __restrict__ sigbuf,
                                                     float* __restrict__ C) {
    int bx = blockIdx.x;
    int mt = bx & 7, nt = (bx >> 3) % 6, b = bx / 48;
    int m0 = mt * 128, n0 = nt * 128;
    const unsigned short* Xb = XT + (size_t)b * Dn * Ln;
    float* Cb = C + (size_t)b * Ln * Dn;
    int tid = threadIdx.x;
    int lane = tid & 63, wave = tid >> 6;
    int wr = wave >> 1, wc = wave & 1;
    __shared__ unsigned short As[4096], Bs[4096];
    f32x4 acc[4][4] = {};
    int r0 = tid >> 2, sl = tid & 3;
    int wof = r0 * 32 + ((sl ^ ((r0 >> 1) & 3)) << 3);
    const unsigned short* gA0 = SP + (size_t)(m0 + r0) * Ln + sl * 8;
    const unsigned short* gB0 = Xb + (size_t)(n0 + r0) * Ln + sl * 8;
    size_t rstep = (size_t)64 * Ln;
    int fra[4], frb[4];
    int kg = lane >> 4, cl = lane & 15;
#pragma unroll
    for (int i = 0; i < 4; ++i) {
        int ra = wr * 64 + i * 16 + cl;
        fra[i] = ra * 32 + ((kg ^ ((ra >> 1) & 3)) << 3);
        int rb = wc * 64 + i * 16 + cl;
        frb[i] = rb * 32 + ((kg ^ ((rb >> 1) & 3)) << 3);
    }
    int nkt = mt * 4 + 4;             // only k-tiles with t0 <= m0+127 (tril)
    s16x8 a0 = *(const s16x8*)(gA0);
    s16x8 a1 = *(const s16x8*)(gA0 + rstep);
    s16x8 b0 = *(const s16x8*)(gB0);
    s16x8 b1 = *(const s16x8*)(gB0 + rstep);
    for (int kt = 0; kt < nkt; ++kt) {
        __syncthreads();
        *(s16x8*)&As[wof] = a0;
        *(s16x8*)&As[wof + 2048] = a1;
        *(s16x8*)&Bs[wof] = b0;
        *(s16x8*)&Bs[wof + 2048] = b1;
        __syncthreads();
        if (kt + 1 < nkt) {
            int ko = (kt + 1) << 5;
            a0 = *(const s16x8*)(gA0 + ko);
            a1 = *(const s16x8*)(gA0 + rstep + ko);
            b0 = *(const s16x8*)(gB0 + ko);
            b1 = *(const s16x8*)(gB0 + rstep + ko);
        }
        s16x8 af[4], bfr[4];
#pragma unroll
        for (int i = 0; i < 4; ++i) af[i] = *(const s16x8*)&As[fra[i]];
#pragma unroll
        for (int i = 0; i < 4; ++i) bfr[i] = *(const s16x8*)&Bs[frb[i]];
#pragma unroll
        for (int mi = 0; mi < 4; ++mi)
#pragma unroll
            for (int ni = 0; ni < 4; ++ni)
                acc[mi][ni] = __builtin_amdgcn_mfma_f32_16x16x32_bf16(af[mi], bfr[ni], acc[mi][ni], 0, 0, 0);
    }
    float invs = sigbuf[0];
    int rg = lane >> 4;
#pragma unroll
    for (int ni = 0; ni < 4; ++ni) {
        int gn = n0 + wc * 64 + ni * 16 + cl;
#pragma unroll
        for (int mi = 0; mi < 4; ++mi) {
            int gm = m0 + wr * 64 + mi * 16 + rg * 4;
            f32x4 v = acc[mi][ni];
#pragma unroll
            for (int ri = 0; ri < 4; ++ri)
                Cb[(size_t)(gm + ri) * Dn + gn] = v[ri] * invs;
        }
    }
}

// ---------------- conversions ----------------
__global__ __launch_bounds__(256) void k_cvt_bf16(const float* __restrict__ in,
                                                  unsigned short* __restrict__ out, int n4) {
    int i = blockIdx.x * 256 + threadIdx.x;
    if (i < n4) {
        float4 v = ((const float4*)in)[i];
        u16x4 o;
        o[0] = f2bf(v.x); o[1] = f2bf(v.y); o[2] = f2bf(v.z); o[3] = f2bf(v.w);
        *(u16x4*)&out[(size_t)i * 4] = o;
    }
}

__global__ __launch_bounds__(256) void k_cvt_sp(const float* __restrict__ SP,
                                                unsigned short* __restrict__ O) {
    int s = blockIdx.x;
    int t0 = threadIdx.x * 4;
    float4 v = *(const float4*)&SP[(size_t)s * 1024 + t0];
    u16x4 o;
    o[0] = (t0 + 0 <= s) ? f2bf(v.x) : 0;
    o[1] = (t0 + 1 <= s) ? f2bf(v.y) : 0;
    o[2] = (t0 + 2 <= s) ? f2bf(v.z) : 0;
    o[3] = (t0 + 3 <= s) ? f2bf(v.w) : 0;
    *(u16x4*)&O[(size_t)s * 1024 + t0] = o;
}

// ---------------- x_bf[b][t][d] -> xT[b][d][t] bf16, 64x64 LDS tile ----------------
__global__ __launch_bounds__(256) void k_transpose_x(const unsigned short* __restrict__ X,
                                                     unsigned short* __restrict__ XT) {
    int d0 = blockIdx.x * 64, t0 = blockIdx.y * 64, b = blockIdx.z;
    const unsigned short* Xb = X + (size_t)b * Ln * Dn;
    unsigned short* Tb = XT + (size_t)b * Dn * Ln;
    __shared__ unsigned short tile[64 * 65];
    int tx = threadIdx.x & 63, ty = threadIdx.x >> 6;
#pragma unroll
    for (int i = 0; i < 16; ++i) {
        int t = ty + i * 4;
        tile[t * 65 + tx] = Xb[(size_t)(t0 + t) * Dn + d0 + tx];
    }
    __syncthreads();
#pragma unroll
    for (int i = 0; i < 16; ++i) {
        int d = ty + i * 4;
        Tb[(size_t)(d0 + d) * Ln + t0 + tx] = tile[tx * 65 + d];
    }
}

// ---------------- spectral norm: parallel column-sum (phase 1) ----------------
__global__ __launch_bounds__(256) void k_sn_colsum(const float* __restrict__ Wm,
                                                   float* __restrict__ partial) {
    int b = blockIdx.x;               // 0..63, rows [16b, 16b+16)
    int tid = threadIdx.x;
    int c0 = tid * 4;
    float4 s = make_float4(0.f, 0.f, 0.f, 0.f);
#pragma unroll
    for (int i = 0; i < 16; ++i) {
        float4 v = *(const float4*)&Wm[(size_t)(b * 16 + i) * 1024 + c0];
        s.x += v.x; s.y += v.y; s.z += v.z; s.w += v.w;
    }
    *(float4*)&partial[(size_t)b * 1024 + c0] = s;
}

// ---------------- spectral norm: finish column-sum + normalize v (phase 2) ----------------
__global__ __launch_bounds__(1024) void k_sn_v2(const float* __restrict__ partial,
                                                float* __restrict__ v) {
    int j = threadIdx.x;
    float s = 0.f;
#pragma unroll 8
    for (int i = 0; i < 64; ++i) s += partial[(size_t)i * 1024 + j];
    s *= 0.03125f;                    // 1/sqrt(1024)
    __shared__ float red[1024];
    red[j] = s * s; __syncthreads();
    for (int st = 512; st > 0; st >>= 1) {
        if (j < st) red[j] += red[j + st];
        __syncthreads();
    }
    float nrm = sqrtf(red[0]);
    v[j] = s / (nrm + 1e-12f);
}

__global__ __launch_bounds__(64) void k_sn_u(const float* __restrict__ Wm,
                                             const float* __restrict__ v,
                                             float* __restrict__ ur) {
    int i = blockIdx.x;
    int lane = threadIdx.x;
    float s = 0.f;
    for (int j = lane; j < 1024; j += 64) s += Wm[(size_t)i * 1024 + j] * v[j];
#pragma unroll
    for (int off = 32; off > 0; off >>= 1) s += __shfl_down(s, off);
    if (lane == 0) ur[i] = s;
}

__global__ __launch_bounds__(1024) void k_sn_sigma(const float* __restrict__ ur,
                                                   float* __restrict__ sig) {
    int i = threadIdx.x;
    __shared__ float red[1024];
    float u = ur[i];
    red[i] = u * u; __syncthreads();
    for (int st = 512; st > 0; st >>= 1) {
        if (i < st) red[i] += red[i + st];
        __syncthreads();
    }
    if (i == 0) {
        float ss = red[0];
        float sigma = ss / (sqrtf(ss) + 1e-12f);
        sig[0] = 1.0f / sigma;
    }
}

// ---------------- final residual + LayerNorm ----------------
__global__ __launch_bounds__(256) void k_final_ln(const float* __restrict__ CE,
                                                  const float* __restrict__ SE,
                                                  const float* __restrict__ EMB,
                                                  const float* __restrict__ g,
                                                  const float* __restrict__ be,
                                                  float* __restrict__ out) {
    int r = blockIdx.x;
    int tid = threadIdx.x;
    float y[3];
    float s = 0.f;
#pragma unroll
    for (int i = 0; i < 3; ++i) {
        int o = tid + i * 256;
        size_t idx = (size_t)r * 768 + o;
        y[i] = CE[idx] + SE[idx] + EMB[idx];
        s += y[i];
    }
    __shared__ float red[256];
    red[tid] = s; __syncthreads();
    for (int st = 128; st > 0; st >>= 1) {
        if (tid < st) red[tid] += red[tid + st];
        __syncthreads();
    }
    float mu = red[0] * (1.f / 768.f);
    __syncthreads();
    float vs = 0.f;
#pragma unroll
    for (int i = 0; i < 3; ++i) { float d = y[i] - mu; vs += d * d; }
    red[tid] = vs; __syncthreads();
    for (int st = 128; st > 0; st >>= 1) {
        if (tid < st) red[tid] += red[tid + st];
        __syncthreads();
    }
    float var = red[0] * (1.f / 768.f);
    float rstd = rsqrtf(var + 1e-12f);
#pragma unroll
    for (int i = 0; i < 3; ++i) {
        int o = tid + i * 256;
        size_t idx = (size_t)r * 768 + o;
        out[idx] = (y[i] - mu) * rstd * g[o] + be[o];
    }
}

extern "C" void kernel_launch(void* const* d_in, const int* in_sizes, int n_in,
                              void* d_out, int out_size, void* d_ws, size_t ws_size,
                              hipStream_t stream) {
    const float* emb     = (const float*)d_in[0];
    const float* pre_w   = (const float*)d_in[1];
    const float* pre_b   = (const float*)d_in[2];
    const float* psfs    = (const float*)d_in[3];
    const float* post_w  = (const float*)d_in[4];
    const float* post_b  = (const float*)d_in[5];
    const float* spmat   = (const float*)d_in[6];
    const float* ln_g    = (const float*)d_in[7];
    const float* ln_b    = (const float*)d_in[8];
    float* out = (float*)d_out;
    float* ws = (float*)d_ws;

    float* p      = ws + O_P;
    float* psfh   = ws + O_PSFH;
    float* part   = ws + O_PART;
    float* qh     = ws + O_QH;
    float* q      = ws + O_SIG + 8;
    float* XHre   = ws + O_XH;
    float* XHim   = ws + O_XH + 6488064;
    float* YHre   = ws + O_YH;
    float* YHim   = ws + O_YH + 6488064;
    float* spe    = ws + O_SPE;
    float* phf    = ws + O_SPE;                      // alias (dead before spe)
    float* v      = ws + O_V;
    float* urw    = ws + O_UR;
    float* sig    = ws + O_SIG;
    float* CE     = ws + O_YH;                       // after YH planes dead

    unsigned short* x_bf      = (unsigned short*)(ws + O_X);
    unsigned short* Wbig      = (unsigned short*)(ws + O_X + 6291456);
    unsigned short* Wi        = (unsigned short*)(ws + O_X + 6635520);
    unsigned short* YT        = (unsigned short*)(ws + O_XH);            // over dead XH planes
    unsigned short* G_bf      = (unsigned short*)(ws + O_XH + 6553600);
    unsigned short* xT_bf     = (unsigned short*)(ws + O_XH);            // over dead YT
    unsigned short* emb_bf    = (unsigned short*)(ws + O_YH);            // dead before YH planes
    unsigned short* SP_bf     = (unsigned short*)(ws + O_P);             // over dead p
    unsigned short* pre_w_bf  = (unsigned short*)(ws + O_PSFH);          // over dead psfh
    unsigned short* post_w_bf = (unsigned short*)(ws + O_PSFH + 294912);

    // PSF preprocessing
    k_psf_softmax<<<Hn * 64, 256, 0, stream>>>(psfs, p, q);
    k_psf_dft<<<Hn * 1024, 64, 0, stream>>>(p, psfh);
    k_q_dft<<<Hn, 64, 0, stream>>>(q, qh);
    k_tap_fft<<<NHK, 256, 0, stream>>>(psfh, qh, phf);

    // spectral norm scalar (parallel column-sum)
    k_sn_colsum<<<64, 256, 0, stream>>>(spmat, part);
    k_sn_v2<<<1, 1024, 0, stream>>>(part, v);
    k_sn_u<<<1024, 64, 0, stream>>>(spmat, v, urw);
    k_sn_sigma<<<1, 1024, 0, stream>>>(urw, sig);

    // conversions + DFT matrix builds
    k_cvt_sp<<<1024, 256, 0, stream>>>(spmat, SP_bf);
    k_cvt_bf16<<<576, 256, 0, stream>>>(pre_w, pre_w_bf, 147456);
    k_cvt_bf16<<<576, 256, 0, stream>>>(post_w, post_w_bf, 147456);
    k_cvt_bf16<<<12288, 256, 0, stream>>>(emb, emb_bf, 3145728);
    k_build_wbig<<<896, 256, 0, stream>>>(Wbig);
    k_build_wi<<<768, 256, 0, stream>>>(Wi);

    // pre-projection (MFMA bf16 -> bf16 x)
    k_mfma_abt_bf<<<dim3(6, 128), 256, 0, stream>>>(emb_bf, pre_w_bf, pre_b, x_bf, Bn * Ln, Dn, Dn);

    // head-dim DFT of x as MFMA GEMM -> split re/im planes
    k_mfma_dft<<<dim3(128, 7), 256, 0, stream>>>(Wbig, x_bf, XHre, XHim);

    // causal conv + uniform suffix via circular-2048 FFT (fused-pair stages)
    k_conv_fft<<<Bn * NHK, 256, 0, stream>>>(XHre, XHim, phf, YHre, YHim);

    // Y planes -> row-major bf16 (K-contiguous for idft GEMM)
    k_transpose_yh<<<Bn * Hn * 8, 256, 0, stream>>>(YHre, YHim, YT);

    // inverse DFT + GELU as MFMA GEMM -> G bf16
    k_mfma_idft<<<dim3(6, 128), 256, 0, stream>>>(YT, Wi, G_bf);

    // transpose x -> xT bf16 (over dead YT region)
    k_transpose_x<<<dim3(12, 16, Bn), 256, 0, stream>>>(x_bf, xT_bf);

    // post-projection (MFMA bf16) -> CE f32 (over dead YH planes)
    k_mfma_abt<<<dim3(6, 128), 256, 0, stream>>>(G_bf, post_w_bf, post_b, CE, Bn * Ln, Dn, Dn);

    // sparse branch (MFMA bf16, triangular k-loop)
    k_mfma_sparse<<<768, 256, 0, stream>>>(SP_bf, xT_bf, sig, spe);

    // residual + LayerNorm
    k_final_ln<<<Bn * Ln, 256, 0, stream>>>(CE, spe, emb, ln_g, ln_b, out);
}

// Round 8
// 386.404 us; speedup vs baseline: 8.2236x; 1.0279x over previous
//
#include <hip/hip_runtime.h>
#include <math.h>

// Problem constants
#define Bn 16
#define Ln 1024
#define Dn 768
#define Hn 12
#define PHDn 64
#define NK 33                 // Hermitian bins for 64-pt DFT (k=0..32)
#define NHK (Hn * NK)         // 396
#define KI 832                // idft GEMM K (792 data + pad to 13*64)
#define TWOPI_64 0.09817477042468103f   // 2*pi/64

typedef short s16x8 __attribute__((ext_vector_type(8)));
typedef float f32x4 __attribute__((ext_vector_type(4)));
typedef unsigned short u16x4 __attribute__((ext_vector_type(4)));

__device__ __forceinline__ unsigned short f2bf(float f) {
    unsigned int u = __float_as_uint(f);
    unsigned int r = (u + 0x7FFFu + ((u >> 16) & 1u)) >> 16;
    return (unsigned short)r;
}

__device__ __forceinline__ float2 cmul(float2 a, float2 b) {
    return make_float2(a.x * b.x - a.y * b.y, a.x * b.y + a.y * b.x);
}

// ---------------- workspace layout (float offsets) ----------------
static const size_t O_P    = 0;          // psf taps; later SP_bf
static const size_t O_PSFH = 786432;     // psf-hat; later pre_w_bf + post_w_bf
static const size_t O_PART = 1376256;    // sn column-sum partials [64][1024]
static const size_t O_QH   = 1597440;    // q-hat
static const size_t O_X    = 1598240;    // x_bf (6291456) + Wbig (344064) + Wi (319488)
static const size_t O_XH   = 14181152;   // XH interleaved [bhk][1024][2]; later YT(832)+...; later xT_bf
static const size_t O_YH   = 27157280;   // emb_bf early; YH interleaved; later CE f32
static const size_t O_SPE  = 40146080;   // phf early; G_bf mid; sparse_emb later
static const size_t O_V    = 52728992;
static const size_t O_UR   = 52730016;
static const size_t O_SIG  = 52731040;   // inv_sigma + q[768] after

// ---------------- psf softmax over 2047 taps (1023 are zeros) ----------------
__global__ __launch_bounds__(256) void k_psf_softmax(const float* __restrict__ psfs,
                                                     float* __restrict__ p,
                                                     float* __restrict__ q) {
    int he = blockIdx.x;            // h*64+e
    int h = he >> 6, e = he & 63;
    int tid = threadIdx.x;
    float ev[4];
    float s = 0.f;
#pragma unroll
    for (int i = 0; i < 4; ++i) {
        int t = tid + 256 * i;
        float v = psfs[((size_t)h * 2047 + t) * 64 + e];
        ev[i] = expf(v);
        s += ev[i];
    }
    __shared__ float red[256];
    red[tid] = s; __syncthreads();
    for (int st = 128; st > 0; st >>= 1) {
        if (tid < st) red[tid] += red[tid + st];
        __syncthreads();
    }
    float denom = red[0] + 1023.0f;
    float inv = 1.0f / denom;
#pragma unroll
    for (int i = 0; i < 4; ++i) {
        int t = tid + 256 * i;
        p[((size_t)h * 1024 + t) * 64 + e] = ev[i] * inv;
    }
    if (tid == 0) q[he] = inv;
}

// ---------------- DFT over head-dim of psf taps (4 t per block) ----------------
__global__ __launch_bounds__(256) void k_psf_dft(const float* __restrict__ p,
                                                 float* __restrict__ psfh) {
    int blk = blockIdx.x;           // h*256 + tb
    int h = blk >> 8, tb = blk & 255;
    int t0 = tb * 4;
    int tid = threadIdx.x;
    int w = tid >> 6, lane = tid & 63;
    __shared__ float pv[4][64], cc[64], ssn[64];
    if (tid < 64) {
        float ang = TWOPI_64 * tid;
        cc[tid] = cosf(ang); ssn[tid] = sinf(ang);
    }
    pv[w][lane] = p[((size_t)h * 1024 + t0 + w) * 64 + lane];
    __syncthreads();
    if (lane < NK) {
        float re = 0.f, im = 0.f;
#pragma unroll 8
        for (int e = 0; e < 64; ++e) {
            int j = (lane * e) & 63;
            float v = pv[w][e];
            re += v * cc[j];
            im -= v * ssn[j];
        }
        size_t o = (((size_t)h * NK + lane) * 1024 + t0 + w) * 2;
        psfh[o] = re; psfh[o + 1] = im;
    }
}

// ---------------- DFT of uniform tap value q[h][e] ----------------
__global__ __launch_bounds__(64) void k_q_dft(const float* __restrict__ q,
                                              float* __restrict__ qh) {
    int h = blockIdx.x;
    int tid = threadIdx.x;
    __shared__ float qv[64], cc[64], ssn[64];
    qv[tid] = q[h * 64 + tid];
    float ang = TWOPI_64 * tid;
    cc[tid] = cosf(ang); ssn[tid] = sinf(ang);
    __syncthreads();
    if (tid < NK) {
        float re = 0.f, im = 0.f;
        for (int e = 0; e < 64; ++e) {
            int j = (tid * e) & 63;
            re += qv[e] * cc[j];
            im -= qv[e] * ssn[j];
        }
        qh[(h * NK + tid) * 2] = re;
        qh[(h * NK + tid) * 2 + 1] = im;
    }
}

__device__ __forceinline__ void build_twiddles(float2* tw, int tid) {
#pragma unroll
    for (int it = 0; it < 4; ++it) {
        int j = tid + it * 256;
        float a = (float)j * 3.0679615757712823e-3f;   // 2*pi/2048
        float sv, cv;
        __sincosf(a, &sv, &cv);
        tw[j] = make_float2(cv, -sv);
    }
}

// ---------------- fused radix-2 stage-pair (stages s,s+1 of 2048-pt Stockham) ----------------
__device__ __forceinline__ void fft_pair(const float2* __restrict__ X,
                                         float2* __restrict__ Y,
                                         const float2* __restrict__ tw,
                                         int tid, int m) {
#pragma unroll
    for (int it = 0; it < 2; ++it) {
        int i = tid + it * 256;
        int r = i & (m - 1);
        int am = i - r;
        float2 w1 = tw[am];
        float2 w1b = make_float2(w1.y, -w1.x);   // tw[am+512] = -j*w1
        float2 w2 = tw[2 * am];
        float2 x0 = X[i], x1 = X[i + 512], x2 = X[i + 1024], x3 = X[i + 1536];
        float2 y0 = make_float2(x0.x + x2.x, x0.y + x2.y);
        float2 y1 = cmul(make_float2(x0.x - x2.x, x0.y - x2.y), w1);
        float2 y2 = make_float2(x1.x + x3.x, x1.y + x3.y);
        float2 y3 = cmul(make_float2(x1.x - x3.x, x1.y - x3.y), w1b);
        int o = 4 * am + r;
        Y[o] = make_float2(y0.x + y2.x, y0.y + y2.y);
        Y[o + m] = make_float2(y1.x + y3.x, y1.y + y3.y);
        Y[o + 2 * m] = cmul(make_float2(y0.x - y2.x, y0.y - y2.y), w2);
        Y[o + 3 * m] = cmul(make_float2(y1.x - y3.x, y1.y - y3.y), w2);
    }
}

// ---------------- FFT of tap vector per (h,k) ----------------
__global__ __launch_bounds__(256) void k_tap_fft(const float* __restrict__ psfh,
                                                 const float* __restrict__ qh,
                                                 float* __restrict__ phf) {
    __shared__ float2 A[2048], B[2048], tw[1024];
    int hk = blockIdx.x, tid = threadIdx.x;
    build_twiddles(tw, tid);
    float2 qv = make_float2(qh[hk * 2], qh[hk * 2 + 1]);
    const float2* Pg = (const float2*)(psfh + (size_t)hk * 2048);
    __syncthreads();
#pragma unroll
    for (int it = 0; it < 2; ++it) {
        int i = tid + it * 256;
        float2 x0 = Pg[i], x1 = Pg[i + 512];
        float2 x2 = (i == 0) ? make_float2(0.f, 0.f) : qv;
        float2 x3 = qv;
        float2 w1 = tw[i];
        float2 w1b = make_float2(w1.y, -w1.x);
        float2 w2 = tw[2 * i];
        float2 y0 = make_float2(x0.x + x2.x, x0.y + x2.y);
        float2 y1 = cmul(make_float2(x0.x - x2.x, x0.y - x2.y), w1);
        float2 y2 = make_float2(x1.x + x3.x, x1.y + x3.y);
        float2 y3 = cmul(make_float2(x1.x - x3.x, x1.y - x3.y), w1b);
        int o = 4 * i;
        A[o] = make_float2(y0.x + y2.x, y0.y + y2.y);
        A[o + 1] = make_float2(y1.x + y3.x, y1.y + y3.y);
        A[o + 2] = cmul(make_float2(y0.x - y2.x, y0.y - y2.y), w2);
        A[o + 3] = cmul(make_float2(y1.x - y3.x, y1.y - y3.y), w2);
    }
    __syncthreads();
    fft_pair(A, B, tw, tid, 4);   __syncthreads();
    fft_pair(B, A, tw, tid, 16);  __syncthreads();
    fft_pair(A, B, tw, tid, 64);  __syncthreads();
    fft_pair(B, A, tw, tid, 256); __syncthreads();
    float2* out = (float2*)(phf + (size_t)hk * 4096);
#pragma unroll
    for (int it = 0; it < 4; ++it) {
        int t = tid + it * 256;
        float2 lo = A[t], hi = A[t + 1024];
        out[t] = make_float2(lo.x + hi.x, lo.y + hi.y);
        out[t + 1024] = make_float2(lo.x - hi.x, lo.y - hi.y);
    }
}

// ---------------- per-(b,h,k) conv via circular-2048 FFT (interleaved planes) ----------------
__global__ __launch_bounds__(256) void k_conv_fft(const float* __restrict__ XH,
                                                  const float* __restrict__ PHF,
                                                  float* __restrict__ YH) {
    __shared__ float2 A[2048], B[2048], tw[1024];
    int bhk = blockIdx.x, tid = threadIdx.x;
    int hk = bhk % NHK;
    build_twiddles(tw, tid);
    const float2* Xg = (const float2*)(XH + (size_t)bhk * 2048);
    __syncthreads();
#pragma unroll
    for (int it = 0; it < 2; ++it) {
        int i = tid + it * 256;
        float2 x0 = Xg[i];
        float2 x1 = Xg[i + 512];
        float2 w1 = tw[i];
        float2 w1b = make_float2(w1.y, -w1.x);
        float2 w2 = tw[2 * i];
        float2 y1 = cmul(x0, w1);
        float2 y3 = cmul(x1, w1b);
        int o = 4 * i;
        A[o] = make_float2(x0.x + x1.x, x0.y + x1.y);
        A[o + 1] = make_float2(y1.x + y3.x, y1.y + y3.y);
        A[o + 2] = cmul(make_float2(x0.x - x1.x, x0.y - x1.y), w2);
        A[o + 3] = cmul(make_float2(y1.x - y3.x, y1.y - y3.y), w2);
    }
    __syncthreads();
    fft_pair(A, B, tw, tid, 4);   __syncthreads();
    fft_pair(B, A, tw, tid, 16);  __syncthreads();
    fft_pair(A, B, tw, tid, 64);  __syncthreads();
    fft_pair(B, A, tw, tid, 256); __syncthreads();
    const float2* P = (const float2*)(PHF + (size_t)hk * 4096);
    float2 q[8];
#pragma unroll
    for (int it = 0; it < 4; ++it) {
        int t = tid + it * 256;
        float2 lo = A[t], hi = A[t + 1024];
        float2 fl = make_float2(lo.x + hi.x, lo.y + hi.y);
        float2 fh = make_float2(lo.x - hi.x, lo.y - hi.y);
        float2 vl = cmul(fl, P[t]);
        float2 vh = cmul(fh, P[t + 1024]);
        q[it] = make_float2(vl.x, -vl.y);
        q[it + 4] = make_float2(vh.x, -vh.y);
    }
#pragma unroll
    for (int it = 0; it < 2; ++it) {
        int i = tid + it * 256;
        float2 x0 = q[it], x1 = q[it + 2], x2 = q[it + 4], x3 = q[it + 6];
        float2 w1 = tw[i];
        float2 w1b = make_float2(w1.y, -w1.x);
        float2 w2 = tw[2 * i];
        float2 y0 = make_float2(x0.x + x2.x, x0.y + x2.y);
        float2 y1 = cmul(make_float2(x0.x - x2.x, x0.y - x2.y), w1);
        float2 y2 = make_float2(x1.x + x3.x, x1.y + x3.y);
        float2 y3 = cmul(make_float2(x1.x - x3.x, x1.y - x3.y), w1b);
        int o = 4 * i;
        B[o] = make_float2(y0.x + y2.x, y0.y + y2.y);
        B[o + 1] = make_float2(y1.x + y3.x, y1.y + y3.y);
        B[o + 2] = cmul(make_float2(y0.x - y2.x, y0.y - y2.y), w2);
        B[o + 3] = cmul(make_float2(y1.x - y3.x, y1.y - y3.y), w2);
    }
    __syncthreads();
    fft_pair(B, A, tw, tid, 4);   __syncthreads();
    fft_pair(A, B, tw, tid, 16);  __syncthreads();
    fft_pair(B, A, tw, tid, 64);  __syncthreads();
    fft_pair(A, B, tw, tid, 256); __syncthreads();
    float2* Yg = (float2*)(YH + (size_t)bhk * 2048);
    const float inv_n = 1.0f / 2048.0f;
#pragma unroll
    for (int it = 0; it < 4; ++it) {
        int s = tid + it * 256;
        float2 lo = B[s], hi = B[s + 1024];
        Yg[s] = make_float2((lo.x + hi.x) * inv_n, -(lo.y + hi.y) * inv_n);
    }
}

// ---------------- build block-diagonal forward DFT matrix Wbig [896][768] bf16 ----------------
__global__ __launch_bounds__(256) void k_build_wbig(unsigned short* __restrict__ W) {
    int m = blockIdx.x;                  // 0..895
    int tid = threadIdx.x;
    int h = m / 66, rem = m - h * 66;
    int k = rem >> 1, od = rem & 1;
    bool valid = (m < 792);
#pragma unroll
    for (int i = 0; i < 3; ++i) {
        int d = tid + i * 256;
        int dh = d >> 6, dd = d & 63;
        float val = 0.f;
        if (valid && dh == h) {
            int j = (k * dd) & 63;
            float ang = TWOPI_64 * (float)j;
            val = od ? -sinf(ang) : cosf(ang);
        }
        W[(size_t)m * 768 + d] = f2bf(val);
    }
}

// ---------------- build inverse DFT matrix Wi [768][832] bf16 (1/64 + Hermitian 2x folded) ----------------
__global__ __launch_bounds__(256) void k_build_wi(unsigned short* __restrict__ W) {
    int hd = blockIdx.x;                 // 0..767
    int tid = threadIdx.x;
    int h = hd >> 6, d = hd & 63;
#pragma unroll
    for (int i = 0; i < 4; ++i) {
        int col = tid + i * 256;
        if (col < KI) {
            float val = 0.f;
            if (col < 792) {
                int h2 = col / 66, rem = col - h2 * 66;
                int k = rem >> 1, od = rem & 1;
                if (h2 == h) {
                    int j = (k * d) & 63;
                    float ang = TWOPI_64 * (float)j;
                    float ck = ((k == 0) || (k == 32)) ? (1.f / 64.f) : (2.f / 64.f);
                    val = od ? -sinf(ang) * ck : cosf(ang) * ck;
                }
            }
            W[(size_t)hd * KI + col] = f2bf(val);
        }
    }
}

// ---------------- BK=64 MFMA core: acc += tileA(128xK) @ tileB(128xK)^T ----------------
// 4 waves 2x2; XOR slot swizzle (slot^(row&7)); 2 barriers per 64-wide k-tile.
__device__ __forceinline__ void mfma_core64(const unsigned short* __restrict__ gA0,
                                            const unsigned short* __restrict__ gB0,
                                            int nkt,
                                            unsigned short* __restrict__ As,
                                            unsigned short* __restrict__ Bs,
                                            int tid, int lane, int wr, int wc,
                                            f32x4 acc[4][4]) {
    int r0 = tid >> 1, hs = (tid & 1) << 2;
    int wbase = r0 * 64;
    int swr = r0 & 7;
    int kg = lane >> 4, cl = lane & 15;
    int fra[8], frb[8];
#pragma unroll
    for (int kk = 0; kk < 2; ++kk)
#pragma unroll
        for (int i = 0; i < 4; ++i) {
            int ra = wr * 64 + i * 16 + cl;
            fra[kk * 4 + i] = ra * 64 + (((kk * 4 + kg) ^ (ra & 7)) << 3);
            int rb = wc * 64 + i * 16 + cl;
            frb[kk * 4 + i] = rb * 64 + (((kk * 4 + kg) ^ (rb & 7)) << 3);
        }
    s16x8 a[4], b[4];
#pragma unroll
    for (int l = 0; l < 4; ++l) {
        a[l] = *(const s16x8*)(gA0 + l * 8);
        b[l] = *(const s16x8*)(gB0 + l * 8);
    }
    for (int kt = 0; kt < nkt; ++kt) {
        __syncthreads();
#pragma unroll
        for (int l = 0; l < 4; ++l) {
            *(s16x8*)&As[wbase + (((hs + l) ^ swr) << 3)] = a[l];
            *(s16x8*)&Bs[wbase + (((hs + l) ^ swr) << 3)] = b[l];
        }
        __syncthreads();
        if (kt + 1 < nkt) {
            size_t ko = (size_t)(kt + 1) * 64;
#pragma unroll
            for (int l = 0; l < 4; ++l) {
                a[l] = *(const s16x8*)(gA0 + ko + l * 8);
                b[l] = *(const s16x8*)(gB0 + ko + l * 8);
            }
        }
#pragma unroll
        for (int kk = 0; kk < 2; ++kk) {
            s16x8 af[4], bfr[4];
#pragma unroll
            for (int i = 0; i < 4; ++i) af[i] = *(const s16x8*)&As[fra[kk * 4 + i]];
#pragma unroll
            for (int i = 0; i < 4; ++i) bfr[i] = *(const s16x8*)&Bs[frb[kk * 4 + i]];
#pragma unroll
            for (int mi = 0; mi < 4; ++mi)
#pragma unroll
                for (int ni = 0; ni < 4; ++ni)
                    acc[mi][ni] = __builtin_amdgcn_mfma_f32_16x16x32_bf16(af[mi], bfr[ni], acc[mi][ni], 0, 0, 0);
        }
    }
}

// ---------------- bf16 MFMA GEMM: C(f32) = A@W^T + bias ----------------
__global__ __launch_bounds__(256) void k_mfma_abt(const unsigned short* __restrict__ A,
                                                  const unsigned short* __restrict__ W,
                                                  const float* __restrict__ bias,
                                                  float* __restrict__ C,
                                                  int M, int N, int K) {
    int n0 = blockIdx.x * 128, m0 = blockIdx.y * 128;
    int tid = threadIdx.x;
    int lane = tid & 63, wave = tid >> 6;
    int wr = wave >> 1, wc = wave & 1;
    __shared__ __align__(16) unsigned short As[8192], Bs[8192];
    f32x4 acc[4][4] = {};
    int r0 = tid >> 1, hs = (tid & 1) << 2;
    const unsigned short* gA0 = A + (size_t)(m0 + r0) * K + hs * 8;
    const unsigned short* gB0 = W + (size_t)(n0 + r0) * K + hs * 8;
    mfma_core64(gA0, gB0, K >> 6, As, Bs, tid, lane, wr, wc, acc);
    int kg = lane >> 4, cl = lane & 15;
#pragma unroll
    for (int ni = 0; ni < 4; ++ni) {
        int gn = n0 + wc * 64 + ni * 16 + cl;
        float bv = bias ? bias[gn] : 0.f;
#pragma unroll
        for (int mi = 0; mi < 4; ++mi) {
            int gm = m0 + wr * 64 + mi * 16 + kg * 4;
            f32x4 v = acc[mi][ni];
#pragma unroll
            for (int ri = 0; ri < 4; ++ri)
                C[(size_t)(gm + ri) * N + gn] = v[ri] + bv;
        }
    }
}

// ---------------- bf16 MFMA GEMM with bf16 output (pre-projection) ----------------
__global__ __launch_bounds__(256) void k_mfma_abt_bf(const unsigned short* __restrict__ A,
                                                     const unsigned short* __restrict__ W,
                                                     const float* __restrict__ bias,
                                                     unsigned short* __restrict__ C,
                                                     int M, int N, int K) {
    int n0 = blockIdx.x * 128, m0 = blockIdx.y * 128;
    int tid = threadIdx.x;
    int lane = tid & 63, wave = tid >> 6;
    int wr = wave >> 1, wc = wave & 1;
    __shared__ __align__(16) unsigned short As[8192], Bs[8192];
    f32x4 acc[4][4] = {};
    int r0 = tid >> 1, hs = (tid & 1) << 2;
    const unsigned short* gA0 = A + (size_t)(m0 + r0) * K + hs * 8;
    const unsigned short* gB0 = W + (size_t)(n0 + r0) * K + hs * 8;
    mfma_core64(gA0, gB0, K >> 6, As, Bs, tid, lane, wr, wc, acc);
    int kg = lane >> 4, cl = lane & 15;
#pragma unroll
    for (int ni = 0; ni < 4; ++ni) {
        int gn = n0 + wc * 64 + ni * 16 + cl;
        float bv = bias ? bias[gn] : 0.f;
#pragma unroll
        for (int mi = 0; mi < 4; ++mi) {
            int gm = m0 + wr * 64 + mi * 16 + kg * 4;
            f32x4 v = acc[mi][ni];
#pragma unroll
            for (int ri = 0; ri < 4; ++ri)
                C[(size_t)(gm + ri) * N + gn] = f2bf(v[ri] + bv);
        }
    }
}

// ---------------- forward head-dim DFT as MFMA GEMM -> interleaved planes ----------------
__global__ __launch_bounds__(256) void k_mfma_dft(const unsigned short* __restrict__ Wb,
                                                  const unsigned short* __restrict__ Xb,
                                                  float* __restrict__ XH) {
    int n0 = blockIdx.x * 128, m0 = blockIdx.y * 128;
    const int K = 768;
    int tid = threadIdx.x;
    int lane = tid & 63, wave = tid >> 6;
    int wr = wave >> 1, wc = wave & 1;
    __shared__ __align__(16) unsigned short As[8192], Bs[8192];
    f32x4 acc[4][4] = {};
    int r0 = tid >> 1, hs = (tid & 1) << 2;
    const unsigned short* gA0 = Wb + (size_t)(m0 + r0) * K + hs * 8;
    const unsigned short* gB0 = Xb + (size_t)(n0 + r0) * K + hs * 8;
    mfma_core64(gA0, gB0, 12, As, Bs, tid, lane, wr, wc, acc);
    int kg = lane >> 4, cl = lane & 15;
#pragma unroll
    for (int ni = 0; ni < 4; ++ni) {
        int gn = n0 + wc * 64 + ni * 16 + cl;   // global row index of x
        int b = gn >> 10, u = gn & 1023;
#pragma unroll
        for (int mi = 0; mi < 4; ++mi) {
            int gmb = m0 + wr * 64 + mi * 16 + kg * 4;
            f32x4 v = acc[mi][ni];
#pragma unroll
            for (int rp = 0; rp < 2; ++rp) {
                int m = gmb + rp * 2;           // even; pair (m, m+1) = (re, im) same h
                if (m < 792) {
                    int h = m / 66, rem = m - h * 66;
                    size_t plane = (size_t)(b * Hn + h) * NK + (rem >> 1);
                    *(float2*)&XH[(plane * 1024 + u) * 2] = make_float2(v[rp * 2], v[rp * 2 + 1]);
                }
            }
        }
    }
}

// ---------------- Y planes (interleaved) -> row-major bf16 YT [16384][832] ----------------
__global__ __launch_bounds__(256) void k_transpose_yh(const float* __restrict__ YH,
                                                      unsigned short* __restrict__ YT) {
    int ut = blockIdx.x & 7;
    int h = (blockIdx.x >> 3) % 12;
    int b = blockIdx.x / 96;
    int u0 = ut * 128;
    __shared__ unsigned short T[128 * 66];
    int tid = threadIdx.x;
    int planeBase = (b * Hn + h) * NK;
    const float2* Yg = (const float2*)YH;
#pragma unroll
    for (int i = 0; i < 17; ++i) {
        int idx = tid + i * 256;        // 0..4223 = 33k x 128uo
        if (idx < 4224) {
            int k = idx >> 7, uo = idx & 127;
            float2 v = Yg[(size_t)(planeBase + k) * 1024 + u0 + uo];
            T[uo * 66 + 2 * k] = f2bf(v.x);
            T[uo * 66 + 2 * k + 1] = f2bf(v.y);
        }
    }
    __syncthreads();
    unsigned int* out = (unsigned int*)YT;
    for (int i = 0; i < 17; ++i) {
        int idx = tid + i * 256;
        if (idx < 4224) {
            int uo = idx / 33;
            int w = idx - uo * 33;
            unsigned int lo = T[uo * 66 + 2 * w];
            unsigned int hi = T[uo * 66 + 2 * w + 1];
            size_t r = (size_t)b * 1024 + u0 + uo;
            out[r * 416 + h * 33 + w] = lo | (hi << 16);
        }
    }
    // zero-fill padding uints 396..415 (u16 cols 792..831): stale bf16 NaN guard
    if (h == 0) {
        for (int i = tid; i < 2560; i += 256) {
            int uo = i / 20, w = 396 + i % 20;
            size_t r = (size_t)b * 1024 + u0 + uo;
            out[r * 416 + w] = 0u;
        }
    }
}

// ---------------- inverse DFT + GELU as MFMA GEMM: G = gelu(YT @ Wi^T) bf16 ----------------
__global__ __launch_bounds__(256) void k_mfma_idft(const unsigned short* __restrict__ YT,
                                                   const unsigned short* __restrict__ Wi,
                                                   unsigned short* __restrict__ G) {
    int n0 = blockIdx.x * 128, m0 = blockIdx.y * 128;
    const int K = KI;
    int tid = threadIdx.x;
    int lane = tid & 63, wave = tid >> 6;
    int wr = wave >> 1, wc = wave & 1;
    __shared__ __align__(16) unsigned short As[8192], Bs[8192];
    f32x4 acc[4][4] = {};
    int r0 = tid >> 1, hs = (tid & 1) << 2;
    const unsigned short* gA0 = YT + (size_t)(m0 + r0) * K + hs * 8;
    const unsigned short* gB0 = Wi + (size_t)(n0 + r0) * K + hs * 8;
    mfma_core64(gA0, gB0, 13, As, Bs, tid, lane, wr, wc, acc);
    int kg = lane >> 4, cl = lane & 15;
#pragma unroll
    for (int ni = 0; ni < 4; ++ni) {
        int gn = n0 + wc * 64 + ni * 16 + cl;
#pragma unroll
        for (int mi = 0; mi < 4; ++mi) {
            int gm = m0 + wr * 64 + mi * 16 + kg * 4;
            f32x4 v = acc[mi][ni];
#pragma unroll
            for (int ri = 0; ri < 4; ++ri) {
                float c = v[ri];
                float g = c * 0.5f * (1.0f + erff(c * 0.70710678118f));
                G[(size_t)(gm + ri) * 768 + gn] = f2bf(g);
            }
        }
    }
}

// ---------------- sparse: C_b = (tril(SP)/sigma) @ x_b via xT bf16, MFMA ----------------
__global__ __launch_bounds__(256) void k_mfma_sparse(const unsigned short* __restrict__ SP,
                                                     const unsigned short* __restrict__ XT,
                                                     const float* __restrict__ sigbuf,
                                                     float* __restrict__ C) {
    int bx = blockIdx.x;
    int mt = bx & 7, nt = (bx >> 3) % 6, b = bx / 48;
    int m0 = mt * 128, n0 = nt * 128;
    const unsigned short* Xb = XT + (size_t)b * Dn * Ln;
    float* Cb = C + (size_t)b * Ln * Dn;
    int tid = threadIdx.x;
    int lane = tid & 63, wave = tid >> 6;
    int wr = wave >> 1, wc = wave & 1;
    __shared__ __align__(16) unsigned short As[8192], Bs[8192];
    f32x4 acc[4][4] = {};
    int r0 = tid >> 1, hs = (tid & 1) << 2;
    const unsigned short* gA0 = SP + (size_t)(m0 + r0) * Ln + hs * 8;
    const unsigned short* gB0 = Xb + (size_t)(n0 + r0) * Ln + hs * 8;
    mfma_core64(gA0, gB0, 2 * mt + 2, As, Bs, tid, lane, wr, wc, acc);
    float invs = sigbuf[0];
    int kg = lane >> 4, cl = lane & 15;
#pragma unroll
    for (int ni = 0; ni < 4; ++ni) {
        int gn = n0 + wc * 64 + ni * 16 + cl;
#pragma unroll
        for (int mi = 0; mi < 4; ++mi) {
            int gm = m0 + wr * 64 + mi * 16 + kg * 4;
            f32x4 v = acc[mi][ni];
#pragma unroll
            for (int ri = 0; ri < 4; ++ri)
                Cb[(size_t)(gm + ri) * Dn + gn] = v[ri] * invs;
        }
    }
}

// ---------------- conversions ----------------
__global__ __launch_bounds__(256) void k_cvt_bf16(const float* __restrict__ in,
                                                  unsigned short* __restrict__ out, int n4) {
    int i = blockIdx.x * 256 + threadIdx.x;
    if (i < n4) {
        float4 v = ((const float4*)in)[i];
        u16x4 o;
        o[0] = f2bf(v.x); o[1] = f2bf(v.y); o[2] = f2bf(v.z); o[3] = f2bf(v.w);
        *(u16x4*)&out[(size_t)i * 4] = o;
    }
}

__global__ __launch_bounds__(256) void k_cvt_sp(const float* __restrict__ SP,
                                                unsigned short* __restrict__ O) {
    int s = blockIdx.x;
    int t0 = threadIdx.x * 4;
    float4 v = *(const float4*)&SP[(size_t)s * 1024 + t0];
    u16x4 o;
    o[0] = (t0 + 0 <= s) ? f2bf(v.x) : 0;
    o[1] = (t0 + 1 <= s) ? f2bf(v.y) : 0;
    o[2] = (t0 + 2 <= s) ? f2bf(v.z) : 0;
    o[3] = (t0 + 3 <= s) ? f2bf(v.w) : 0;
    *(u16x4*)&O[(size_t)s * 1024 + t0] = o;
}

// ---------------- x_bf[b][t][d] -> xT[b][d][t] bf16, 64x64 LDS tile ----------------
__global__ __launch_bounds__(256) void k_transpose_x(const unsigned short* __restrict__ X,
                                                     unsigned short* __restrict__ XT) {
    int d0 = blockIdx.x * 64, t0 = blockIdx.y * 64, b = blockIdx.z;
    const unsigned short* Xb = X + (size_t)b * Ln * Dn;
    unsigned short* Tb = XT + (size_t)b * Dn * Ln;
    __shared__ unsigned short tile[64 * 65];
    int tx = threadIdx.x & 63, ty = threadIdx.x >> 6;
#pragma unroll
    for (int i = 0; i < 16; ++i) {
        int t = ty + i * 4;
        tile[t * 65 + tx] = Xb[(size_t)(t0 + t) * Dn + d0 + tx];
    }
    __syncthreads();
#pragma unroll
    for (int i = 0; i < 16; ++i) {
        int d = ty + i * 4;
        Tb[(size_t)(d0 + d) * Ln + t0 + tx] = tile[tx * 65 + d];
    }
}

// ---------------- spectral norm: parallel column-sum (phase 1) ----------------
__global__ __launch_bounds__(256) void k_sn_colsum(const float* __restrict__ Wm,
                                                   float* __restrict__ partial) {
    int b = blockIdx.x;               // 0..63, rows [16b, 16b+16)
    int tid = threadIdx.x;
    int c0 = tid * 4;
    float4 s = make_float4(0.f, 0.f, 0.f, 0.f);
#pragma unroll
    for (int i = 0; i < 16; ++i) {
        float4 v = *(const float4*)&Wm[(size_t)(b * 16 + i) * 1024 + c0];
        s.x += v.x; s.y += v.y; s.z += v.z; s.w += v.w;
    }
    *(float4*)&partial[(size_t)b * 1024 + c0] = s;
}

// ---------------- spectral norm: finish column-sum + normalize v (phase 2) ----------------
__global__ __launch_bounds__(1024) void k_sn_v2(const float* __restrict__ partial,
                                                float* __restrict__ v) {
    int j = threadIdx.x;
    float s = 0.f;
#pragma unroll 8
    for (int i = 0; i < 64; ++i) s += partial[(size_t)i * 1024 + j];
    s *= 0.03125f;                    // 1/sqrt(1024)
    __shared__ float red[1024];
    red[j] = s * s; __syncthreads();
    for (int st = 512; st > 0; st >>= 1) {
        if (j < st) red[j] += red[j + st];
        __syncthreads();
    }
    float nrm = sqrtf(red[0]);
    v[j] = s / (nrm + 1e-12f);
}

__global__ __launch_bounds__(64) void k_sn_u(const float* __restrict__ Wm,
                                             const float* __restrict__ v,
                                             float* __restrict__ ur) {
    int i = blockIdx.x;
    int lane = threadIdx.x;
    float s = 0.f;
    for (int j = lane; j < 1024; j += 64) s += Wm[(size_t)i * 1024 + j] * v[j];
#pragma unroll
    for (int off = 32; off > 0; off >>= 1) s += __shfl_down(s, off);
    if (lane == 0) ur[i] = s;
}

__global__ __launch_bounds__(1024) void k_sn_sigma(const float* __restrict__ ur,
                                                   float* __restrict__ sig) {
    int i = threadIdx.x;
    __shared__ float red[1024];
    float u = ur[i];
    red[i] = u * u; __syncthreads();
    for (int st = 512; st > 0; st >>= 1) {
        if (i < st) red[i] += red[i + st];
        __syncthreads();
    }
    if (i == 0) {
        float ss = red[0];
        float sigma = ss / (sqrtf(ss) + 1e-12f);
        sig[0] = 1.0f / sigma;
    }
}

// ---------------- final residual + LayerNorm ----------------
__global__ __launch_bounds__(256) void k_final_ln(const float* __restrict__ CE,
                                                  const float* __restrict__ SE,
                                                  const float* __restrict__ EMB,
                                                  const float* __restrict__ g,
                                                  const float* __restrict__ be,
                                                  float* __restrict__ out) {
    int r = blockIdx.x;
    int tid = threadIdx.x;
    float y[3];
    float s = 0.f;
#pragma unroll
    for (int i = 0; i < 3; ++i) {
        int o = tid + i * 256;
        size_t idx = (size_t)r * 768 + o;
        y[i] = CE[idx] + SE[idx] + EMB[idx];
        s += y[i];
    }
    __shared__ float red[256];
    red[tid] = s; __syncthreads();
    for (int st = 128; st > 0; st >>= 1) {
        if (tid < st) red[tid] += red[tid + st];
        __syncthreads();
    }
    float mu = red[0] * (1.f / 768.f);
    __syncthreads();
    float vs = 0.f;
#pragma unroll
    for (int i = 0; i < 3; ++i) { float d = y[i] - mu; vs += d * d; }
    red[tid] = vs; __syncthreads();
    for (int st = 128; st > 0; st >>= 1) {
        if (tid < st) red[tid] += red[tid + st];
        __syncthreads();
    }
    float var = red[0] * (1.f / 768.f);
    float rstd = rsqrtf(var + 1e-12f);
#pragma unroll
    for (int i = 0; i < 3; ++i) {
        int o = tid + i * 256;
        size_t idx = (size_t)r * 768 + o;
        out[idx] = (y[i] - mu) * rstd * g[o] + be[o];
    }
}

extern "C" void kernel_launch(void* const* d_in, const int* in_sizes, int n_in,
                              void* d_out, int out_size, void* d_ws, size_t ws_size,
                              hipStream_t stream) {
    const float* emb     = (const float*)d_in[0];
    const float* pre_w   = (const float*)d_in[1];
    const float* pre_b   = (const float*)d_in[2];
    const float* psfs    = (const float*)d_in[3];
    const float* post_w  = (const float*)d_in[4];
    const float* post_b  = (const float*)d_in[5];
    const float* spmat   = (const float*)d_in[6];
    const float* ln_g    = (const float*)d_in[7];
    const float* ln_b    = (const float*)d_in[8];
    float* out = (float*)d_out;
    float* ws = (float*)d_ws;

    float* p      = ws + O_P;
    float* psfh   = ws + O_PSFH;
    float* part   = ws + O_PART;
    float* qh     = ws + O_QH;
    float* q      = ws + O_SIG + 8;
    float* XH     = ws + O_XH;                       // interleaved [bhk][1024][2]
    float* YH     = ws + O_YH;                       // interleaved
    float* spe    = ws + O_SPE;
    float* phf    = ws + O_SPE;                      // alias (dead before G/spe)
    float* v      = ws + O_V;
    float* urw    = ws + O_UR;
    float* sig    = ws + O_SIG;
    float* CE     = ws + O_YH;                       // after YH dead

    unsigned short* x_bf      = (unsigned short*)(ws + O_X);
    unsigned short* Wbig      = (unsigned short*)(ws + O_X + 6291456);
    unsigned short* Wi        = (unsigned short*)(ws + O_X + 6635520);      // 768*832 shorts
    unsigned short* YT        = (unsigned short*)(ws + O_XH);               // over dead XH (16384*832 shorts)
    unsigned short* G_bf      = (unsigned short*)(ws + O_SPE + 1622016);    // after dead phf
    unsigned short* xT_bf     = (unsigned short*)(ws + O_XH);               // over dead YT
    unsigned short* emb_bf    = (unsigned short*)(ws + O_YH);               // dead before YH written
    unsigned short* SP_bf     = (unsigned short*)(ws + O_P);                // over dead p
    unsigned short* pre_w_bf  = (unsigned short*)(ws + O_PSFH);             // over dead psfh
    unsigned short* post_w_bf = (unsigned short*)(ws + O_PSFH + 294912);

    // PSF preprocessing
    k_psf_softmax<<<Hn * 64, 256, 0, stream>>>(psfs, p, q);
    k_psf_dft<<<Hn * 256, 256, 0, stream>>>(p, psfh);
    k_q_dft<<<Hn, 64, 0, stream>>>(q, qh);
    k_tap_fft<<<NHK, 256, 0, stream>>>(psfh, qh, phf);

    // spectral norm scalar (parallel column-sum)
    k_sn_colsum<<<64, 256, 0, stream>>>(spmat, part);
    k_sn_v2<<<1, 1024, 0, stream>>>(part, v);
    k_sn_u<<<1024, 64, 0, stream>>>(spmat, v, urw);
    k_sn_sigma<<<1, 1024, 0, stream>>>(urw, sig);

    // conversions + DFT matrix builds
    k_cvt_sp<<<1024, 256, 0, stream>>>(spmat, SP_bf);
    k_cvt_bf16<<<576, 256, 0, stream>>>(pre_w, pre_w_bf, 147456);
    k_cvt_bf16<<<576, 256, 0, stream>>>(post_w, post_w_bf, 147456);
    k_cvt_bf16<<<12288, 256, 0, stream>>>(emb, emb_bf, 3145728);
    k_build_wbig<<<896, 256, 0, stream>>>(Wbig);
    k_build_wi<<<768, 256, 0, stream>>>(Wi);

    // pre-projection (MFMA bf16 -> bf16 x)
    k_mfma_abt_bf<<<dim3(6, 128), 256, 0, stream>>>(emb_bf, pre_w_bf, pre_b, x_bf, Bn * Ln, Dn, Dn);

    // head-dim DFT of x as MFMA GEMM -> interleaved planes
    k_mfma_dft<<<dim3(128, 7), 256, 0, stream>>>(Wbig, x_bf, XH);

    // causal conv + uniform suffix via circular-2048 FFT (fused-pair stages)
    k_conv_fft<<<Bn * NHK, 256, 0, stream>>>(XH, phf, YH);

    // Y planes -> row-major bf16 YT [16384][832]
    k_transpose_yh<<<Bn * Hn * 8, 256, 0, stream>>>(YH, YT);

    // inverse DFT + GELU as MFMA GEMM -> G bf16 (over dead phf tail region)
    k_mfma_idft<<<dim3(6, 128), 256, 0, stream>>>(YT, Wi, G_bf);

    // transpose x -> xT bf16 (over dead YT region)
    k_transpose_x<<<dim3(12, 16, Bn), 256, 0, stream>>>(x_bf, xT_bf);

    // post-projection (MFMA bf16) -> CE f32 (over dead YH region)
    k_mfma_abt<<<dim3(6, 128), 256, 0, stream>>>(G_bf, post_w_bf, post_b, CE, Bn * Ln, Dn, Dn);

    // sparse branch (MFMA bf16, triangular k-loop; overwrites G region after post done? no —
    // spe starts at O_SPE, G at O_SPE+1622016: G is dead once post-GEMM finished, order is safe)
    k_mfma_sparse<<<768, 256, 0, stream>>>(SP_bf, xT_bf, sig, spe);

    // residual + LayerNorm
    k_final_ln<<<Bn * Ln, 256, 0, stream>>>(CE, spe, emb, ln_g, ln_b, out);
}

// Round 9
// 327.483 us; speedup vs baseline: 9.7032x; 1.1799x over previous
//
#include <hip/hip_runtime.h>
#include <math.h>

// Problem constants
#define Bn 16
#define Ln 1024
#define Dn 768
#define Hn 12
#define PHDn 64
#define NK 33                 // Hermitian bins for 64-pt DFT (k=0..32)
#define NHK (Hn * NK)         // 396
#define TWOPI_64 0.09817477042468103f   // 2*pi/64

typedef short s16x8 __attribute__((ext_vector_type(8)));
typedef float f32x4 __attribute__((ext_vector_type(4)));
typedef unsigned short u16x4 __attribute__((ext_vector_type(4)));

__device__ __forceinline__ unsigned short f2bf(float f) {
    unsigned int u = __float_as_uint(f);
    unsigned int r = (u + 0x7FFFu + ((u >> 16) & 1u)) >> 16;
    return (unsigned short)r;
}
__device__ __forceinline__ float bf2f(unsigned short s) {
    unsigned int u = ((unsigned int)s) << 16;
    return __uint_as_float(u);
}
__device__ __forceinline__ float2 cmul(float2 a, float2 b) {
    return make_float2(a.x * b.x - a.y * b.y, a.x * b.y + a.y * b.x);
}

// LDS anti-bank-conflict swizzle for FFT buffers (XOR bits[3:2] with bits[7:6])
#define SW(j) ((j) ^ (((j) >> 4) & 12))

// ---------------- workspace layout (float offsets) ----------------
static const size_t O_P    = 0;          // psf taps; later SP_bf
static const size_t O_PSFH = 786432;     // psf-hat; later pre_w_bf + post_w_bf
static const size_t O_PART = 1376256;    // sn column-sum partials [64][1024]
static const size_t O_QH   = 1597440;    // q-hat
static const size_t O_X    = 1598240;    // x_bf (6291456) + Wf1 (4096) + Wi1 (4096)
static const size_t O_XH   = 14181152;   // XH interleaved [bhk][1024][2]; later YT[16384][768]bf; later xT_bf
static const size_t O_YH   = 27157280;   // emb_bf early; YH interleaved; later CE_bf
static const size_t O_SPE  = 40146080;   // phf early; spe_bf later; G_bf at +3145728
static const size_t O_V    = 52728992;
static const size_t O_UR   = 52730016;
static const size_t O_SIG  = 52731040;   // inv_sigma + q[768] after

// ---------------- psf softmax over 2047 taps (1023 are zeros) ----------------
__global__ __launch_bounds__(256) void k_psf_softmax(const float* __restrict__ psfs,
                                                     float* __restrict__ p,
                                                     float* __restrict__ q) {
    int he = blockIdx.x;            // h*64+e
    int h = he >> 6, e = he & 63;
    int tid = threadIdx.x;
    float ev[4];
    float s = 0.f;
#pragma unroll
    for (int i = 0; i < 4; ++i) {
        int t = tid + 256 * i;
        float v = psfs[((size_t)h * 2047 + t) * 64 + e];
        ev[i] = expf(v);
        s += ev[i];
    }
    __shared__ float red[256];
    red[tid] = s; __syncthreads();
    for (int st = 128; st > 0; st >>= 1) {
        if (tid < st) red[tid] += red[tid + st];
        __syncthreads();
    }
    float denom = red[0] + 1023.0f;
    float inv = 1.0f / denom;
#pragma unroll
    for (int i = 0; i < 4; ++i) {
        int t = tid + 256 * i;
        p[((size_t)h * 1024 + t) * 64 + e] = ev[i] * inv;
    }
    if (tid == 0) q[he] = inv;
}

// ---------------- DFT over head-dim of psf taps (4 t per block) ----------------
__global__ __launch_bounds__(256) void k_psf_dft(const float* __restrict__ p,
                                                 float* __restrict__ psfh) {
    int blk = blockIdx.x;           // h*256 + tb
    int h = blk >> 8, tb = blk & 255;
    int t0 = tb * 4;
    int tid = threadIdx.x;
    int w = tid >> 6, lane = tid & 63;
    __shared__ float pv[4][64], cc[64], ssn[64];
    if (tid < 64) {
        float ang = TWOPI_64 * tid;
        cc[tid] = cosf(ang); ssn[tid] = sinf(ang);
    }
    pv[w][lane] = p[((size_t)h * 1024 + t0 + w) * 64 + lane];
    __syncthreads();
    if (lane < NK) {
        float re = 0.f, im = 0.f;
#pragma unroll 8
        for (int e = 0; e < 64; ++e) {
            int j = (lane * e) & 63;
            float v = pv[w][e];
            re += v * cc[j];
            im -= v * ssn[j];
        }
        size_t o = (((size_t)h * NK + lane) * 1024 + t0 + w) * 2;
        psfh[o] = re; psfh[o + 1] = im;
    }
}

// ---------------- DFT of uniform tap value q[h][e] ----------------
__global__ __launch_bounds__(64) void k_q_dft(const float* __restrict__ q,
                                              float* __restrict__ qh) {
    int h = blockIdx.x;
    int tid = threadIdx.x;
    __shared__ float qv[64], cc[64], ssn[64];
    qv[tid] = q[h * 64 + tid];
    float ang = TWOPI_64 * tid;
    cc[tid] = cosf(ang); ssn[tid] = sinf(ang);
    __syncthreads();
    if (tid < NK) {
        float re = 0.f, im = 0.f;
        for (int e = 0; e < 64; ++e) {
            int j = (tid * e) & 63;
            re += qv[e] * cc[j];
            im -= qv[e] * ssn[j];
        }
        qh[(h * NK + tid) * 2] = re;
        qh[(h * NK + tid) * 2 + 1] = im;
    }
}

__device__ __forceinline__ void build_twiddles(float2* tw, int tid) {
#pragma unroll
    for (int it = 0; it < 4; ++it) {
        int j = tid + it * 256;
        float a = (float)j * 3.0679615757712823e-3f;   // 2*pi/2048
        float sv, cv;
        __sincosf(a, &sv, &cv);
        tw[j] = make_float2(cv, -sv);
    }
}

// ---------------- fused radix-2 stage-pair (swizzled LDS) ----------------
__device__ __forceinline__ void fft_pair(const float2* __restrict__ X,
                                         float2* __restrict__ Y,
                                         const float2* __restrict__ tw,
                                         int tid, int m) {
#pragma unroll
    for (int it = 0; it < 2; ++it) {
        int i = tid + it * 256;
        int r = i & (m - 1);
        int am = i - r;
        float2 w1 = tw[am];
        float2 w1b = make_float2(w1.y, -w1.x);   // tw[am+512] = -j*w1
        float2 w2 = tw[2 * am];
        float2 x0 = X[SW(i)], x1 = X[SW(i + 512)], x2 = X[SW(i + 1024)], x3 = X[SW(i + 1536)];
        float2 y0 = make_float2(x0.x + x2.x, x0.y + x2.y);
        float2 y1 = cmul(make_float2(x0.x - x2.x, x0.y - x2.y), w1);
        float2 y2 = make_float2(x1.x + x3.x, x1.y + x3.y);
        float2 y3 = cmul(make_float2(x1.x - x3.x, x1.y - x3.y), w1b);
        int o = 4 * am + r;
        Y[SW(o)] = make_float2(y0.x + y2.x, y0.y + y2.y);
        Y[SW(o + m)] = make_float2(y1.x + y3.x, y1.y + y3.y);
        Y[SW(o + 2 * m)] = cmul(make_float2(y0.x - y2.x, y0.y - y2.y), w2);
        Y[SW(o + 3 * m)] = cmul(make_float2(y1.x - y3.x, y1.y - y3.y), w2);
    }
}

// ---------------- FFT of tap vector per (h,k) ----------------
__global__ __launch_bounds__(256) void k_tap_fft(const float* __restrict__ psfh,
                                                 const float* __restrict__ qh,
                                                 float* __restrict__ phf) {
    __shared__ float2 A[2048], B[2048], tw[1024];
    int hk = blockIdx.x, tid = threadIdx.x;
    build_twiddles(tw, tid);
    float2 qv = make_float2(qh[hk * 2], qh[hk * 2 + 1]);
    const float2* Pg = (const float2*)(psfh + (size_t)hk * 2048);
    __syncthreads();
#pragma unroll
    for (int it = 0; it < 2; ++it) {
        int i = tid + it * 256;
        float2 x0 = Pg[i], x1 = Pg[i + 512];
        float2 x2 = (i == 0) ? make_float2(0.f, 0.f) : qv;
        float2 x3 = qv;
        float2 w1 = tw[i];
        float2 w1b = make_float2(w1.y, -w1.x);
        float2 w2 = tw[2 * i];
        float2 y0 = make_float2(x0.x + x2.x, x0.y + x2.y);
        float2 y1 = cmul(make_float2(x0.x - x2.x, x0.y - x2.y), w1);
        float2 y2 = make_float2(x1.x + x3.x, x1.y + x3.y);
        float2 y3 = cmul(make_float2(x1.x - x3.x, x1.y - x3.y), w1b);
        int o = 4 * i;
        A[SW(o)] = make_float2(y0.x + y2.x, y0.y + y2.y);
        A[SW(o + 1)] = make_float2(y1.x + y3.x, y1.y + y3.y);
        A[SW(o + 2)] = cmul(make_float2(y0.x - y2.x, y0.y - y2.y), w2);
        A[SW(o + 3)] = cmul(make_float2(y1.x - y3.x, y1.y - y3.y), w2);
    }
    __syncthreads();
    fft_pair(A, B, tw, tid, 4);   __syncthreads();
    fft_pair(B, A, tw, tid, 16);  __syncthreads();
    fft_pair(A, B, tw, tid, 64);  __syncthreads();
    fft_pair(B, A, tw, tid, 256); __syncthreads();
    float2* out = (float2*)(phf + (size_t)hk * 4096);
#pragma unroll
    for (int it = 0; it < 4; ++it) {
        int t = tid + it * 256;
        float2 lo = A[SW(t)], hi = A[SW(t + 1024)];
        out[t] = make_float2(lo.x + hi.x, lo.y + hi.y);
        out[t + 1024] = make_float2(lo.x - hi.x, lo.y - hi.y);
    }
}

// ---------------- per-(b,h,k) conv via circular-2048 FFT ----------------
__global__ __launch_bounds__(256) void k_conv_fft(const float* __restrict__ XH,
                                                  const float* __restrict__ PHF,
                                                  float* __restrict__ YH) {
    __shared__ float2 A[2048], B[2048], tw[1024];
    int bhk = blockIdx.x, tid = threadIdx.x;
    int hk = bhk % NHK;
    build_twiddles(tw, tid);
    const float2* Xg = (const float2*)(XH + (size_t)bhk * 2048);
    __syncthreads();
#pragma unroll
    for (int it = 0; it < 2; ++it) {
        int i = tid + it * 256;
        float2 x0 = Xg[i];
        float2 x1 = Xg[i + 512];
        float2 w1 = tw[i];
        float2 w1b = make_float2(w1.y, -w1.x);
        float2 w2 = tw[2 * i];
        float2 y1 = cmul(x0, w1);
        float2 y3 = cmul(x1, w1b);
        int o = 4 * i;
        A[SW(o)] = make_float2(x0.x + x1.x, x0.y + x1.y);
        A[SW(o + 1)] = make_float2(y1.x + y3.x, y1.y + y3.y);
        A[SW(o + 2)] = cmul(make_float2(x0.x - x1.x, x0.y - x1.y), w2);
        A[SW(o + 3)] = cmul(make_float2(y1.x - y3.x, y1.y - y3.y), w2);
    }
    __syncthreads();
    fft_pair(A, B, tw, tid, 4);   __syncthreads();
    fft_pair(B, A, tw, tid, 16);  __syncthreads();
    fft_pair(A, B, tw, tid, 64);  __syncthreads();
    fft_pair(B, A, tw, tid, 256); __syncthreads();
    const float2* P = (const float2*)(PHF + (size_t)hk * 4096);
    float2 q[8];
#pragma unroll
    for (int it = 0; it < 4; ++it) {
        int t = tid + it * 256;
        float2 lo = A[SW(t)], hi = A[SW(t + 1024)];
        float2 fl = make_float2(lo.x + hi.x, lo.y + hi.y);
        float2 fh = make_float2(lo.x - hi.x, lo.y - hi.y);
        float2 vl = cmul(fl, P[t]);
        float2 vh = cmul(fh, P[t + 1024]);
        q[it] = make_float2(vl.x, -vl.y);
        q[it + 4] = make_float2(vh.x, -vh.y);
    }
#pragma unroll
    for (int it = 0; it < 2; ++it) {
        int i = tid + it * 256;
        float2 x0 = q[it], x1 = q[it + 2], x2 = q[it + 4], x3 = q[it + 6];
        float2 w1 = tw[i];
        float2 w1b = make_float2(w1.y, -w1.x);
        float2 w2 = tw[2 * i];
        float2 y0 = make_float2(x0.x + x2.x, x0.y + x2.y);
        float2 y1 = cmul(make_float2(x0.x - x2.x, x0.y - x2.y), w1);
        float2 y2 = make_float2(x1.x + x3.x, x1.y + x3.y);
        float2 y3 = cmul(make_float2(x1.x - x3.x, x1.y - x3.y), w1b);
        int o = 4 * i;
        B[SW(o)] = make_float2(y0.x + y2.x, y0.y + y2.y);
        B[SW(o + 1)] = make_float2(y1.x + y3.x, y1.y + y3.y);
        B[SW(o + 2)] = cmul(make_float2(y0.x - y2.x, y0.y - y2.y), w2);
        B[SW(o + 3)] = cmul(make_float2(y1.x - y3.x, y1.y - y3.y), w2);
    }
    __syncthreads();
    fft_pair(B, A, tw, tid, 4);   __syncthreads();
    fft_pair(A, B, tw, tid, 16);  __syncthreads();
    fft_pair(B, A, tw, tid, 64);  __syncthreads();
    fft_pair(A, B, tw, tid, 256); __syncthreads();
    float2* Yg = (float2*)(YH + (size_t)bhk * 2048);
    const float inv_n = 1.0f / 2048.0f;
#pragma unroll
    for (int it = 0; it < 4; ++it) {
        int s = tid + it * 256;
        float2 lo = B[SW(s)], hi = B[SW(s + 1024)];
        Yg[s] = make_float2((lo.x + hi.x) * inv_n, -(lo.y + hi.y) * inv_n);
    }
}

// ---------------- build per-head forward DFT block Wf1 [128][64] bf16 ----------------
// row m = 2k+od (m<66): od=0 -> cos(2*pi*k*d/64), od=1 -> -sin(...); rows 66..127 zero
__global__ __launch_bounds__(64) void k_build_wf1(unsigned short* __restrict__ W) {
    int m = blockIdx.x;                  // 0..127
    int d = threadIdx.x;                 // 0..63
    float val = 0.f;
    if (m < 66) {
        int k = m >> 1, od = m & 1;
        int j = (k * d) & 63;
        float ang = TWOPI_64 * (float)j;
        val = od ? -sinf(ang) : cosf(ang);
    }
    W[m * 64 + d] = f2bf(val);
}

// ---------------- build per-head inverse DFT block Wi1 [128][64] bf16 ----------------
// row = d (d<64, rows 64..127 zero); col c: c=0->(k=0,re,1/64); c=1->(k=32,re,1/64);
// c>=2: k=c>>1, od=c&1, coeff 2/64.
__global__ __launch_bounds__(64) void k_build_wi1(unsigned short* __restrict__ W) {
    int m = blockIdx.x;                  // 0..127 (= d if <64)
    int c = threadIdx.x;                 // 0..63
    float val = 0.f;
    if (m < 64) {
        int d = m;
        int k, od;
        float ck;
        if (c == 0)      { k = 0;  od = 0; ck = 1.f / 64.f; }
        else if (c == 1) { k = 32; od = 0; ck = 1.f / 64.f; }
        else             { k = c >> 1; od = c & 1; ck = 2.f / 64.f; }
        int j = (k * d) & 63;
        float ang = TWOPI_64 * (float)j;
        val = od ? -sinf(ang) * ck : cosf(ang) * ck;
    }
    W[m * 64 + c] = f2bf(val);
}

// ---------------- BK=64 MFMA core ----------------
__device__ __forceinline__ void mfma_core64(const unsigned short* __restrict__ gA0,
                                            const unsigned short* __restrict__ gB0,
                                            int nkt,
                                            unsigned short* __restrict__ As,
                                            unsigned short* __restrict__ Bs,
                                            int tid, int lane, int wr, int wc,
                                            f32x4 acc[4][4]) {
    int r0 = tid >> 1, hs = (tid & 1) << 2;
    int wbase = r0 * 64;
    int swr = r0 & 7;
    int kg = lane >> 4, cl = lane & 15;
    int fra[8], frb[8];
#pragma unroll
    for (int kk = 0; kk < 2; ++kk)
#pragma unroll
        for (int i = 0; i < 4; ++i) {
            int ra = wr * 64 + i * 16 + cl;
            fra[kk * 4 + i] = ra * 64 + (((kk * 4 + kg) ^ (ra & 7)) << 3);
            int rb = wc * 64 + i * 16 + cl;
            frb[kk * 4 + i] = rb * 64 + (((kk * 4 + kg) ^ (rb & 7)) << 3);
        }
    s16x8 a[4], b[4];
#pragma unroll
    for (int l = 0; l < 4; ++l) {
        a[l] = *(const s16x8*)(gA0 + l * 8);
        b[l] = *(const s16x8*)(gB0 + l * 8);
    }
    for (int kt = 0; kt < nkt; ++kt) {
        __syncthreads();
#pragma unroll
        for (int l = 0; l < 4; ++l) {
            *(s16x8*)&As[wbase + (((hs + l) ^ swr) << 3)] = a[l];
            *(s16x8*)&Bs[wbase + (((hs + l) ^ swr) << 3)] = b[l];
        }
        __syncthreads();
        if (kt + 1 < nkt) {
            size_t ko = (size_t)(kt + 1) * 64;
#pragma unroll
            for (int l = 0; l < 4; ++l) {
                a[l] = *(const s16x8*)(gA0 + ko + l * 8);
                b[l] = *(const s16x8*)(gB0 + ko + l * 8);
            }
        }
#pragma unroll
        for (int kk = 0; kk < 2; ++kk) {
            s16x8 af[4], bfr[4];
#pragma unroll
            for (int i = 0; i < 4; ++i) af[i] = *(const s16x8*)&As[fra[kk * 4 + i]];
#pragma unroll
            for (int i = 0; i < 4; ++i) bfr[i] = *(const s16x8*)&Bs[frb[kk * 4 + i]];
#pragma unroll
            for (int mi = 0; mi < 4; ++mi)
#pragma unroll
                for (int ni = 0; ni < 4; ++ni)
                    acc[mi][ni] = __builtin_amdgcn_mfma_f32_16x16x32_bf16(af[mi], bfr[ni], acc[mi][ni], 0, 0, 0);
        }
    }
}

// ---------------- bf16 MFMA GEMM with bf16 output (pre & post projections) ----------------
__global__ __launch_bounds__(256) void k_mfma_abt_bf(const unsigned short* __restrict__ A,
                                                     const unsigned short* __restrict__ W,
                                                     const float* __restrict__ bias,
                                                     unsigned short* __restrict__ C,
                                                     int M, int N, int K) {
    int n0 = blockIdx.x * 128, m0 = blockIdx.y * 128;
    int tid = threadIdx.x;
    int lane = tid & 63, wave = tid >> 6;
    int wr = wave >> 1, wc = wave & 1;
    __shared__ __align__(16) unsigned short As[8192], Bs[8192];
    f32x4 acc[4][4] = {};
    int r0 = tid >> 1, hs = (tid & 1) << 2;
    const unsigned short* gA0 = A + (size_t)(m0 + r0) * K + hs * 8;
    const unsigned short* gB0 = W + (size_t)(n0 + r0) * K + hs * 8;
    mfma_core64(gA0, gB0, K >> 6, As, Bs, tid, lane, wr, wc, acc);
    int kg = lane >> 4, cl = lane & 15;
#pragma unroll
    for (int ni = 0; ni < 4; ++ni) {
        int gn = n0 + wc * 64 + ni * 16 + cl;
        float bv = bias ? bias[gn] : 0.f;
#pragma unroll
        for (int mi = 0; mi < 4; ++mi) {
            int gm = m0 + wr * 64 + mi * 16 + kg * 4;
            f32x4 v = acc[mi][ni];
#pragma unroll
            for (int ri = 0; ri < 4; ++ri)
                C[(size_t)(gm + ri) * N + gn] = f2bf(v[ri] + bv);
        }
    }
}

// ---------------- per-head forward DFT GEMM: XH planes = Wf1 @ x_h^T ----------------
__global__ __launch_bounds__(256) void k_mfma_dft_h(const unsigned short* __restrict__ Wf1,
                                                    const unsigned short* __restrict__ Xb,
                                                    float* __restrict__ XH) {
    int n0 = blockIdx.x * 128;          // x-row tile
    int h = blockIdx.y;                 // head
    int tid = threadIdx.x;
    int lane = tid & 63, wave = tid >> 6;
    int wr = wave >> 1, wc = wave & 1;
    __shared__ __align__(16) unsigned short As[8192], Bs[8192];
    f32x4 acc[4][4] = {};
    int r0 = tid >> 1, hs = (tid & 1) << 2;
    const unsigned short* gA0 = Wf1 + r0 * 64 + hs * 8;
    const unsigned short* gB0 = Xb + (size_t)(n0 + r0) * Dn + h * 64 + hs * 8;
    mfma_core64(gA0, gB0, 1, As, Bs, tid, lane, wr, wc, acc);
    int kg = lane >> 4, cl = lane & 15;
#pragma unroll
    for (int ni = 0; ni < 4; ++ni) {
        int gn = n0 + wc * 64 + ni * 16 + cl;   // global x row
        int b = gn >> 10, u = gn & 1023;
#pragma unroll
        for (int mi = 0; mi < 4; ++mi) {
            int gmb = wr * 64 + mi * 16 + kg * 4;
            f32x4 v = acc[mi][ni];
#pragma unroll
            for (int rp = 0; rp < 2; ++rp) {
                int m = gmb + rp * 2;           // even: pair (re,im) of bin m>>1
                if (m < 66) {
                    size_t plane = (size_t)(b * Hn + h) * NK + (m >> 1);
                    *(float2*)&XH[(plane * 1024 + u) * 2] = make_float2(v[rp * 2], v[rp * 2 + 1]);
                }
            }
        }
    }
}

// ---------------- Y planes (interleaved) -> packed bf16 YT [16384][768] ----------------
// per head 64 cols: c=0:(k0,re), c=1:(k32,re), c=2k+od (k>=1)
__global__ __launch_bounds__(256) void k_transpose_yh(const float* __restrict__ YH,
                                                      unsigned short* __restrict__ YT) {
    int ut = blockIdx.x & 7;
    int h = (blockIdx.x >> 3) % 12;
    int b = blockIdx.x / 96;
    int u0 = ut * 128;
    __shared__ unsigned short T[128 * 66];
    int tid = threadIdx.x;
    int planeBase = (b * Hn + h) * NK;
    const float2* Yg = (const float2*)YH;
#pragma unroll
    for (int i = 0; i < 17; ++i) {
        int idx = tid + i * 256;        // 33k x 128uo
        if (idx < 4224) {
            int k = idx >> 7, uo = idx & 127;
            float2 v = Yg[(size_t)(planeBase + k) * 1024 + u0 + uo];
            T[uo * 66 + 2 * k] = f2bf(v.x);
            T[uo * 66 + 2 * k + 1] = f2bf(v.y);
        }
    }
    __syncthreads();
    unsigned int* out = (unsigned int*)YT;
#pragma unroll
    for (int i = 0; i < 16; ++i) {
        int idx = tid + i * 256;        // 128uo x 32w
        int uo = idx >> 5, w = idx & 31;
        unsigned int lo, hi;
        if (w == 0) {
            lo = T[uo * 66 + 0];        // re k=0
            hi = T[uo * 66 + 64];       // re k=32
        } else {
            lo = T[uo * 66 + 2 * w];    // re k=w
            hi = T[uo * 66 + 2 * w + 1];// im k=w
        }
        size_t r = (size_t)b * 1024 + u0 + uo;
        out[r * 384 + h * 32 + w] = lo | (hi << 16);
    }
}

// ---------------- per-head inverse DFT + GELU GEMM: G_h = gelu(YT_h @ Wi1^T) ----------------
__global__ __launch_bounds__(256) void k_mfma_idft_h(const unsigned short* __restrict__ YT,
                                                     const unsigned short* __restrict__ Wi1,
                                                     unsigned short* __restrict__ G) {
    int m0 = blockIdx.x * 128;          // row tile
    int h = blockIdx.y;                 // head
    int tid = threadIdx.x;
    int lane = tid & 63, wave = tid >> 6;
    int wr = wave >> 1, wc = wave & 1;
    __shared__ __align__(16) unsigned short As[8192], Bs[8192];
    f32x4 acc[4][4] = {};
    int r0 = tid >> 1, hs = (tid & 1) << 2;
    const unsigned short* gA0 = YT + (size_t)(m0 + r0) * Dn + h * 64 + hs * 8;
    const unsigned short* gB0 = Wi1 + r0 * 64 + hs * 8;
    mfma_core64(gA0, gB0, 1, As, Bs, tid, lane, wr, wc, acc);
    int kg = lane >> 4, cl = lane & 15;
#pragma unroll
    for (int ni = 0; ni < 4; ++ni) {
        int gn = wc * 64 + ni * 16 + cl;    // d index (valid < 64)
        if (gn < 64) {
#pragma unroll
            for (int mi = 0; mi < 4; ++mi) {
                int gm = m0 + wr * 64 + mi * 16 + kg * 4;
                f32x4 v = acc[mi][ni];
#pragma unroll
                for (int ri = 0; ri < 4; ++ri) {
                    float c = v[ri];
                    float g = c * 0.5f * (1.0f + erff(c * 0.70710678118f));
                    G[(size_t)(gm + ri) * Dn + h * 64 + gn] = f2bf(g);
                }
            }
        }
    }
}

// ---------------- sparse: spe_b = (tril(SP)/sigma) @ x_b, bf16 out ----------------
__global__ __launch_bounds__(256) void k_mfma_sparse(const unsigned short* __restrict__ SP,
                                                     const unsigned short* __restrict__ XT,
                                                     const float* __restrict__ sigbuf,
                                                     unsigned short* __restrict__ C) {
    int bx = blockIdx.x;
    int mt = bx & 7, nt = (bx >> 3) % 6, b = bx / 48;
    int m0 = mt * 128, n0 = nt * 128;
    const unsigned short* Xb = XT + (size_t)b * Dn * Ln;
    unsigned short* Cb = C + (size_t)b * Ln * Dn;
    int tid = threadIdx.x;
    int lane = tid & 63, wave = tid >> 6;
    int wr = wave >> 1, wc = wave & 1;
    __shared__ __align__(16) unsigned short As[8192], Bs[8192];
    f32x4 acc[4][4] = {};
    int r0 = tid >> 1, hs = (tid & 1) << 2;
    const unsigned short* gA0 = SP + (size_t)(m0 + r0) * Ln + hs * 8;
    const unsigned short* gB0 = Xb + (size_t)(n0 + r0) * Ln + hs * 8;
    mfma_core64(gA0, gB0, 2 * mt + 2, As, Bs, tid, lane, wr, wc, acc);
    float invs = sigbuf[0];
    int kg = lane >> 4, cl = lane & 15;
#pragma unroll
    for (int ni = 0; ni < 4; ++ni) {
        int gn = n0 + wc * 64 + ni * 16 + cl;
#pragma unroll
        for (int mi = 0; mi < 4; ++mi) {
            int gm = m0 + wr * 64 + mi * 16 + kg * 4;
            f32x4 v = acc[mi][ni];
#pragma unroll
            for (int ri = 0; ri < 4; ++ri)
                Cb[(size_t)(gm + ri) * Dn + gn] = f2bf(v[ri] * invs);
        }
    }
}

// ---------------- conversions ----------------
__global__ __launch_bounds__(256) void k_cvt_bf16(const float* __restrict__ in,
                                                  unsigned short* __restrict__ out, int n4) {
    int i = blockIdx.x * 256 + threadIdx.x;
    if (i < n4) {
        float4 v = ((const float4*)in)[i];
        u16x4 o;
        o[0] = f2bf(v.x); o[1] = f2bf(v.y); o[2] = f2bf(v.z); o[3] = f2bf(v.w);
        *(u16x4*)&out[(size_t)i * 4] = o;
    }
}

__global__ __launch_bounds__(256) void k_cvt_sp(const float* __restrict__ SP,
                                                unsigned short* __restrict__ O) {
    int s = blockIdx.x;
    int t0 = threadIdx.x * 4;
    float4 v = *(const float4*)&SP[(size_t)s * 1024 + t0];
    u16x4 o;
    o[0] = (t0 + 0 <= s) ? f2bf(v.x) : 0;
    o[1] = (t0 + 1 <= s) ? f2bf(v.y) : 0;
    o[2] = (t0 + 2 <= s) ? f2bf(v.z) : 0;
    o[3] = (t0 + 3 <= s) ? f2bf(v.w) : 0;
    *(u16x4*)&O[(size_t)s * 1024 + t0] = o;
}

// ---------------- x_bf[b][t][d] -> xT[b][d][t] bf16 ----------------
__global__ __launch_bounds__(256) void k_transpose_x(const unsigned short* __restrict__ X,
                                                     unsigned short* __restrict__ XT) {
    int d0 = blockIdx.x * 64, t0 = blockIdx.y * 64, b = blockIdx.z;
    const unsigned short* Xb = X + (size_t)b * Ln * Dn;
    unsigned short* Tb = XT + (size_t)b * Dn * Ln;
    __shared__ unsigned short tile[64 * 65];
    int tx = threadIdx.x & 63, ty = threadIdx.x >> 6;
#pragma unroll
    for (int i = 0; i < 16; ++i) {
        int t = ty + i * 4;
        tile[t * 65 + tx] = Xb[(size_t)(t0 + t) * Dn + d0 + tx];
    }
    __syncthreads();
#pragma unroll
    for (int i = 0; i < 16; ++i) {
        int d = ty + i * 4;
        Tb[(size_t)(d0 + d) * Ln + t0 + tx] = tile[tx * 65 + d];
    }
}

// ---------------- spectral norm ----------------
__global__ __launch_bounds__(256) void k_sn_colsum(const float* __restrict__ Wm,
                                                   float* __restrict__ partial) {
    int b = blockIdx.x;
    int tid = threadIdx.x;
    int c0 = tid * 4;
    float4 s = make_float4(0.f, 0.f, 0.f, 0.f);
#pragma unroll
    for (int i = 0; i < 16; ++i) {
        float4 v = *(const float4*)&Wm[(size_t)(b * 16 + i) * 1024 + c0];
        s.x += v.x; s.y += v.y; s.z += v.z; s.w += v.w;
    }
    *(float4*)&partial[(size_t)b * 1024 + c0] = s;
}

__global__ __launch_bounds__(1024) void k_sn_v2(const float* __restrict__ partial,
                                                float* __restrict__ v) {
    int j = threadIdx.x;
    float s = 0.f;
#pragma unroll 8
    for (int i = 0; i < 64; ++i) s += partial[(size_t)i * 1024 + j];
    s *= 0.03125f;
    __shared__ float red[1024];
    red[j] = s * s; __syncthreads();
    for (int st = 512; st > 0; st >>= 1) {
        if (j < st) red[j] += red[j + st];
        __syncthreads();
    }
    float nrm = sqrtf(red[0]);
    v[j] = s / (nrm + 1e-12f);
}

__global__ __launch_bounds__(64) void k_sn_u(const float* __restrict__ Wm,
                                             const float* __restrict__ v,
                                             float* __restrict__ ur) {
    int i = blockIdx.x;
    int lane = threadIdx.x;
    float s = 0.f;
    for (int j = lane; j < 1024; j += 64) s += Wm[(size_t)i * 1024 + j] * v[j];
#pragma unroll
    for (int off = 32; off > 0; off >>= 1) s += __shfl_down(s, off);
    if (lane == 0) ur[i] = s;
}

__global__ __launch_bounds__(1024) void k_sn_sigma(const float* __restrict__ ur,
                                                   float* __restrict__ sig) {
    int i = threadIdx.x;
    __shared__ float red[1024];
    float u = ur[i];
    red[i] = u * u; __syncthreads();
    for (int st = 512; st > 0; st >>= 1) {
        if (i < st) red[i] += red[i + st];
        __syncthreads();
    }
    if (i == 0) {
        float ss = red[0];
        float sigma = ss / (sqrtf(ss) + 1e-12f);
        sig[0] = 1.0f / sigma;
    }
}

// ---------------- final residual + LayerNorm (bf16 CE/SE) ----------------
__global__ __launch_bounds__(256) void k_final_ln(const unsigned short* __restrict__ CE,
                                                  const unsigned short* __restrict__ SE,
                                                  const float* __restrict__ EMB,
                                                  const float* __restrict__ g,
                                                  const float* __restrict__ be,
                                                  float* __restrict__ out) {
    int r = blockIdx.x;
    int tid = threadIdx.x;
    float y[3];
    float s = 0.f;
#pragma unroll
    for (int i = 0; i < 3; ++i) {
        int o = tid + i * 256;
        size_t idx = (size_t)r * 768 + o;
        y[i] = bf2f(CE[idx]) + bf2f(SE[idx]) + EMB[idx];
        s += y[i];
    }
    __shared__ float red[256];
    red[tid] = s; __syncthreads();
    for (int st = 128; st > 0; st >>= 1) {
        if (tid < st) red[tid] += red[tid + st];
        __syncthreads();
    }
    float mu = red[0] * (1.f / 768.f);
    __syncthreads();
    float vs = 0.f;
#pragma unroll
    for (int i = 0; i < 3; ++i) { float d = y[i] - mu; vs += d * d; }
    red[tid] = vs; __syncthreads();
    for (int st = 128; st > 0; st >>= 1) {
        if (tid < st) red[tid] += red[tid + st];
        __syncthreads();
    }
    float var = red[0] * (1.f / 768.f);
    float rstd = rsqrtf(var + 1e-12f);
#pragma unroll
    for (int i = 0; i < 3; ++i) {
        int o = tid + i * 256;
        size_t idx = (size_t)r * 768 + o;
        out[idx] = (y[i] - mu) * rstd * g[o] + be[o];
    }
}

extern "C" void kernel_launch(void* const* d_in, const int* in_sizes, int n_in,
                              void* d_out, int out_size, void* d_ws, size_t ws_size,
                              hipStream_t stream) {
    const float* emb     = (const float*)d_in[0];
    const float* pre_w   = (const float*)d_in[1];
    const float* pre_b   = (const float*)d_in[2];
    const float* psfs    = (const float*)d_in[3];
    const float* post_w  = (const float*)d_in[4];
    const float* post_b  = (const float*)d_in[5];
    const float* spmat   = (const float*)d_in[6];
    const float* ln_g    = (const float*)d_in[7];
    const float* ln_b    = (const float*)d_in[8];
    float* out = (float*)d_out;
    float* ws = (float*)d_ws;

    float* p      = ws + O_P;
    float* psfh   = ws + O_PSFH;
    float* part   = ws + O_PART;
    float* qh     = ws + O_QH;
    float* q      = ws + O_SIG + 8;
    float* XH     = ws + O_XH;                       // interleaved [bhk][1024][2]
    float* YH     = ws + O_YH;                       // interleaved
    float* phf    = ws + O_SPE;                      // alias (dead after conv)
    float* v      = ws + O_V;
    float* urw    = ws + O_UR;
    float* sig    = ws + O_SIG;

    unsigned short* x_bf      = (unsigned short*)(ws + O_X);
    unsigned short* Wf1       = (unsigned short*)(ws + O_X + 6291456);      // [128][64]
    unsigned short* Wi1       = (unsigned short*)(ws + O_X + 6295552);      // [128][64]
    unsigned short* YT        = (unsigned short*)(ws + O_XH);               // [16384][768] over dead XH
    unsigned short* xT_bf     = (unsigned short*)(ws + O_XH);               // over dead YT
    unsigned short* emb_bf    = (unsigned short*)(ws + O_YH);               // dead before YH written
    unsigned short* CE_bf     = (unsigned short*)(ws + O_YH);               // over dead YH
    unsigned short* spe_bf    = (unsigned short*)(ws + O_SPE);              // over dead phf
    unsigned short* G_bf      = (unsigned short*)(ws + O_SPE + 3145728);    // disjoint from spe/phf
    unsigned short* SP_bf     = (unsigned short*)(ws + O_P);                // over dead p
    unsigned short* pre_w_bf  = (unsigned short*)(ws + O_PSFH);             // over dead psfh
    unsigned short* post_w_bf = (unsigned short*)(ws + O_PSFH + 294912);

    // PSF preprocessing
    k_psf_softmax<<<Hn * 64, 256, 0, stream>>>(psfs, p, q);
    k_psf_dft<<<Hn * 256, 256, 0, stream>>>(p, psfh);
    k_q_dft<<<Hn, 64, 0, stream>>>(q, qh);
    k_tap_fft<<<NHK, 256, 0, stream>>>(psfh, qh, phf);

    // spectral norm scalar
    k_sn_colsum<<<64, 256, 0, stream>>>(spmat, part);
    k_sn_v2<<<1, 1024, 0, stream>>>(part, v);
    k_sn_u<<<1024, 64, 0, stream>>>(spmat, v, urw);
    k_sn_sigma<<<1, 1024, 0, stream>>>(urw, sig);

    // conversions + DFT block builds
    k_cvt_sp<<<1024, 256, 0, stream>>>(spmat, SP_bf);
    k_cvt_bf16<<<576, 256, 0, stream>>>(pre_w, pre_w_bf, 147456);
    k_cvt_bf16<<<576, 256, 0, stream>>>(post_w, post_w_bf, 147456);
    k_cvt_bf16<<<12288, 256, 0, stream>>>(emb, emb_bf, 3145728);
    k_build_wf1<<<128, 64, 0, stream>>>(Wf1);
    k_build_wi1<<<128, 64, 0, stream>>>(Wi1);

    // pre-projection (MFMA bf16 -> bf16 x)
    k_mfma_abt_bf<<<dim3(6, 128), 256, 0, stream>>>(emb_bf, pre_w_bf, pre_b, x_bf, Bn * Ln, Dn, Dn);

    // head-dim DFT: per-head batched GEMM -> interleaved planes
    k_mfma_dft_h<<<dim3(128, Hn), 256, 0, stream>>>(Wf1, x_bf, XH);

    // causal conv + uniform suffix via circular-2048 FFT (swizzled LDS)
    k_conv_fft<<<Bn * NHK, 256, 0, stream>>>(XH, phf, YH);

    // Y planes -> packed bf16 YT [16384][768]
    k_transpose_yh<<<Bn * Hn * 8, 256, 0, stream>>>(YH, YT);

    // inverse DFT + GELU: per-head batched GEMM -> G bf16
    k_mfma_idft_h<<<dim3(128, Hn), 256, 0, stream>>>(YT, Wi1, G_bf);

    // transpose x -> xT bf16 (over dead YT)
    k_transpose_x<<<dim3(12, 16, Bn), 256, 0, stream>>>(x_bf, xT_bf);

    // post-projection (MFMA bf16) -> CE bf16 (over dead YH)
    k_mfma_abt_bf<<<dim3(6, 128), 256, 0, stream>>>(G_bf, post_w_bf, post_b, CE_bf, Bn * Ln, Dn, Dn);

    // sparse branch (MFMA bf16, triangular k-loop) -> spe bf16 (over dead phf)
    k_mfma_sparse<<<768, 256, 0, stream>>>(SP_bf, xT_bf, sig, spe_bf);

    // residual + LayerNorm
    k_final_ln<<<Bn * Ln, 256, 0, stream>>>(CE_bf, spe_bf, emb, ln_g, ln_b, out);
}

// Round 10
// 319.532 us; speedup vs baseline: 9.9446x; 1.0249x over previous
//
#include <hip/hip_runtime.h>
#include <math.h>

// Problem constants
#define Bn 16
#define Ln 1024
#define Dn 768
#define Hn 12
#define PHDn 64
#define NK 33                 // Hermitian bins for 64-pt DFT (k=0..32)
#define NHK (Hn * NK)         // 396
#define TWOPI_64 0.09817477042468103f   // 2*pi/64

typedef short s16x8 __attribute__((ext_vector_type(8)));
typedef float f32x4 __attribute__((ext_vector_type(4)));
typedef unsigned short u16x4 __attribute__((ext_vector_type(4)));

__device__ __forceinline__ unsigned short f2bf(float f) {
    unsigned int u = __float_as_uint(f);
    unsigned int r = (u + 0x7FFFu + ((u >> 16) & 1u)) >> 16;
    return (unsigned short)r;
}
__device__ __forceinline__ float bf2f(unsigned short s) {
    unsigned int u = ((unsigned int)s) << 16;
    return __uint_as_float(u);
}
__device__ __forceinline__ float2 cmul(float2 a, float2 b) {
    return make_float2(a.x * b.x - a.y * b.y, a.x * b.y + a.y * b.x);
}

// LDS bank swizzle (involution): bits[3:2] ^= bits[5:4], bits[1:0] ^= bits[7:6].
// Makes every FFT stage's LDS instruction <=2 lanes/bank (free on CDNA4).
#define SW(j) ((j) ^ (((j) >> 2) & 12) ^ (((j) >> 6) & 3))

// ---------------- workspace layout (float offsets) ----------------
static const size_t O_P    = 0;          // psf taps; later SP_bf
static const size_t O_PSFH = 786432;     // psf-hat; later pre_w_bf + post_w_bf
static const size_t O_PART = 1376256;    // sn column-sum partials [64][1024]
static const size_t O_QH   = 1597440;    // q-hat
static const size_t O_X    = 1598240;    // x_bf (6291456) + Wf1 (4096) + Wi1 (4096)
static const size_t O_XH   = 14181152;   // XH interleaved [bhk][1024][2]; later YT[16384][768]bf; later xT_bf
static const size_t O_YH   = 27157280;   // emb_bf early; YH interleaved; later CE_bf
static const size_t O_SPE  = 40146080;   // phf early; spe_bf later; G_bf at +3145728
static const size_t O_V    = 52728992;
static const size_t O_UR   = 52730016;
static const size_t O_SIG  = 52731040;   // inv_sigma + q[768] after

// ---------------- psf softmax over 2047 taps (1023 are zeros) ----------------
__global__ __launch_bounds__(256) void k_psf_softmax(const float* __restrict__ psfs,
                                                     float* __restrict__ p,
                                                     float* __restrict__ q) {
    int he = blockIdx.x;            // h*64+e
    int h = he >> 6, e = he & 63;
    int tid = threadIdx.x;
    float ev[4];
    float s = 0.f;
#pragma unroll
    for (int i = 0; i < 4; ++i) {
        int t = tid + 256 * i;
        float v = psfs[((size_t)h * 2047 + t) * 64 + e];
        ev[i] = expf(v);
        s += ev[i];
    }
    __shared__ float red[256];
    red[tid] = s; __syncthreads();
    for (int st = 128; st > 0; st >>= 1) {
        if (tid < st) red[tid] += red[tid + st];
        __syncthreads();
    }
    float denom = red[0] + 1023.0f;
    float inv = 1.0f / denom;
#pragma unroll
    for (int i = 0; i < 4; ++i) {
        int t = tid + 256 * i;
        p[((size_t)h * 1024 + t) * 64 + e] = ev[i] * inv;
    }
    if (tid == 0) q[he] = inv;
}

// ---------------- DFT over head-dim of psf taps (4 t per block) ----------------
__global__ __launch_bounds__(256) void k_psf_dft(const float* __restrict__ p,
                                                 float* __restrict__ psfh) {
    int blk = blockIdx.x;           // h*256 + tb
    int h = blk >> 8, tb = blk & 255;
    int t0 = tb * 4;
    int tid = threadIdx.x;
    int w = tid >> 6, lane = tid & 63;
    __shared__ float pv[4][64], cc[64], ssn[64];
    if (tid < 64) {
        float ang = TWOPI_64 * tid;
        cc[tid] = cosf(ang); ssn[tid] = sinf(ang);
    }
    pv[w][lane] = p[((size_t)h * 1024 + t0 + w) * 64 + lane];
    __syncthreads();
    if (lane < NK) {
        float re = 0.f, im = 0.f;
#pragma unroll 8
        for (int e = 0; e < 64; ++e) {
            int j = (lane * e) & 63;
            float v = pv[w][e];
            re += v * cc[j];
            im -= v * ssn[j];
        }
        size_t o = (((size_t)h * NK + lane) * 1024 + t0 + w) * 2;
        psfh[o] = re; psfh[o + 1] = im;
    }
}

// ---------------- DFT of uniform tap value q[h][e] ----------------
__global__ __launch_bounds__(64) void k_q_dft(const float* __restrict__ q,
                                              float* __restrict__ qh) {
    int h = blockIdx.x;
    int tid = threadIdx.x;
    __shared__ float qv[64], cc[64], ssn[64];
    qv[tid] = q[h * 64 + tid];
    float ang = TWOPI_64 * tid;
    cc[tid] = cosf(ang); ssn[tid] = sinf(ang);
    __syncthreads();
    if (tid < NK) {
        float re = 0.f, im = 0.f;
        for (int e = 0; e < 64; ++e) {
            int j = (tid * e) & 63;
            re += qv[e] * cc[j];
            im -= qv[e] * ssn[j];
        }
        qh[(h * NK + tid) * 2] = re;
        qh[(h * NK + tid) * 2 + 1] = im;
    }
}

// tw table: only 512 entries (indices am < 512); tw[2am] computed as tw[am]^2
__device__ __forceinline__ void build_twiddles(float2* tw, int tid) {
#pragma unroll
    for (int it = 0; it < 2; ++it) {
        int j = tid + it * 256;
        float a = (float)j * 3.0679615757712823e-3f;   // 2*pi/2048
        float sv, cv;
        __sincosf(a, &sv, &cv);
        tw[j] = make_float2(cv, -sv);
    }
}

// ---------------- fused radix-2 stage-pair (swizzled LDS, w2 = w1^2) ----------------
__device__ __forceinline__ void fft_pair(const float2* __restrict__ X,
                                         float2* __restrict__ Y,
                                         const float2* __restrict__ tw,
                                         int tid, int m) {
#pragma unroll
    for (int it = 0; it < 2; ++it) {
        int i = tid + it * 256;
        int r = i & (m - 1);
        int am = i - r;
        float2 w1 = tw[am];
        float2 w1b = make_float2(w1.y, -w1.x);   // tw[am+512] = -j*w1
        float2 w2 = cmul(w1, w1);                // tw[2am] exactly (double angle)
        float2 x0 = X[SW(i)], x1 = X[SW(i + 512)], x2 = X[SW(i + 1024)], x3 = X[SW(i + 1536)];
        float2 y0 = make_float2(x0.x + x2.x, x0.y + x2.y);
        float2 y1 = cmul(make_float2(x0.x - x2.x, x0.y - x2.y), w1);
        float2 y2 = make_float2(x1.x + x3.x, x1.y + x3.y);
        float2 y3 = cmul(make_float2(x1.x - x3.x, x1.y - x3.y), w1b);
        int o = 4 * am + r;
        Y[SW(o)] = make_float2(y0.x + y2.x, y0.y + y2.y);
        Y[SW(o + m)] = make_float2(y1.x + y3.x, y1.y + y3.y);
        Y[SW(o + 2 * m)] = cmul(make_float2(y0.x - y2.x, y0.y - y2.y), w2);
        Y[SW(o + 3 * m)] = cmul(make_float2(y1.x - y3.x, y1.y - y3.y), w2);
    }
}

// ---------------- FFT of tap vector per (h,k) ----------------
__global__ __launch_bounds__(256) void k_tap_fft(const float* __restrict__ psfh,
                                                 const float* __restrict__ qh,
                                                 float* __restrict__ phf) {
    __shared__ float2 A[2048], B[2048], tw[512];
    int hk = blockIdx.x, tid = threadIdx.x;
    build_twiddles(tw, tid);
    float2 qv = make_float2(qh[hk * 2], qh[hk * 2 + 1]);
    const float2* Pg = (const float2*)(psfh + (size_t)hk * 2048);
    __syncthreads();
#pragma unroll
    for (int it = 0; it < 2; ++it) {
        int i = tid + it * 256;
        float2 x0 = Pg[i], x1 = Pg[i + 512];
        float2 x2 = (i == 0) ? make_float2(0.f, 0.f) : qv;
        float2 x3 = qv;
        float2 w1 = tw[i];
        float2 w1b = make_float2(w1.y, -w1.x);
        float2 w2 = cmul(w1, w1);
        float2 y0 = make_float2(x0.x + x2.x, x0.y + x2.y);
        float2 y1 = cmul(make_float2(x0.x - x2.x, x0.y - x2.y), w1);
        float2 y2 = make_float2(x1.x + x3.x, x1.y + x3.y);
        float2 y3 = cmul(make_float2(x1.x - x3.x, x1.y - x3.y), w1b);
        int o = 4 * i;
        A[SW(o)] = make_float2(y0.x + y2.x, y0.y + y2.y);
        A[SW(o + 1)] = make_float2(y1.x + y3.x, y1.y + y3.y);
        A[SW(o + 2)] = cmul(make_float2(y0.x - y2.x, y0.y - y2.y), w2);
        A[SW(o + 3)] = cmul(make_float2(y1.x - y3.x, y1.y - y3.y), w2);
    }
    __syncthreads();
    fft_pair(A, B, tw, tid, 4);   __syncthreads();
    fft_pair(B, A, tw, tid, 16);  __syncthreads();
    fft_pair(A, B, tw, tid, 64);  __syncthreads();
    fft_pair(B, A, tw, tid, 256); __syncthreads();
    float2* out = (float2*)(phf + (size_t)hk * 4096);
#pragma unroll
    for (int it = 0; it < 4; ++it) {
        int t = tid + it * 256;
        float2 lo = A[SW(t)], hi = A[SW(t + 1024)];
        out[t] = make_float2(lo.x + hi.x, lo.y + hi.y);
        out[t + 1024] = make_float2(lo.x - hi.x, lo.y - hi.y);
    }
}

// ---------------- per-(b,h,k) conv via circular-2048 FFT ----------------
__global__ __launch_bounds__(256) void k_conv_fft(const float* __restrict__ XH,
                                                  const float* __restrict__ PHF,
                                                  float* __restrict__ YH) {
    __shared__ float2 A[2048], B[2048], tw[512];
    int bhk = blockIdx.x, tid = threadIdx.x;
    int hk = bhk % NHK;
    build_twiddles(tw, tid);
    const float2* Xg = (const float2*)(XH + (size_t)bhk * 2048);
    __syncthreads();
#pragma unroll
    for (int it = 0; it < 2; ++it) {
        int i = tid + it * 256;
        float2 x0 = Xg[i];
        float2 x1 = Xg[i + 512];
        float2 w1 = tw[i];
        float2 w1b = make_float2(w1.y, -w1.x);
        float2 w2 = cmul(w1, w1);
        float2 y1 = cmul(x0, w1);
        float2 y3 = cmul(x1, w1b);
        int o = 4 * i;
        A[SW(o)] = make_float2(x0.x + x1.x, x0.y + x1.y);
        A[SW(o + 1)] = make_float2(y1.x + y3.x, y1.y + y3.y);
        A[SW(o + 2)] = cmul(make_float2(x0.x - x1.x, x0.y - x1.y), w2);
        A[SW(o + 3)] = cmul(make_float2(y1.x - y3.x, y1.y - y3.y), w2);
    }
    __syncthreads();
    fft_pair(A, B, tw, tid, 4);   __syncthreads();
    fft_pair(B, A, tw, tid, 16);  __syncthreads();
    fft_pair(A, B, tw, tid, 64);  __syncthreads();
    fft_pair(B, A, tw, tid, 256); __syncthreads();
    const float2* P = (const float2*)(PHF + (size_t)hk * 4096);
    float2 q[8];
#pragma unroll
    for (int it = 0; it < 4; ++it) {
        int t = tid + it * 256;
        float2 lo = A[SW(t)], hi = A[SW(t + 1024)];
        float2 fl = make_float2(lo.x + hi.x, lo.y + hi.y);
        float2 fh = make_float2(lo.x - hi.x, lo.y - hi.y);
        float2 vl = cmul(fl, P[t]);
        float2 vh = cmul(fh, P[t + 1024]);
        q[it] = make_float2(vl.x, -vl.y);
        q[it + 4] = make_float2(vh.x, -vh.y);
    }
#pragma unroll
    for (int it = 0; it < 2; ++it) {
        int i = tid + it * 256;
        float2 x0 = q[it], x1 = q[it + 2], x2 = q[it + 4], x3 = q[it + 6];
        float2 w1 = tw[i];
        float2 w1b = make_float2(w1.y, -w1.x);
        float2 w2 = cmul(w1, w1);
        float2 y0 = make_float2(x0.x + x2.x, x0.y + x2.y);
        float2 y1 = cmul(make_float2(x0.x - x2.x, x0.y - x2.y), w1);
        float2 y2 = make_float2(x1.x + x3.x, x1.y + x3.y);
        float2 y3 = cmul(make_float2(x1.x - x3.x, x1.y - x3.y), w1b);
        int o = 4 * i;
        B[SW(o)] = make_float2(y0.x + y2.x, y0.y + y2.y);
        B[SW(o + 1)] = make_float2(y1.x + y3.x, y1.y + y3.y);
        B[SW(o + 2)] = cmul(make_float2(y0.x - y2.x, y0.y - y2.y), w2);
        B[SW(o + 3)] = cmul(make_float2(y1.x - y3.x, y1.y - y3.y), w2);
    }
    __syncthreads();
    fft_pair(B, A, tw, tid, 4);   __syncthreads();
    fft_pair(A, B, tw, tid, 16);  __syncthreads();
    fft_pair(B, A, tw, tid, 64);  __syncthreads();
    fft_pair(A, B, tw, tid, 256); __syncthreads();
    float2* Yg = (float2*)(YH + (size_t)bhk * 2048);
    const float inv_n = 1.0f / 2048.0f;
#pragma unroll
    for (int it = 0; it < 4; ++it) {
        int s = tid + it * 256;
        float2 lo = B[SW(s)], hi = B[SW(s + 1024)];
        Yg[s] = make_float2((lo.x + hi.x) * inv_n, -(lo.y + hi.y) * inv_n);
    }
}

// ---------------- build per-head forward DFT block Wf1 [128][64] bf16 ----------------
__global__ __launch_bounds__(64) void k_build_wf1(unsigned short* __restrict__ W) {
    int m = blockIdx.x;                  // 0..127
    int d = threadIdx.x;                 // 0..63
    float val = 0.f;
    if (m < 66) {
        int k = m >> 1, od = m & 1;
        int j = (k * d) & 63;
        float ang = TWOPI_64 * (float)j;
        val = od ? -sinf(ang) : cosf(ang);
    }
    W[m * 64 + d] = f2bf(val);
}

// ---------------- build per-head inverse DFT block Wi1 [128][64] bf16 ----------------
__global__ __launch_bounds__(64) void k_build_wi1(unsigned short* __restrict__ W) {
    int m = blockIdx.x;                  // 0..127 (= d if <64)
    int c = threadIdx.x;                 // 0..63
    float val = 0.f;
    if (m < 64) {
        int d = m;
        int k, od;
        float ck;
        if (c == 0)      { k = 0;  od = 0; ck = 1.f / 64.f; }
        else if (c == 1) { k = 32; od = 0; ck = 1.f / 64.f; }
        else             { k = c >> 1; od = c & 1; ck = 2.f / 64.f; }
        int j = (k * d) & 63;
        float ang = TWOPI_64 * (float)j;
        val = od ? -sinf(ang) * ck : cosf(ang) * ck;
    }
    W[m * 64 + c] = f2bf(val);
}

// ---------------- BK=64 MFMA core ----------------
__device__ __forceinline__ void mfma_core64(const unsigned short* __restrict__ gA0,
                                            const unsigned short* __restrict__ gB0,
                                            int nkt,
                                            unsigned short* __restrict__ As,
                                            unsigned short* __restrict__ Bs,
                                            int tid, int lane, int wr, int wc,
                                            f32x4 acc[4][4]) {
    int r0 = tid >> 1, hs = (tid & 1) << 2;
    int wbase = r0 * 64;
    int swr = r0 & 7;
    int kg = lane >> 4, cl = lane & 15;
    int fra[8], frb[8];
#pragma unroll
    for (int kk = 0; kk < 2; ++kk)
#pragma unroll
        for (int i = 0; i < 4; ++i) {
            int ra = wr * 64 + i * 16 + cl;
            fra[kk * 4 + i] = ra * 64 + (((kk * 4 + kg) ^ (ra & 7)) << 3);
            int rb = wc * 64 + i * 16 + cl;
            frb[kk * 4 + i] = rb * 64 + (((kk * 4 + kg) ^ (rb & 7)) << 3);
        }
    s16x8 a[4], b[4];
#pragma unroll
    for (int l = 0; l < 4; ++l) {
        a[l] = *(const s16x8*)(gA0 + l * 8);
        b[l] = *(const s16x8*)(gB0 + l * 8);
    }
    for (int kt = 0; kt < nkt; ++kt) {
        __syncthreads();
#pragma unroll
        for (int l = 0; l < 4; ++l) {
            *(s16x8*)&As[wbase + (((hs + l) ^ swr) << 3)] = a[l];
            *(s16x8*)&Bs[wbase + (((hs + l) ^ swr) << 3)] = b[l];
        }
        __syncthreads();
        if (kt + 1 < nkt) {
            size_t ko = (size_t)(kt + 1) * 64;
#pragma unroll
            for (int l = 0; l < 4; ++l) {
                a[l] = *(const s16x8*)(gA0 + ko + l * 8);
                b[l] = *(const s16x8*)(gB0 + ko + l * 8);
            }
        }
#pragma unroll
        for (int kk = 0; kk < 2; ++kk) {
            s16x8 af[4], bfr[4];
#pragma unroll
            for (int i = 0; i < 4; ++i) af[i] = *(const s16x8*)&As[fra[kk * 4 + i]];
#pragma unroll
            for (int i = 0; i < 4; ++i) bfr[i] = *(const s16x8*)&Bs[frb[kk * 4 + i]];
#pragma unroll
            for (int mi = 0; mi < 4; ++mi)
#pragma unroll
                for (int ni = 0; ni < 4; ++ni)
                    acc[mi][ni] = __builtin_amdgcn_mfma_f32_16x16x32_bf16(af[mi], bfr[ni], acc[mi][ni], 0, 0, 0);
        }
    }
}

// ---------------- bf16 MFMA GEMM with bf16 output (pre & post projections) ----------------
__global__ __launch_bounds__(256) void k_mfma_abt_bf(const unsigned short* __restrict__ A,
                                                     const unsigned short* __restrict__ W,
                                                     const float* __restrict__ bias,
                                                     unsigned short* __restrict__ C,
                                                     int M, int N, int K) {
    int n0 = blockIdx.x * 128, m0 = blockIdx.y * 128;
    int tid = threadIdx.x;
    int lane = tid & 63, wave = tid >> 6;
    int wr = wave >> 1, wc = wave & 1;
    __shared__ __align__(16) unsigned short As[8192], Bs[8192];
    f32x4 acc[4][4] = {};
    int r0 = tid >> 1, hs = (tid & 1) << 2;
    const unsigned short* gA0 = A + (size_t)(m0 + r0) * K + hs * 8;
    const unsigned short* gB0 = W + (size_t)(n0 + r0) * K + hs * 8;
    mfma_core64(gA0, gB0, K >> 6, As, Bs, tid, lane, wr, wc, acc);
    int kg = lane >> 4, cl = lane & 15;
#pragma unroll
    for (int ni = 0; ni < 4; ++ni) {
        int gn = n0 + wc * 64 + ni * 16 + cl;
        float bv = bias ? bias[gn] : 0.f;
#pragma unroll
        for (int mi = 0; mi < 4; ++mi) {
            int gm = m0 + wr * 64 + mi * 16 + kg * 4;
            f32x4 v = acc[mi][ni];
#pragma unroll
            for (int ri = 0; ri < 4; ++ri)
                C[(size_t)(gm + ri) * N + gn] = f2bf(v[ri] + bv);
        }
    }
}

// ---------------- per-head forward DFT GEMM: XH planes = Wf1 @ x_h^T ----------------
__global__ __launch_bounds__(256) void k_mfma_dft_h(const unsigned short* __restrict__ Wf1,
                                                    const unsigned short* __restrict__ Xb,
                                                    float* __restrict__ XH) {
    int n0 = blockIdx.x * 128;          // x-row tile
    int h = blockIdx.y;                 // head
    int tid = threadIdx.x;
    int lane = tid & 63, wave = tid >> 6;
    int wr = wave >> 1, wc = wave & 1;
    __shared__ __align__(16) unsigned short As[8192], Bs[8192];
    f32x4 acc[4][4] = {};
    int r0 = tid >> 1, hs = (tid & 1) << 2;
    const unsigned short* gA0 = Wf1 + r0 * 64 + hs * 8;
    const unsigned short* gB0 = Xb + (size_t)(n0 + r0) * Dn + h * 64 + hs * 8;
    mfma_core64(gA0, gB0, 1, As, Bs, tid, lane, wr, wc, acc);
    int kg = lane >> 4, cl = lane & 15;
#pragma unroll
    for (int ni = 0; ni < 4; ++ni) {
        int gn = n0 + wc * 64 + ni * 16 + cl;   // global x row
        int b = gn >> 10, u = gn & 1023;
#pragma unroll
        for (int mi = 0; mi < 4; ++mi) {
            int gmb = wr * 64 + mi * 16 + kg * 4;
            f32x4 v = acc[mi][ni];
#pragma unroll
            for (int rp = 0; rp < 2; ++rp) {
                int m = gmb + rp * 2;           // even: pair (re,im) of bin m>>1
                if (m < 66) {
                    size_t plane = (size_t)(b * Hn + h) * NK + (m >> 1);
                    *(float2*)&XH[(plane * 1024 + u) * 2] = make_float2(v[rp * 2], v[rp * 2 + 1]);
                }
            }
        }
    }
}

// ---------------- Y planes (interleaved) -> packed bf16 YT [16384][768] ----------------
__global__ __launch_bounds__(256) void k_transpose_yh(const float* __restrict__ YH,
                                                      unsigned short* __restrict__ YT) {
    int ut = blockIdx.x & 7;
    int h = (blockIdx.x >> 3) % 12;
    int b = blockIdx.x / 96;
    int u0 = ut * 128;
    __shared__ unsigned short T[128 * 66];
    int tid = threadIdx.x;
    int planeBase = (b * Hn + h) * NK;
    const float2* Yg = (const float2*)YH;
#pragma unroll
    for (int i = 0; i < 17; ++i) {
        int idx = tid + i * 256;        // 33k x 128uo
        if (idx < 4224) {
            int k = idx >> 7, uo = idx & 127;
            float2 v = Yg[(size_t)(planeBase + k) * 1024 + u0 + uo];
            T[uo * 66 + 2 * k] = f2bf(v.x);
            T[uo * 66 + 2 * k + 1] = f2bf(v.y);
        }
    }
    __syncthreads();
    unsigned int* out = (unsigned int*)YT;
#pragma unroll
    for (int i = 0; i < 16; ++i) {
        int idx = tid + i * 256;        // 128uo x 32w
        int uo = idx >> 5, w = idx & 31;
        unsigned int lo, hi;
        if (w == 0) {
            lo = T[uo * 66 + 0];        // re k=0
            hi = T[uo * 66 + 64];       // re k=32
        } else {
            lo = T[uo * 66 + 2 * w];    // re k=w
            hi = T[uo * 66 + 2 * w + 1];// im k=w
        }
        size_t r = (size_t)b * 1024 + u0 + uo;
        out[r * 384 + h * 32 + w] = lo | (hi << 16);
    }
}

// ---------------- per-head inverse DFT + GELU GEMM: G_h = gelu(YT_h @ Wi1^T) ----------------
__global__ __launch_bounds__(256) void k_mfma_idft_h(const unsigned short* __restrict__ YT,
                                                     const unsigned short* __restrict__ Wi1,
                                                     unsigned short* __restrict__ G) {
    int m0 = blockIdx.x * 128;          // row tile
    int h = blockIdx.y;                 // head
    int tid = threadIdx.x;
    int lane = tid & 63, wave = tid >> 6;
    int wr = wave >> 1, wc = wave & 1;
    __shared__ __align__(16) unsigned short As[8192], Bs[8192];
    f32x4 acc[4][4] = {};
    int r0 = tid >> 1, hs = (tid & 1) << 2;
    const unsigned short* gA0 = YT + (size_t)(m0 + r0) * Dn + h * 64 + hs * 8;
    const unsigned short* gB0 = Wi1 + r0 * 64 + hs * 8;
    mfma_core64(gA0, gB0, 1, As, Bs, tid, lane, wr, wc, acc);
    int kg = lane >> 4, cl = lane & 15;
#pragma unroll
    for (int ni = 0; ni < 4; ++ni) {
        int gn = wc * 64 + ni * 16 + cl;    // d index (valid < 64)
        if (gn < 64) {
#pragma unroll
            for (int mi = 0; mi < 4; ++mi) {
                int gm = m0 + wr * 64 + mi * 16 + kg * 4;
                f32x4 v = acc[mi][ni];
#pragma unroll
                for (int ri = 0; ri < 4; ++ri) {
                    float c = v[ri];
                    float g = c * 0.5f * (1.0f + erff(c * 0.70710678118f));
                    G[(size_t)(gm + ri) * Dn + h * 64 + gn] = f2bf(g);
                }
            }
        }
    }
}

// ---------------- sparse: spe_b = (tril(SP)/sigma) @ x_b, bf16 out ----------------
__global__ __launch_bounds__(256) void k_mfma_sparse(const unsigned short* __restrict__ SP,
                                                     const unsigned short* __restrict__ XT,
                                                     const float* __restrict__ sigbuf,
                                                     unsigned short* __restrict__ C) {
    int bx = blockIdx.x;
    int mt = bx & 7, nt = (bx >> 3) % 6, b = bx / 48;
    int m0 = mt * 128, n0 = nt * 128;
    const unsigned short* Xb = XT + (size_t)b * Dn * Ln;
    unsigned short* Cb = C + (size_t)b * Ln * Dn;
    int tid = threadIdx.x;
    int lane = tid & 63, wave = tid >> 6;
    int wr = wave >> 1, wc = wave & 1;
    __shared__ __align__(16) unsigned short As[8192], Bs[8192];
    f32x4 acc[4][4] = {};
    int r0 = tid >> 1, hs = (tid & 1) << 2;
    const unsigned short* gA0 = SP + (size_t)(m0 + r0) * Ln + hs * 8;
    const unsigned short* gB0 = Xb + (size_t)(n0 + r0) * Ln + hs * 8;
    mfma_core64(gA0, gB0, 2 * mt + 2, As, Bs, tid, lane, wr, wc, acc);
    float invs = sigbuf[0];
    int kg = lane >> 4, cl = lane & 15;
#pragma unroll
    for (int ni = 0; ni < 4; ++ni) {
        int gn = n0 + wc * 64 + ni * 16 + cl;
#pragma unroll
        for (int mi = 0; mi < 4; ++mi) {
            int gm = m0 + wr * 64 + mi * 16 + kg * 4;
            f32x4 v = acc[mi][ni];
#pragma unroll
            for (int ri = 0; ri < 4; ++ri)
                Cb[(size_t)(gm + ri) * Dn + gn] = f2bf(v[ri] * invs);
        }
    }
}

// ---------------- conversions ----------------
__global__ __launch_bounds__(256) void k_cvt_bf16(const float* __restrict__ in,
                                                  unsigned short* __restrict__ out, int n4) {
    int i = blockIdx.x * 256 + threadIdx.x;
    if (i < n4) {
        float4 v = ((const float4*)in)[i];
        u16x4 o;
        o[0] = f2bf(v.x); o[1] = f2bf(v.y); o[2] = f2bf(v.z); o[3] = f2bf(v.w);
        *(u16x4*)&out[(size_t)i * 4] = o;
    }
}

__global__ __launch_bounds__(256) void k_cvt_sp(const float* __restrict__ SP,
                                                unsigned short* __restrict__ O) {
    int s = blockIdx.x;
    int t0 = threadIdx.x * 4;
    float4 v = *(const float4*)&SP[(size_t)s * 1024 + t0];
    u16x4 o;
    o[0] = (t0 + 0 <= s) ? f2bf(v.x) : 0;
    o[1] = (t0 + 1 <= s) ? f2bf(v.y) : 0;
    o[2] = (t0 + 2 <= s) ? f2bf(v.z) : 0;
    o[3] = (t0 + 3 <= s) ? f2bf(v.w) : 0;
    *(u16x4*)&O[(size_t)s * 1024 + t0] = o;
}

// ---------------- x_bf[b][t][d] -> xT[b][d][t] bf16 ----------------
__global__ __launch_bounds__(256) void k_transpose_x(const unsigned short* __restrict__ X,
                                                     unsigned short* __restrict__ XT) {
    int d0 = blockIdx.x * 64, t0 = blockIdx.y * 64, b = blockIdx.z;
    const unsigned short* Xb = X + (size_t)b * Ln * Dn;
    unsigned short* Tb = XT + (size_t)b * Dn * Ln;
    __shared__ unsigned short tile[64 * 65];
    int tx = threadIdx.x & 63, ty = threadIdx.x >> 6;
#pragma unroll
    for (int i = 0; i < 16; ++i) {
        int t = ty + i * 4;
        tile[t * 65 + tx] = Xb[(size_t)(t0 + t) * Dn + d0 + tx];
    }
    __syncthreads();
#pragma unroll
    for (int i = 0; i < 16; ++i) {
        int d = ty + i * 4;
        Tb[(size_t)(d0 + d) * Ln + t0 + tx] = tile[tx * 65 + d];
    }
}

// ---------------- spectral norm ----------------
__global__ __launch_bounds__(256) void k_sn_colsum(const float* __restrict__ Wm,
                                                   float* __restrict__ partial) {
    int b = blockIdx.x;
    int tid = threadIdx.x;
    int c0 = tid * 4;
    float4 s = make_float4(0.f, 0.f, 0.f, 0.f);
#pragma unroll
    for (int i = 0; i < 16; ++i) {
        float4 v = *(const float4*)&Wm[(size_t)(b * 16 + i) * 1024 + c0];
        s.x += v.x; s.y += v.y; s.z += v.z; s.w += v.w;
    }
    *(float4*)&partial[(size_t)b * 1024 + c0] = s;
}

__global__ __launch_bounds__(1024) void k_sn_v2(const float* __restrict__ partial,
                                                float* __restrict__ v) {
    int j = threadIdx.x;
    float s = 0.f;
#pragma unroll 8
    for (int i = 0; i < 64; ++i) s += partial[(size_t)i * 1024 + j];
    s *= 0.03125f;
    __shared__ float red[1024];
    red[j] = s * s; __syncthreads();
    for (int st = 512; st > 0; st >>= 1) {
        if (j < st) red[j] += red[j + st];
        __syncthreads();
    }
    float nrm = sqrtf(red[0]);
    v[j] = s / (nrm + 1e-12f);
}

__global__ __launch_bounds__(64) void k_sn_u(const float* __restrict__ Wm,
                                             const float* __restrict__ v,
                                             float* __restrict__ ur) {
    int i = blockIdx.x;
    int lane = threadIdx.x;
    float s = 0.f;
    for (int j = lane; j < 1024; j += 64) s += Wm[(size_t)i * 1024 + j] * v[j];
#pragma unroll
    for (int off = 32; off > 0; off >>= 1) s += __shfl_down(s, off);
    if (lane == 0) ur[i] = s;
}

__global__ __launch_bounds__(1024) void k_sn_sigma(const float* __restrict__ ur,
                                                   float* __restrict__ sig) {
    int i = threadIdx.x;
    __shared__ float red[1024];
    float u = ur[i];
    red[i] = u * u; __syncthreads();
    for (int st = 512; st > 0; st >>= 1) {
        if (i < st) red[i] += red[i + st];
        __syncthreads();
    }
    if (i == 0) {
        float ss = red[0];
        float sigma = ss / (sqrtf(ss) + 1e-12f);
        sig[0] = 1.0f / sigma;
    }
}

// ---------------- final residual + LayerNorm (bf16 CE/SE) ----------------
__global__ __launch_bounds__(256) void k_final_ln(const unsigned short* __restrict__ CE,
                                                  const unsigned short* __restrict__ SE,
                                                  const float* __restrict__ EMB,
                                                  const float* __restrict__ g,
                                                  const float* __restrict__ be,
                                                  float* __restrict__ out) {
    int r = blockIdx.x;
    int tid = threadIdx.x;
    float y[3];
    float s = 0.f;
#pragma unroll
    for (int i = 0; i < 3; ++i) {
        int o = tid + i * 256;
        size_t idx = (size_t)r * 768 + o;
        y[i] = bf2f(CE[idx]) + bf2f(SE[idx]) + EMB[idx];
        s += y[i];
    }
    __shared__ float red[256];
    red[tid] = s; __syncthreads();
    for (int st = 128; st > 0; st >>= 1) {
        if (tid < st) red[tid] += red[tid + st];
        __syncthreads();
    }
    float mu = red[0] * (1.f / 768.f);
    __syncthreads();
    float vs = 0.f;
#pragma unroll
    for (int i = 0; i < 3; ++i) { float d = y[i] - mu; vs += d * d; }
    red[tid] = vs; __syncthreads();
    for (int st = 128; st > 0; st >>= 1) {
        if (tid < st) red[tid] += red[tid + st];
        __syncthreads();
    }
    float var = red[0] * (1.f / 768.f);
    float rstd = rsqrtf(var + 1e-12f);
#pragma unroll
    for (int i = 0; i < 3; ++i) {
        int o = tid + i * 256;
        size_t idx = (size_t)r * 768 + o;
        out[idx] = (y[i] - mu) * rstd * g[o] + be[o];
    }
}

extern "C" void kernel_launch(void* const* d_in, const int* in_sizes, int n_in,
                              void* d_out, int out_size, void* d_ws, size_t ws_size,
                              hipStream_t stream) {
    const float* emb     = (const float*)d_in[0];
    const float* pre_w   = (const float*)d_in[1];
    const float* pre_b   = (const float*)d_in[2];
    const float* psfs    = (const float*)d_in[3];
    const float* post_w  = (const float*)d_in[4];
    const float* post_b  = (const float*)d_in[5];
    const float* spmat   = (const float*)d_in[6];
    const float* ln_g    = (const float*)d_in[7];
    const float* ln_b    = (const float*)d_in[8];
    float* out = (float*)d_out;
    float* ws = (float*)d_ws;

    float* p      = ws + O_P;
    float* psfh   = ws + O_PSFH;
    float* part   = ws + O_PART;
    float* qh     = ws + O_QH;
    float* q      = ws + O_SIG + 8;
    float* XH     = ws + O_XH;                       // interleaved [bhk][1024][2]
    float* YH     = ws + O_YH;                       // interleaved
    float* phf    = ws + O_SPE;                      // alias (dead after conv)
    float* v      = ws + O_V;
    float* urw    = ws + O_UR;
    float* sig    = ws + O_SIG;

    unsigned short* x_bf      = (unsigned short*)(ws + O_X);
    unsigned short* Wf1       = (unsigned short*)(ws + O_X + 6291456);      // [128][64]
    unsigned short* Wi1       = (unsigned short*)(ws + O_X + 6295552);      // [128][64]
    unsigned short* YT        = (unsigned short*)(ws + O_XH);               // [16384][768] over dead XH
    unsigned short* xT_bf     = (unsigned short*)(ws + O_XH);               // over dead YT
    unsigned short* emb_bf    = (unsigned short*)(ws + O_YH);               // dead before YH written
    unsigned short* CE_bf     = (unsigned short*)(ws + O_YH);               // over dead YH
    unsigned short* spe_bf    = (unsigned short*)(ws + O_SPE);              // over dead phf
    unsigned short* G_bf      = (unsigned short*)(ws + O_SPE + 3145728);    // disjoint from spe/phf
    unsigned short* SP_bf     = (unsigned short*)(ws + O_P);                // over dead p
    unsigned short* pre_w_bf  = (unsigned short*)(ws + O_PSFH);             // over dead psfh
    unsigned short* post_w_bf = (unsigned short*)(ws + O_PSFH + 294912);

    // PSF preprocessing
    k_psf_softmax<<<Hn * 64, 256, 0, stream>>>(psfs, p, q);
    k_psf_dft<<<Hn * 256, 256, 0, stream>>>(p, psfh);
    k_q_dft<<<Hn, 64, 0, stream>>>(q, qh);
    k_tap_fft<<<NHK, 256, 0, stream>>>(psfh, qh, phf);

    // spectral norm scalar
    k_sn_colsum<<<64, 256, 0, stream>>>(spmat, part);
    k_sn_v2<<<1, 1024, 0, stream>>>(part, v);
    k_sn_u<<<1024, 64, 0, stream>>>(spmat, v, urw);
    k_sn_sigma<<<1, 1024, 0, stream>>>(urw, sig);

    // conversions + DFT block builds
    k_cvt_sp<<<1024, 256, 0, stream>>>(spmat, SP_bf);
    k_cvt_bf16<<<576, 256, 0, stream>>>(pre_w, pre_w_bf, 147456);
    k_cvt_bf16<<<576, 256, 0, stream>>>(post_w, post_w_bf, 147456);
    k_cvt_bf16<<<12288, 256, 0, stream>>>(emb, emb_bf, 3145728);
    k_build_wf1<<<128, 64, 0, stream>>>(Wf1);
    k_build_wi1<<<128, 64, 0, stream>>>(Wi1);

    // pre-projection (MFMA bf16 -> bf16 x)
    k_mfma_abt_bf<<<dim3(6, 128), 256, 0, stream>>>(emb_bf, pre_w_bf, pre_b, x_bf, Bn * Ln, Dn, Dn);

    // head-dim DFT: per-head batched GEMM -> interleaved planes
    k_mfma_dft_h<<<dim3(128, Hn), 256, 0, stream>>>(Wf1, x_bf, XH);

    // causal conv + uniform suffix via circular-2048 FFT (conflict-free swizzle)
    k_conv_fft<<<Bn * NHK, 256, 0, stream>>>(XH, phf, YH);

    // Y planes -> packed bf16 YT [16384][768]
    k_transpose_yh<<<Bn * Hn * 8, 256, 0, stream>>>(YH, YT);

    // inverse DFT + GELU: per-head batched GEMM -> G bf16
    k_mfma_idft_h<<<dim3(128, Hn), 256, 0, stream>>>(YT, Wi1, G_bf);

    // transpose x -> xT bf16 (over dead YT)
    k_transpose_x<<<dim3(12, 16, Bn), 256, 0, stream>>>(x_bf, xT_bf);

    // post-projection (MFMA bf16) -> CE bf16 (over dead YH)
    k_mfma_abt_bf<<<dim3(6, 128), 256, 0, stream>>>(G_bf, post_w_bf, post_b, CE_bf, Bn * Ln, Dn, Dn);

    // sparse branch (MFMA bf16, triangular k-loop) -> spe bf16 (over dead phf)
    k_mfma_sparse<<<768, 256, 0, stream>>>(SP_bf, xT_bf, sig, spe_bf);

    // residual + LayerNorm
    k_final_ln<<<Bn * Ln, 256, 0, stream>>>(CE_bf, spe_bf, emb, ln_g, ln_b, out);
}